// Round 14
// baseline (1235.126 us; speedup 1.0000x reference)
//
#include <hip/hip_runtime.h>
#include <hip/hip_bf16.h>
#include <math.h>

#define B_  2
#define T_  4096
#define D_  1024
#define HD_ 128
#define HQ_ 8
#define W_  1024
#define HH_ 1536
#define HG_ 2048
#define KC_ 4

typedef float  f32x4  __attribute__((ext_vector_type(4)));
typedef float  f32x2  __attribute__((ext_vector_type(2)));
typedef __bf16 bf16x8 __attribute__((ext_vector_type(8)));
typedef unsigned short u16;
typedef unsigned short u16x2 __attribute__((ext_vector_type(2)));
typedef unsigned short u16x4 __attribute__((ext_vector_type(4)));
typedef unsigned short u16x8 __attribute__((ext_vector_type(8)));

__device__ __forceinline__ u16 f2bf(float f) {
    unsigned int u = __builtin_bit_cast(unsigned int, f);
    u += 0x7fffu + ((u >> 16) & 1u);           // RNE
    return (u16)(u >> 16);
}
__device__ __forceinline__ float bf2f(u16 v) {
    unsigned int u = ((unsigned int)v) << 16;
    return __builtin_bit_cast(float, u);
}
__device__ __forceinline__ float gelu_exact(float x) {
    return 0.5f * x * (1.0f + erff(x * 0.70710678118654752f));
}
__device__ __forceinline__ float sigmoidf_(float x) {
    return 1.0f / (1.0f + expf(-x));
}

#define GLOAD16(gp, lp) __builtin_amdgcn_global_load_lds( \
    (const __attribute__((address_space(1))) void*)(gp),  \
    (__attribute__((address_space(3))) void*)(lp), 16, 0, 0)

// ---------------------------------------------------------------------------
// Fused f32 -> bf16 conversion for all 10 weight matrices (1 dispatch).
// ---------------------------------------------------------------------------
struct CvtArgs {
    const float* src[10];
    u16* dst[10];
    long cum[11];
};
__global__ __launch_bounds__(256)
void cvt_all_kernel(CvtArgs a)
{
    long i = ((long)blockIdx.x * 256 + threadIdx.x) * 8;
    if (i >= a.cum[10]) return;
    int seg = 0;
#pragma unroll
    for (int s = 1; s < 10; s++) if (i >= a.cum[s]) seg = s;
    long off = i - a.cum[seg];
    const float* src = a.src[seg];
    u16* dst = a.dst[seg];
    f32x4 x = *(const f32x4*)(src + off);
    f32x4 y = *(const f32x4*)(src + off + 4);
    u16x4 ua, ub;
    ua.x = f2bf(x.x); ua.y = f2bf(x.y); ua.z = f2bf(x.z); ua.w = f2bf(x.w);
    ub.x = f2bf(y.x); ub.y = f2bf(y.y); ub.z = f2bf(y.z); ub.w = f2bf(y.w);
    *(u16x4*)(dst + off) = ua;
    *(u16x4*)(dst + off + 4) = ub;
}

// ---------------------------------------------------------------------------
// bf16 GEMM v4 "big": 256x128 tile, 512 thr = 8 waves (4M x 2N), BK=32,
// triple-buffered LDS (72 KB), 2 tiles in flight, counted vmcnt(3), one
// barrier per K-step. Additive slot swizzle (verified).
// EPI: 0 none | 1 +bias | 2 +res(f32) | 3 glu: out=gelu(gatebuf)*acc
// ---------------------------------------------------------------------------
template<int EPI, bool OBF>
__global__ __launch_bounds__(512)
void gemm_big_kernel(const u16* __restrict__ A, const u16* __restrict__ Bw,
                     const float* __restrict__ bias, const float* __restrict__ res,
                     const u16* gatebuf, void* outv,
                     int M, int N, int K)
{
    __shared__ u16 lA[3][256 * 32];   // 16 KB each
    __shared__ u16 lB[3][128 * 32];   // 8 KB each
    const int n0 = blockIdx.x * 128, m0 = blockIdx.y * 256;
    const int tid = threadIdx.x, w = tid >> 6, l = tid & 63;
    const int wr = w >> 1, wc = w & 1;
    const int lr = l & 15, lg = l >> 4;

    f32x4 acc[4][4];
#pragma unroll
    for (int i = 0; i < 4; i++)
#pragma unroll
        for (int j = 0; j < 4; j++) acc[i][j] = {0.f, 0.f, 0.f, 0.f};

    const int srow = tid >> 2;
    const int gslot = (((tid) & 3) - ((tid >> 3) & 3)) & 3;
    const u16* gA = A + (long)(m0 + srow) * K + gslot * 8;
    const u16* gB = Bw + (long)(n0 + srow) * K + gslot * 8;
    const int lofs = tid * 8;

#define STAGE_G(buf, kk)                                            \
    {                                                               \
        GLOAD16(gA + (kk),                 &lA[buf][lofs]);         \
        GLOAD16(gA + (long)128 * K + (kk), &lA[buf][4096 + lofs]);  \
        GLOAD16(gB + (kk),                 &lB[buf][lofs]);         \
    }

    const int NT = K >> 5;
    STAGE_G(0, 0);
    STAGE_G(1, 32);

    const int swzr = (lr >> 1) & 3;
    int cur = 0;
    for (int t = 0; t < NT; ++t) {
        if (t == NT - 1) { asm volatile("s_waitcnt vmcnt(0)" ::: "memory"); }
        else             { asm volatile("s_waitcnt vmcnt(3)" ::: "memory"); }
        __builtin_amdgcn_s_barrier();
        __builtin_amdgcn_sched_barrier(0);
        if (t + 2 < NT) {
            int nb = cur + 2; if (nb >= 3) nb -= 3;
            STAGE_G(nb, (t + 2) << 5);
        }
        bf16x8 af[4], bfr[4];
#pragma unroll
        for (int m = 0; m < 4; m++)
            af[m] = *(const bf16x8*)&lA[cur][(wr * 64 + m * 16 + lr) * 32 + (((lg + swzr) & 3) * 8)];
#pragma unroll
        for (int n = 0; n < 4; n++)
            bfr[n] = *(const bf16x8*)&lB[cur][(wc * 64 + n * 16 + lr) * 32 + (((lg + swzr) & 3) * 8)];
        __builtin_amdgcn_s_setprio(1);
#pragma unroll
        for (int m = 0; m < 4; m++)
#pragma unroll
            for (int n = 0; n < 4; n++)
                acc[m][n] = __builtin_amdgcn_mfma_f32_16x16x32_bf16(af[m], bfr[n], acc[m][n], 0, 0, 0);
        __builtin_amdgcn_s_setprio(0);
        cur++; if (cur == 3) cur = 0;
    }
#undef STAGE_G

#pragma unroll
    for (int m = 0; m < 4; m++)
#pragma unroll
        for (int n = 0; n < 4; n++) {
            const int col = n0 + wc * 64 + n * 16 + lr;
            const float bv = (EPI == 1) ? bias[col] : 0.f;
#pragma unroll
            for (int r = 0; r < 4; r++) {
                const int row = m0 + wr * 64 + m * 16 + lg * 4 + r;
                const long idx = (long)row * N + col;
                float v = acc[m][n][r] + bv;
                if (EPI == 2) v += res[idx];
                if (EPI == 3) v = gelu_exact(bf2f(gatebuf[idx])) * v;
                if (OBF) ((u16*)outv)[idx] = f2bf(v);
                else     ((float*)outv)[idx] = v;
            }
        }
}

// ---------------------------------------------------------------------------
// bf16 GEMM v3 (128x128, 256 thr, BK=32, 3-buf 48KB) — for N=1536 and KV.
// ---------------------------------------------------------------------------
template<int EPI, bool OBF>
__global__ __launch_bounds__(256)
void gemm_bf16_kernel(const u16* __restrict__ A, const u16* __restrict__ Bw,
                      const float* __restrict__ bias, const float* __restrict__ res,
                      const u16* gatebuf, void* outv,
                      int M, int N, int K)
{
    __shared__ u16 lA[3][128 * 32];
    __shared__ u16 lB[3][128 * 32];
    const int n0 = blockIdx.x * 128, m0 = blockIdx.y * 128;
    const int tid = threadIdx.x, w = tid >> 6, l = tid & 63;
    const int wr = w >> 1, wc = w & 1, lr = l & 15, lg = l >> 4;

    f32x4 acc[4][4];
#pragma unroll
    for (int i = 0; i < 4; i++)
#pragma unroll
        for (int j = 0; j < 4; j++) acc[i][j] = {0.f, 0.f, 0.f, 0.f};

    const int srow = w * 16 + (l >> 2);
    const int gslot = ((l & 3) - ((l >> 3) & 3)) & 3;
    const u16* gA = A + (long)(m0 + srow) * K + gslot * 8;
    const u16* gB = Bw + (long)(n0 + srow) * K + gslot * 8;
    const int lofs = w * 512 + l * 8;

#define STAGE_G(buf, kk)                                          \
    {                                                             \
        GLOAD16(gA + (kk),                &lA[buf][lofs]);        \
        GLOAD16(gA + (long)64 * K + (kk), &lA[buf][2048 + lofs]); \
        GLOAD16(gB + (kk),                &lB[buf][lofs]);        \
        GLOAD16(gB + (long)64 * K + (kk), &lB[buf][2048 + lofs]); \
    }

    const int NT = K >> 5;
    STAGE_G(0, 0);
    STAGE_G(1, 32);

    const int swzr = (lr >> 1) & 3;
    int cur = 0;
    for (int t = 0; t < NT; ++t) {
        if (t == NT - 1) { asm volatile("s_waitcnt vmcnt(0)" ::: "memory"); }
        else             { asm volatile("s_waitcnt vmcnt(4)" ::: "memory"); }
        __builtin_amdgcn_s_barrier();
        __builtin_amdgcn_sched_barrier(0);
        if (t + 2 < NT) {
            int nb = cur + 2; if (nb >= 3) nb -= 3;
            STAGE_G(nb, (t + 2) << 5);
        }
        bf16x8 af[4], bfr[4];
#pragma unroll
        for (int m = 0; m < 4; m++)
            af[m] = *(const bf16x8*)&lA[cur][(wr * 64 + m * 16 + lr) * 32 + (((lg + swzr) & 3) * 8)];
#pragma unroll
        for (int n = 0; n < 4; n++)
            bfr[n] = *(const bf16x8*)&lB[cur][(wc * 64 + n * 16 + lr) * 32 + (((lg + swzr) & 3) * 8)];
        __builtin_amdgcn_s_setprio(1);
#pragma unroll
        for (int m = 0; m < 4; m++)
#pragma unroll
            for (int n = 0; n < 4; n++)
                acc[m][n] = __builtin_amdgcn_mfma_f32_16x16x32_bf16(af[m], bfr[n], acc[m][n], 0, 0, 0);
        __builtin_amdgcn_s_setprio(0);
        cur++; if (cur == 3) cur = 0;
    }
#undef STAGE_G

#pragma unroll
    for (int m = 0; m < 4; m++)
#pragma unroll
        for (int n = 0; n < 4; n++) {
            const int col = n0 + wc * 64 + n * 16 + lr;
            const float bv = (EPI == 1) ? bias[col] : 0.f;
#pragma unroll
            for (int r = 0; r < 4; r++) {
                const int row = m0 + wr * 64 + m * 16 + lg * 4 + r;
                const long idx = (long)row * N + col;
                float v = acc[m][n][r] + bv;
                if (EPI == 2) v += res[idx];
                if (EPI == 3) v = gelu_exact(bf2f(gatebuf[idx])) * v;
                if (OBF) ((u16*)outv)[idx] = f2bf(v);
                else     ((float*)outv)[idx] = v;
            }
        }
}

// ---------------------------------------------------------------------------
// RMSNorm -> bf16
// ---------------------------------------------------------------------------
__global__ __launch_bounds__(256)
void rmsnorm_kernel(const float* __restrict__ x, const float* __restrict__ g,
                    u16* __restrict__ out)
{
    const long row = blockIdx.x;
    const int tid = threadIdx.x;
    const float* xp = x + row * D_;
    f32x4 v = *(const f32x4*)(xp + tid * 4);
    float ss = v.x * v.x + v.y * v.y + v.z * v.z + v.w * v.w;
#pragma unroll
    for (int o = 1; o < 64; o <<= 1) ss += __shfl_xor(ss, o);
    __shared__ float ps[4];
    if ((tid & 63) == 0) ps[tid >> 6] = ss;
    __syncthreads();
    float tot = ps[0] + ps[1] + ps[2] + ps[3];
    float inv = rsqrtf(tot) * 32.0f;     // sqrt(1024)=32
    f32x4 gv = *(const f32x4*)(g + tid * 4);
    u16x4 o4;
    o4.x = f2bf(gv.x * v.x * inv); o4.y = f2bf(gv.y * v.y * inv);
    o4.z = f2bf(gv.z * v.z * inv); o4.w = f2bf(gv.w * v.w * inv);
    *(u16x4*)(out + row * D_ + tid * 4) = o4;
}

// ---------------------------------------------------------------------------
// RoPE: f32 Q/KV -> bf16 Qb [B,T,HQ,128], Kb [B,T,128]
// ---------------------------------------------------------------------------
__global__ void rope_bf16_kernel(const float* __restrict__ q, const float* __restrict__ kv,
                                 u16* __restrict__ qb, u16* __restrict__ kb)
{
    const long NQ = (long)B_ * T_ * HQ_ * 64;
    const long NK = (long)B_ * T_ * 64;
    long idx = (long)blockIdx.x * blockDim.x + threadIdx.x;
    if (idx >= NQ + NK) return;
    int i; long t; const float* src; u16* dst;
    if (idx < NQ) {
        i = idx & 63;
        long bth = idx >> 6;
        t = (bth / HQ_) % T_;
        src = q + bth * HD_ + 2 * i;
        dst = qb + bth * HD_ + 2 * i;
    } else {
        long k = idx - NQ;
        i = k & 63;
        long bt = k >> 6;
        t = bt % T_;
        src = kv + bt * (2 * HD_) + 2 * i;
        dst = kb + bt * HD_ + 2 * i;
    }
    float freq = exp2f(-(float)i * 0.20762050593046014f);  // log2(1e4)/64
    float ang = (float)t * freq;
    float sn, cs;
    sincosf(ang, &sn, &cs);
    f32x2 xv = *(const f32x2*)src;
    u16x2 yv;
    yv.x = f2bf(xv.x * cs - xv.y * sn);
    yv.y = f2bf(xv.x * sn + xv.y * cs);
    *(u16x2*)dst = yv;
}

// ---------------------------------------------------------------------------
// V transpose: KV f32 [B,T,2,128] (v half) -> Vt bf16 [B,128,T]
// ---------------------------------------------------------------------------
__global__ __launch_bounds__(256)
void vtrans_kernel(const float* __restrict__ kv, u16* __restrict__ vt)
{
    __shared__ float tile[64][65];
    const int t0 = blockIdx.x * 64, d0 = blockIdx.y * 64, b = blockIdx.z;
    const int tid = threadIdx.x;
    {
        const int tl = tid & 63, dg = tid >> 6;
        const float* vp = kv + (((long)b * T_ + t0 + tl) * 2 + 1) * HD_ + d0 + dg * 16;
#pragma unroll
        for (int j = 0; j < 4; j++) {
            f32x4 v = *(const f32x4*)(vp + j * 4);
            tile[dg * 16 + j * 4 + 0][tl] = v.x;
            tile[dg * 16 + j * 4 + 1][tl] = v.y;
            tile[dg * 16 + j * 4 + 2][tl] = v.z;
            tile[dg * 16 + j * 4 + 3][tl] = v.w;
        }
    }
    __syncthreads();
    {
        const int dl = tid >> 2, tg = (tid & 3) * 16;
        u16x8 a, c;
#pragma unroll
        for (int j = 0; j < 8; j++) a[j] = f2bf(tile[dl][tg + j]);
#pragma unroll
        for (int j = 0; j < 8; j++) c[j] = f2bf(tile[dl][tg + 8 + j]);
        u16* dst = vt + ((long)b * HD_ + d0 + dl) * T_ + t0 + tg;
        *(u16x8*)dst = a;
        *(u16x8*)(dst + 8) = c;
    }
}

// ---------------------------------------------------------------------------
// MFMA sliding-window attention v4: NO K/V LDS staging — K and V^T fragments
// read directly from global (window is L2-resident, shared by 8 heads;
// guide m169 lesson: staging L2-fit data is pure overhead). Barrier-free:
// only per-wave P tile in LDS (9 KB), synced with lgkmcnt. Softmax/mask/
// defer-max identical to verified v3.
// ---------------------------------------------------------------------------
#define PLD 72

__global__ __launch_bounds__(256)
void attn_mfma4_kernel(const u16* __restrict__ qb, const u16* __restrict__ kb,
                       const u16* __restrict__ vt, u16* __restrict__ o)
{
    __shared__ u16 Psh[4 * 16 * PLD];

    const int qt = blockIdx.x, h = blockIdx.y, b = blockIdx.z;
    const int q0 = qt * 64;
    const int tid = threadIdx.x;
    const int w = tid >> 6, l = tid & 63;
    const int lr = l & 15, lg = l >> 4;

    bf16x8 qfr[4];
    {
        const u16* qp = qb + (((long)b * T_ + q0 + w * 16 + lr) * HQ_ + h) * HD_;
#pragma unroll
        for (int kt = 0; kt < 4; kt++)
            qfr[kt] = *(const bf16x8*)(qp + kt * 32 + lg * 8);
    }

    const u16* kbase = kb + (long)b * T_ * HD_;
    const u16* vbase = vt + (long)b * HD_ * T_;

    f32x4 oacc[8];
#pragma unroll
    for (int dt = 0; dt < 8; dt++) oacc[dt] = {0.f, 0.f, 0.f, 0.f};
    float mrun[4], srun[4];
#pragma unroll
    for (int r = 0; r < 4; r++) { mrun[r] = -1e30f; srun[r] = 0.f; }

    const int kt_lo = (q0 >= W_) ? (q0 - W_) : 0;
    const int nt = ((q0 - kt_lo) >> 6) + 1;
    const float scale = 0.08838834764831845f;

    for (int t = 0; t < nt; ++t) {
        const int kt0 = kt_lo + t * 64;

        // QK^T: B-fragments straight from global K (L2-hit)
        f32x4 s[4];
#pragma unroll
        for (int ct = 0; ct < 4; ct++) {
            s[ct] = {0.f, 0.f, 0.f, 0.f};
#pragma unroll
            for (int kt = 0; kt < 4; kt++) {
                bf16x8 kf = *(const bf16x8*)&kbase[(kt0 + ct * 16 + lr) * HD_ + kt * 32 + lg * 8];
                s[ct] = __builtin_amdgcn_mfma_f32_16x16x32_bf16(qfr[kt], kf, s[ct], 0, 0, 0);
            }
        }

        float tmax[4] = {-3e38f, -3e38f, -3e38f, -3e38f};
        if (kt0 == q0) {                 // diagonal: causal mask
#pragma unroll
            for (int ct = 0; ct < 4; ct++) {
                const int kpos = kt0 + ct * 16 + lr;
#pragma unroll
                for (int r = 0; r < 4; r++) {
                    const int qpos = q0 + w * 16 + lg * 4 + r;
                    float v = s[ct][r] * scale;
                    v = (kpos <= qpos) ? v : -3e38f;
                    s[ct][r] = v;
                    tmax[r] = fmaxf(tmax[r], v);
                }
            }
        } else if (kt0 == q0 - W_) {     // far-left: window bound
#pragma unroll
            for (int ct = 0; ct < 4; ct++) {
                const int kpos = kt0 + ct * 16 + lr;
#pragma unroll
                for (int r = 0; r < 4; r++) {
                    const int qpos = q0 + w * 16 + lg * 4 + r;
                    float v = s[ct][r] * scale;
                    v = (kpos + W_ >= qpos) ? v : -3e38f;
                    s[ct][r] = v;
                    tmax[r] = fmaxf(tmax[r], v);
                }
            }
        } else {                         // full tile: maskless
#pragma unroll
            for (int ct = 0; ct < 4; ct++)
#pragma unroll
                for (int r = 0; r < 4; r++) {
                    float v = s[ct][r] * scale;
                    s[ct][r] = v;
                    tmax[r] = fmaxf(tmax[r], v);
                }
        }
#pragma unroll
        for (int r = 0; r < 4; r++)
#pragma unroll
            for (int msk = 1; msk < 16; msk <<= 1)
                tmax[r] = fmaxf(tmax[r], __shfl_xor(tmax[r], msk));

        bool defer = (tmax[0] <= mrun[0] + 8.f) && (tmax[1] <= mrun[1] + 8.f) &&
                     (tmax[2] <= mrun[2] + 8.f) && (tmax[3] <= mrun[3] + 8.f);
        if (!__all(defer)) {
            float frv[4];
#pragma unroll
            for (int r = 0; r < 4; r++) {
                float mnew = fmaxf(mrun[r], tmax[r]);
                frv[r] = __expf(mrun[r] - mnew);
                mrun[r] = mnew;
                srun[r] *= frv[r];
            }
#pragma unroll
            for (int dt = 0; dt < 8; dt++) {
                oacc[dt][0] *= frv[0]; oacc[dt][1] *= frv[1];
                oacc[dt][2] *= frv[2]; oacc[dt][3] *= frv[3];
            }
        }

        u16* pw = &Psh[w * 16 * PLD];
        float psum[4] = {0.f, 0.f, 0.f, 0.f};
#pragma unroll
        for (int ct = 0; ct < 4; ct++)
#pragma unroll
            for (int r = 0; r < 4; r++) {
                float p = __expf(s[ct][r] - mrun[r]);
                psum[r] += p;
                pw[(lg * 4 + r) * PLD + ct * 16 + lr] = f2bf(p);
            }
#pragma unroll
        for (int r = 0; r < 4; r++) {
#pragma unroll
            for (int msk = 1; msk < 16; msk <<= 1)
                psum[r] += __shfl_xor(psum[r], msk);
            srun[r] += psum[r];
        }

        asm volatile("s_waitcnt lgkmcnt(0)" ::: "memory");
        bf16x8 pa0 = *(const bf16x8*)&pw[lr * PLD + lg * 8];
        bf16x8 pa1 = *(const bf16x8*)&pw[lr * PLD + 32 + lg * 8];
        __builtin_amdgcn_s_setprio(1);
#pragma unroll
        for (int dt = 0; dt < 8; dt++) {
            bf16x8 vf0 = *(const bf16x8*)&vbase[(dt * 16 + lr) * T_ + kt0 + lg * 8];
            bf16x8 vf1 = *(const bf16x8*)&vbase[(dt * 16 + lr) * T_ + kt0 + 32 + lg * 8];
            oacc[dt] = __builtin_amdgcn_mfma_f32_16x16x32_bf16(pa0, vf0, oacc[dt], 0, 0, 0);
            oacc[dt] = __builtin_amdgcn_mfma_f32_16x16x32_bf16(pa1, vf1, oacc[dt], 0, 0, 0);
        }
        __builtin_amdgcn_s_setprio(0);
        // per-wave P buffer: next tile's writes ordered by lgkmcnt above;
        // reads complete before MFMA consumed them (compiler waitcnt). No
        // cross-wave sharing -> no barrier needed.
    }

#pragma unroll
    for (int r = 0; r < 4; r++) {
        const int qpos = q0 + w * 16 + lg * 4 + r;
        float inv = 1.f / srun[r];
        u16* op = o + ((long)b * T_ + qpos) * (HQ_ * HD_) + h * HD_;
#pragma unroll
        for (int dt = 0; dt < 8; dt++)
            op[dt * 16 + lr] = f2bf(oacc[dt][r] * inv);
    }
}

// ---------------------------------------------------------------------------
// Depthwise causal conv K=4 over bf16 u [8192,1536] -> bf16 xc
// ---------------------------------------------------------------------------
__global__ void conv_kernel(const u16* __restrict__ u, const float* __restrict__ w,
                            const float* __restrict__ bias, u16* __restrict__ xc)
{
    long idx = (long)blockIdx.x * blockDim.x + threadIdx.x;
    if (idx >= (long)B_ * T_ * HH_) return;
    int ch = (int)(idx % HH_);
    long row = idx / HH_;
    int t = (int)(row % T_);
    float acc = bias[ch];
#pragma unroll
    for (int k = 0; k < KC_; k++) {
        int ts = t - 3 + k;
        if (ts >= 0) acc += bf2f(u[(row - t + ts) * HH_ + ch]) * w[ch * KC_ + k];
    }
    xc[idx] = f2bf(acc);
}

// ---------------------------------------------------------------------------
// Chunked scan over recomputed (alpha, xin) from bf16 fg/ig/xc.
// ---------------------------------------------------------------------------
#define CS_ 64
#define NC_ (T_ / CS_)

__device__ __forceinline__ void alpha_xin(const u16 fg, const u16 ig, const u16 xc,
                                          float sp, float& a, float& xin)
{
    a = expf(-8.0f * sp * sigmoidf_(bf2f(fg)));
    xin = sqrtf(1.f - a * a + 1e-6f) * sigmoidf_(bf2f(ig)) * bf2f(xc);
}

__global__ void scan1_kernel(const u16* __restrict__ fg, const u16* __restrict__ ig,
                             const u16* __restrict__ xc, const float* __restrict__ fb,
                             float* __restrict__ P, float* __restrict__ L)
{
    long idx = (long)blockIdx.x * blockDim.x + threadIdx.x;
    if (idx >= (long)B_ * NC_ * HH_) return;
    int ch = (int)(idx % HH_);
    int chunk = (int)((idx / HH_) % NC_);
    int b = (int)(idx / ((long)HH_ * NC_));
    long base = ((long)b * T_ + chunk * CS_) * HH_ + ch;
    float f = fb[ch];
    float sp = (f > 20.f) ? f : log1pf(expf(f));
    float p = 1.f, lacc = 0.f;
    for (int i = 0; i < CS_; i++) {
        long o = base + (long)i * HH_;
        float a, xin;
        alpha_xin(fg[o], ig[o], xc[o], sp, a, xin);
        lacc = a * lacc + xin;
        p *= a;
    }
    P[idx] = p; L[idx] = lacc;
}
__global__ void scan2_kernel(const float* __restrict__ P, const float* __restrict__ L,
                             float* __restrict__ I)
{
    long idx = (long)blockIdx.x * blockDim.x + threadIdx.x;
    if (idx >= (long)B_ * HH_) return;
    int ch = (int)(idx % HH_);
    int b = (int)(idx / HH_);
    float init = 0.f;
    for (int c = 0; c < NC_; c++) {
        long o = ((long)b * NC_ + c) * HH_ + ch;
        I[o] = init;
        init = P[o] * init + L[o];
    }
}
__global__ void scan3_kernel(const u16* __restrict__ fg, const u16* __restrict__ ig,
                             const u16* __restrict__ xc, const float* __restrict__ fb,
                             const float* __restrict__ I, const u16* __restrict__ gate,
                             u16* __restrict__ glu)
{
    long idx = (long)blockIdx.x * blockDim.x + threadIdx.x;
    if (idx >= (long)B_ * NC_ * HH_) return;
    int ch = (int)(idx % HH_);
    int chunk = (int)((idx / HH_) % NC_);
    int b = (int)(idx / ((long)HH_ * NC_));
    long base = ((long)b * T_ + chunk * CS_) * HH_ + ch;
    float f = fb[ch];
    float sp = (f > 20.f) ? f : log1pf(expf(f));
    float h = I[idx];
    for (int i = 0; i < CS_; i++) {
        long o = base + (long)i * HH_;
        float a, xin;
        alpha_xin(fg[o], ig[o], xc[o], sp, a, xin);
        h = a * h + xin;
        glu[o] = f2bf(gelu_exact(bf2f(gate[o])) * h);
    }
}

// ---------------------------------------------------------------------------
// launch
// ---------------------------------------------------------------------------
static inline long cdivl(long a, long b) { return (a + b - 1) / b; }

extern "C" void kernel_launch(void* const* d_in, const int* in_sizes, int n_in,
                              void* d_out, int out_size, void* d_ws, size_t ws_size,
                              hipStream_t stream)
{
    const float* x_in   = (const float*)d_in[0];
    const float* sn_g   = (const float*)d_in[1];
    const float* q_w    = (const float*)d_in[2];
    const float* kv_w   = (const float*)d_in[3];
    const float* ao_w   = (const float*)d_in[4];
    const float* sgn_g  = (const float*)d_in[5];
    const float* sg_grow   = (const float*)d_in[6];
    const float* sg_shrink = (const float*)d_in[7];
    const float* hn_g   = (const float*)d_in[8];
    const float* h_in_w = (const float*)d_in[9];
    const float* h_conv_w = (const float*)d_in[10];
    const float* h_conv_b = (const float*)d_in[11];
    const float* h_gates_w = (const float*)d_in[12];
    const float* h_gates_b = (const float*)d_in[13];
    const float* h_forget  = (const float*)d_in[14];
    const float* h_out_w   = (const float*)d_in[15];
    const float* hgn_g  = (const float*)d_in[16];
    const float* hg_grow   = (const float*)d_in[17];
    const float* hg_shrink = (const float*)d_in[18];
    float* out = (float*)d_out;

    // ---- workspace layout ----
    char* wsb = (char*)d_ws;
    u16* Wq  = (u16*)wsb;                 // 1,048,576
    u16* Wkv = Wq  + 1048576;             // 262,144
    u16* Wao = Wkv + 262144;              // 1,048,576
    u16* Wsg = Wao + 1048576;             // 4,194,304
    u16* Wss = Wsg + 4194304;             // 2,097,152
    u16* Whi = Wss + 2097152;             // 3,145,728
    u16* Whg = Whi + 3145728;             // 4,718,592
    u16* Who = Whg + 4718592;             // 1,572,864
    u16* Wgg = Who + 1572864;             // 4,194,304
    u16* Wgs = Wgg + 4194304;             // 2,097,152
    char* ab = wsb + 48758784;            // activation arena
    u16*   XN   = (u16*)(ab + 0);                    // [8192,1024] bf16
    char*  S2   = ab + 16777216;
    char*  S3   = ab + 50331648;
    char*  S4   = ab + 75497472;
    char*  S5   = ab + 100663296;
    char*  S6   = ab + 125829120;
    float* PB   = (float*)(ab + 150994944);
    float* LB   = (float*)(ab + 151781376);
    float* IB   = (float*)(ab + 152567808);

    const long M = (long)B_ * T_;   // 8192
    dim3 blk(256);
    dim3 blk5(512);
    const float* NULF = nullptr;
    const u16*   NULB = nullptr;

    // ---- weight conversion (single dispatch) ----
    {
        CvtArgs ca;
        const float* srcs[10] = {q_w, kv_w, ao_w, sg_grow, sg_shrink,
                                 h_in_w, h_gates_w, h_out_w, hg_grow, hg_shrink};
        u16* dsts[10] = {Wq, Wkv, Wao, Wsg, Wss, Whi, Whg, Who, Wgg, Wgs};
        long ns[10] = {1048576, 262144, 1048576, 4194304, 2097152,
                       3145728, 4718592, 1572864, 4194304, 2097152};
        long cum = 0;
        for (int i = 0; i < 10; i++) {
            ca.src[i] = srcs[i]; ca.dst[i] = dsts[i]; ca.cum[i] = cum; cum += ns[i];
        }
        ca.cum[10] = cum;
        cvt_all_kernel<<<dim3(cdivl(cum / 8, 256)), blk, 0, stream>>>(ca);
    }

    // ---- attention sublayer ----
    {
        float* Q  = (float*)S2;                      // [8192,1024] f32
        float* KV = (float*)S3;                      // [8192,256]  f32
        u16*   Kb = (u16*)(S3 + 8388608);            // [B,T,128] bf16
        u16*   Vt = (u16*)(S3 + 10485760);           // [B,128,T] bf16
        u16*   Qb = (u16*)S4;                        // [B,T,HQ,128] bf16
        u16*   AT = (u16*)S5;                        // [8192,1024] bf16
        rmsnorm_kernel<<<dim3(M), blk, 0, stream>>>(x_in, sn_g, XN);
        gemm_big_kernel<0,false><<<dim3(8, 32), blk5, 0, stream>>>(XN, Wq, NULF, NULF, NULB, Q, M, 1024, 1024);
        gemm_bf16_kernel<0,false><<<dim3(2, 64), blk, 0, stream>>>(XN, Wkv, NULF, NULF, NULB, KV, M, 256, 1024);
        rope_bf16_kernel<<<dim3(cdivl((long)B_ * T_ * (HQ_ + 1) * 64, 256)), blk, 0, stream>>>(Q, KV, Qb, Kb);
        vtrans_kernel<<<dim3(T_ / 64, 2, B_), blk, 0, stream>>>(KV, Vt);
        attn_mfma4_kernel<<<dim3(T_ / 64, HQ_, B_), blk, 0, stream>>>(Qb, Kb, Vt, AT);
        gemm_big_kernel<2,false><<<dim3(8, 32), blk5, 0, stream>>>(AT, Wao, NULF, x_in, NULB, out, M, 1024, 1024);
    }

    // ---- MLP 1 ----
    {
        u16* GATE = (u16*)S2;             // [8192,2048] bf16
        rmsnorm_kernel<<<dim3(M), blk, 0, stream>>>(out, sgn_g, XN);
        gemm_big_kernel<0,true><<<dim3(16, 32), blk5, 0, stream>>>(XN, Wsg, NULF, NULF, NULB, GATE, M, 2048, 1024);
        gemm_big_kernel<3,true><<<dim3(16, 32), blk5, 0, stream>>>(XN, Wsg + (size_t)2048 * 1024, NULF, NULF, GATE, GATE, M, 2048, 1024);
        gemm_big_kernel<2,false><<<dim3(8, 32), blk5, 0, stream>>>(GATE, Wss, NULF, out, NULB, out, M, 1024, 2048);
    }

    // ---- hawk ----
    {
        u16* GATEH = (u16*)S2;            // [8192,1536] bf16
        u16* U     = (u16*)S3;            // [8192,1536] bf16 (reused as GLUH)
        u16* XC    = (u16*)S4;            // [8192,1536] bf16
        u16* FG    = (u16*)S5;            // [8192,1536] bf16
        u16* IG    = (u16*)S6;            // [8192,1536] bf16
        rmsnorm_kernel<<<dim3(M), blk, 0, stream>>>(out, hn_g, XN);
        gemm_bf16_kernel<0,true><<<dim3(12, 64), blk, 0, stream>>>(XN, Whi, NULF, NULF, NULB, GATEH, M, 1536, 1024);
        gemm_bf16_kernel<0,true><<<dim3(12, 64), blk, 0, stream>>>(XN, Whi + (size_t)1536 * 1024, NULF, NULF, NULB, U, M, 1536, 1024);
        conv_kernel<<<dim3(cdivl(M * HH_, 256)), blk, 0, stream>>>(U, h_conv_w, h_conv_b, XC);
        gemm_bf16_kernel<1,true><<<dim3(12, 64), blk, 0, stream>>>(XC, Whg, h_gates_b, NULF, NULB, FG, M, 1536, 1536);
        gemm_bf16_kernel<1,true><<<dim3(12, 64), blk, 0, stream>>>(XC, Whg + (size_t)1536 * 1536, h_gates_b + 1536, NULF, NULB, IG, M, 1536, 1536);
        scan1_kernel<<<dim3(cdivl((long)B_ * NC_ * HH_, 256)), blk, 0, stream>>>(FG, IG, XC, h_forget, PB, LB);
        scan2_kernel<<<dim3(cdivl((long)B_ * HH_, 256)), blk, 0, stream>>>(PB, LB, IB);
        scan3_kernel<<<dim3(cdivl((long)B_ * NC_ * HH_, 256)), blk, 0, stream>>>(FG, IG, XC, h_forget, IB, GATEH, U);
        gemm_big_kernel<2,false><<<dim3(8, 32), blk5, 0, stream>>>(U, Who, NULF, out, NULB, out, M, 1024, 1536);
    }

    // ---- MLP 2 ----
    {
        u16* GLU = (u16*)S2;              // [8192,2048] bf16
        rmsnorm_kernel<<<dim3(M), blk, 0, stream>>>(out, hgn_g, XN);
        gemm_big_kernel<0,true><<<dim3(16, 32), blk5, 0, stream>>>(XN, Wgg, NULF, NULF, NULB, GLU, M, 2048, 1024);
        gemm_big_kernel<3,true><<<dim3(16, 32), blk5, 0, stream>>>(XN, Wgg + (size_t)2048 * 1024, NULF, NULF, GLU, GLU, M, 2048, 1024);
        gemm_big_kernel<2,false><<<dim3(8, 32), blk5, 0, stream>>>(GLU, Wgs, NULF, out, NULB, out, M, 1024, 2048);
    }
}

// Round 15
// 1073.782 us; speedup vs baseline: 1.1503x; 1.1503x over previous
//
#include <hip/hip_runtime.h>
#include <hip/hip_bf16.h>
#include <math.h>

#define B_  2
#define T_  4096
#define D_  1024
#define HD_ 128
#define HQ_ 8
#define W_  1024
#define HH_ 1536
#define HG_ 2048
#define KC_ 4

typedef float  f32x4  __attribute__((ext_vector_type(4)));
typedef float  f32x2  __attribute__((ext_vector_type(2)));
typedef __bf16 bf16x8 __attribute__((ext_vector_type(8)));
typedef unsigned short u16;
typedef unsigned short u16x2 __attribute__((ext_vector_type(2)));
typedef unsigned short u16x4 __attribute__((ext_vector_type(4)));
typedef unsigned short u16x8 __attribute__((ext_vector_type(8)));

__device__ __forceinline__ u16 f2bf(float f) {
    unsigned int u = __builtin_bit_cast(unsigned int, f);
    u += 0x7fffu + ((u >> 16) & 1u);           // RNE
    return (u16)(u >> 16);
}
__device__ __forceinline__ float bf2f(u16 v) {
    unsigned int u = ((unsigned int)v) << 16;
    return __builtin_bit_cast(float, u);
}
__device__ __forceinline__ float gelu_exact(float x) {
    return 0.5f * x * (1.0f + erff(x * 0.70710678118654752f));
}
__device__ __forceinline__ float sigmoidf_(float x) {
    return 1.0f / (1.0f + expf(-x));
}

#define GLOAD16(gp, lp) __builtin_amdgcn_global_load_lds( \
    (const __attribute__((address_space(1))) void*)(gp),  \
    (__attribute__((address_space(3))) void*)(lp), 16, 0, 0)

// ---------------------------------------------------------------------------
// Fused f32 -> bf16 conversion for all 10 weight matrices (1 dispatch).
// ---------------------------------------------------------------------------
struct CvtArgs {
    const float* src[10];
    u16* dst[10];
    long cum[11];
};
__global__ __launch_bounds__(256)
void cvt_all_kernel(CvtArgs a)
{
    long i = ((long)blockIdx.x * 256 + threadIdx.x) * 8;
    if (i >= a.cum[10]) return;
    int seg = 0;
#pragma unroll
    for (int s = 1; s < 10; s++) if (i >= a.cum[s]) seg = s;
    long off = i - a.cum[seg];
    const float* src = a.src[seg];
    u16* dst = a.dst[seg];
    f32x4 x = *(const f32x4*)(src + off);
    f32x4 y = *(const f32x4*)(src + off + 4);
    u16x4 ua, ub;
    ua.x = f2bf(x.x); ua.y = f2bf(x.y); ua.z = f2bf(x.z); ua.w = f2bf(x.w);
    ub.x = f2bf(y.x); ub.y = f2bf(y.y); ub.z = f2bf(y.z); ub.w = f2bf(y.w);
    *(u16x4*)(dst + off) = ua;
    *(u16x4*)(dst + off + 4) = ub;
}

// ---------------------------------------------------------------------------
// bf16 GEMM v4 "big": 256x128 tile, 512 thr = 8 waves (4M x 2N), BK=32,
// triple-buffered LDS (72 KB), counted vmcnt(3), one barrier per K-step.
// EPI: 0 none | 1 +bias | 2 +res(f32) | 3 glu: out=gelu(gatebuf)*acc
// ---------------------------------------------------------------------------
template<int EPI, bool OBF>
__global__ __launch_bounds__(512)
void gemm_big_kernel(const u16* __restrict__ A, const u16* __restrict__ Bw,
                     const float* __restrict__ bias, const float* __restrict__ res,
                     const u16* gatebuf, void* outv,
                     int M, int N, int K)
{
    __shared__ u16 lA[3][256 * 32];   // 16 KB each
    __shared__ u16 lB[3][128 * 32];   // 8 KB each
    const int n0 = blockIdx.x * 128, m0 = blockIdx.y * 256;
    const int tid = threadIdx.x, w = tid >> 6, l = tid & 63;
    const int wr = w >> 1, wc = w & 1;
    const int lr = l & 15, lg = l >> 4;

    f32x4 acc[4][4];
#pragma unroll
    for (int i = 0; i < 4; i++)
#pragma unroll
        for (int j = 0; j < 4; j++) acc[i][j] = {0.f, 0.f, 0.f, 0.f};

    const int srow = tid >> 2;
    const int gslot = (((tid) & 3) - ((tid >> 3) & 3)) & 3;
    const u16* gA = A + (long)(m0 + srow) * K + gslot * 8;
    const u16* gB = Bw + (long)(n0 + srow) * K + gslot * 8;
    const int lofs = tid * 8;

#define STAGE_G(buf, kk)                                            \
    {                                                               \
        GLOAD16(gA + (kk),                 &lA[buf][lofs]);         \
        GLOAD16(gA + (long)128 * K + (kk), &lA[buf][4096 + lofs]);  \
        GLOAD16(gB + (kk),                 &lB[buf][lofs]);         \
    }

    const int NT = K >> 5;
    STAGE_G(0, 0);
    STAGE_G(1, 32);

    const int swzr = (lr >> 1) & 3;
    int cur = 0;
    for (int t = 0; t < NT; ++t) {
        if (t == NT - 1) { asm volatile("s_waitcnt vmcnt(0)" ::: "memory"); }
        else             { asm volatile("s_waitcnt vmcnt(3)" ::: "memory"); }
        __builtin_amdgcn_s_barrier();
        __builtin_amdgcn_sched_barrier(0);
        if (t + 2 < NT) {
            int nb = cur + 2; if (nb >= 3) nb -= 3;
            STAGE_G(nb, (t + 2) << 5);
        }
        bf16x8 af[4], bfr[4];
#pragma unroll
        for (int m = 0; m < 4; m++)
            af[m] = *(const bf16x8*)&lA[cur][(wr * 64 + m * 16 + lr) * 32 + (((lg + swzr) & 3) * 8)];
#pragma unroll
        for (int n = 0; n < 4; n++)
            bfr[n] = *(const bf16x8*)&lB[cur][(wc * 64 + n * 16 + lr) * 32 + (((lg + swzr) & 3) * 8)];
        __builtin_amdgcn_s_setprio(1);
#pragma unroll
        for (int m = 0; m < 4; m++)
#pragma unroll
            for (int n = 0; n < 4; n++)
                acc[m][n] = __builtin_amdgcn_mfma_f32_16x16x32_bf16(af[m], bfr[n], acc[m][n], 0, 0, 0);
        __builtin_amdgcn_s_setprio(0);
        cur++; if (cur == 3) cur = 0;
    }
#undef STAGE_G

#pragma unroll
    for (int m = 0; m < 4; m++)
#pragma unroll
        for (int n = 0; n < 4; n++) {
            const int col = n0 + wc * 64 + n * 16 + lr;
            const float bv = (EPI == 1) ? bias[col] : 0.f;
#pragma unroll
            for (int r = 0; r < 4; r++) {
                const int row = m0 + wr * 64 + m * 16 + lg * 4 + r;
                const long idx = (long)row * N + col;
                float v = acc[m][n][r] + bv;
                if (EPI == 2) v += res[idx];
                if (EPI == 3) v = gelu_exact(bf2f(gatebuf[idx])) * v;
                if (OBF) ((u16*)outv)[idx] = f2bf(v);
                else     ((float*)outv)[idx] = v;
            }
        }
}

// ---------------------------------------------------------------------------
// bf16 GEMM v3 (128x128, 256 thr, BK=32, 3-buf 48KB) — for N=1536 and KV.
// ---------------------------------------------------------------------------
template<int EPI, bool OBF>
__global__ __launch_bounds__(256)
void gemm_bf16_kernel(const u16* __restrict__ A, const u16* __restrict__ Bw,
                      const float* __restrict__ bias, const float* __restrict__ res,
                      const u16* gatebuf, void* outv,
                      int M, int N, int K)
{
    __shared__ u16 lA[3][128 * 32];
    __shared__ u16 lB[3][128 * 32];
    const int n0 = blockIdx.x * 128, m0 = blockIdx.y * 128;
    const int tid = threadIdx.x, w = tid >> 6, l = tid & 63;
    const int wr = w >> 1, wc = w & 1, lr = l & 15, lg = l >> 4;

    f32x4 acc[4][4];
#pragma unroll
    for (int i = 0; i < 4; i++)
#pragma unroll
        for (int j = 0; j < 4; j++) acc[i][j] = {0.f, 0.f, 0.f, 0.f};

    const int srow = w * 16 + (l >> 2);
    const int gslot = ((l & 3) - ((l >> 3) & 3)) & 3;
    const u16* gA = A + (long)(m0 + srow) * K + gslot * 8;
    const u16* gB = Bw + (long)(n0 + srow) * K + gslot * 8;
    const int lofs = w * 512 + l * 8;

#define STAGE_G(buf, kk)                                          \
    {                                                             \
        GLOAD16(gA + (kk),                &lA[buf][lofs]);        \
        GLOAD16(gA + (long)64 * K + (kk), &lA[buf][2048 + lofs]); \
        GLOAD16(gB + (kk),                &lB[buf][lofs]);        \
        GLOAD16(gB + (long)64 * K + (kk), &lB[buf][2048 + lofs]); \
    }

    const int NT = K >> 5;
    STAGE_G(0, 0);
    STAGE_G(1, 32);

    const int swzr = (lr >> 1) & 3;
    int cur = 0;
    for (int t = 0; t < NT; ++t) {
        if (t == NT - 1) { asm volatile("s_waitcnt vmcnt(0)" ::: "memory"); }
        else             { asm volatile("s_waitcnt vmcnt(4)" ::: "memory"); }
        __builtin_amdgcn_s_barrier();
        __builtin_amdgcn_sched_barrier(0);
        if (t + 2 < NT) {
            int nb = cur + 2; if (nb >= 3) nb -= 3;
            STAGE_G(nb, (t + 2) << 5);
        }
        bf16x8 af[4], bfr[4];
#pragma unroll
        for (int m = 0; m < 4; m++)
            af[m] = *(const bf16x8*)&lA[cur][(wr * 64 + m * 16 + lr) * 32 + (((lg + swzr) & 3) * 8)];
#pragma unroll
        for (int n = 0; n < 4; n++)
            bfr[n] = *(const bf16x8*)&lB[cur][(wc * 64 + n * 16 + lr) * 32 + (((lg + swzr) & 3) * 8)];
        __builtin_amdgcn_s_setprio(1);
#pragma unroll
        for (int m = 0; m < 4; m++)
#pragma unroll
            for (int n = 0; n < 4; n++)
                acc[m][n] = __builtin_amdgcn_mfma_f32_16x16x32_bf16(af[m], bfr[n], acc[m][n], 0, 0, 0);
        __builtin_amdgcn_s_setprio(0);
        cur++; if (cur == 3) cur = 0;
    }
#undef STAGE_G

#pragma unroll
    for (int m = 0; m < 4; m++)
#pragma unroll
        for (int n = 0; n < 4; n++) {
            const int col = n0 + wc * 64 + n * 16 + lr;
            const float bv = (EPI == 1) ? bias[col] : 0.f;
#pragma unroll
            for (int r = 0; r < 4; r++) {
                const int row = m0 + wr * 64 + m * 16 + lg * 4 + r;
                const long idx = (long)row * N + col;
                float v = acc[m][n][r] + bv;
                if (EPI == 2) v += res[idx];
                if (EPI == 3) v = gelu_exact(bf2f(gatebuf[idx])) * v;
                if (OBF) ((u16*)outv)[idx] = f2bf(v);
                else     ((float*)outv)[idx] = v;
            }
        }
}

// ---------------------------------------------------------------------------
// RMSNorm -> bf16
// ---------------------------------------------------------------------------
__global__ __launch_bounds__(256)
void rmsnorm_kernel(const float* __restrict__ x, const float* __restrict__ g,
                    u16* __restrict__ out)
{
    const long row = blockIdx.x;
    const int tid = threadIdx.x;
    const float* xp = x + row * D_;
    f32x4 v = *(const f32x4*)(xp + tid * 4);
    float ss = v.x * v.x + v.y * v.y + v.z * v.z + v.w * v.w;
#pragma unroll
    for (int o = 1; o < 64; o <<= 1) ss += __shfl_xor(ss, o);
    __shared__ float ps[4];
    if ((tid & 63) == 0) ps[tid >> 6] = ss;
    __syncthreads();
    float tot = ps[0] + ps[1] + ps[2] + ps[3];
    float inv = rsqrtf(tot) * 32.0f;     // sqrt(1024)=32
    f32x4 gv = *(const f32x4*)(g + tid * 4);
    u16x4 o4;
    o4.x = f2bf(gv.x * v.x * inv); o4.y = f2bf(gv.y * v.y * inv);
    o4.z = f2bf(gv.z * v.z * inv); o4.w = f2bf(gv.w * v.w * inv);
    *(u16x4*)(out + row * D_ + tid * 4) = o4;
}

// ---------------------------------------------------------------------------
// RoPE: f32 Q/KV -> bf16 Qb [B,T,HQ,128], Kb [B,T,128]
// ---------------------------------------------------------------------------
__global__ void rope_bf16_kernel(const float* __restrict__ q, const float* __restrict__ kv,
                                 u16* __restrict__ qb, u16* __restrict__ kb)
{
    const long NQ = (long)B_ * T_ * HQ_ * 64;
    const long NK = (long)B_ * T_ * 64;
    long idx = (long)blockIdx.x * blockDim.x + threadIdx.x;
    if (idx >= NQ + NK) return;
    int i; long t; const float* src; u16* dst;
    if (idx < NQ) {
        i = idx & 63;
        long bth = idx >> 6;
        t = (bth / HQ_) % T_;
        src = q + bth * HD_ + 2 * i;
        dst = qb + bth * HD_ + 2 * i;
    } else {
        long k = idx - NQ;
        i = k & 63;
        long bt = k >> 6;
        t = bt % T_;
        src = kv + bt * (2 * HD_) + 2 * i;
        dst = kb + bt * HD_ + 2 * i;
    }
    float freq = exp2f(-(float)i * 0.20762050593046014f);  // log2(1e4)/64
    float ang = (float)t * freq;
    float sn, cs;
    sincosf(ang, &sn, &cs);
    f32x2 xv = *(const f32x2*)src;
    u16x2 yv;
    yv.x = f2bf(xv.x * cs - xv.y * sn);
    yv.y = f2bf(xv.x * sn + xv.y * cs);
    *(u16x2*)dst = yv;
}

// ---------------------------------------------------------------------------
// V transpose: KV f32 [B,T,2,128] (v half) -> Vt bf16 [B,128,T]
// ---------------------------------------------------------------------------
__global__ __launch_bounds__(256)
void vtrans_kernel(const float* __restrict__ kv, u16* __restrict__ vt)
{
    __shared__ float tile[64][65];
    const int t0 = blockIdx.x * 64, d0 = blockIdx.y * 64, b = blockIdx.z;
    const int tid = threadIdx.x;
    {
        const int tl = tid & 63, dg = tid >> 6;
        const float* vp = kv + (((long)b * T_ + t0 + tl) * 2 + 1) * HD_ + d0 + dg * 16;
#pragma unroll
        for (int j = 0; j < 4; j++) {
            f32x4 v = *(const f32x4*)(vp + j * 4);
            tile[dg * 16 + j * 4 + 0][tl] = v.x;
            tile[dg * 16 + j * 4 + 1][tl] = v.y;
            tile[dg * 16 + j * 4 + 2][tl] = v.z;
            tile[dg * 16 + j * 4 + 3][tl] = v.w;
        }
    }
    __syncthreads();
    {
        const int dl = tid >> 2, tg = (tid & 3) * 16;
        u16x8 a, c;
#pragma unroll
        for (int j = 0; j < 8; j++) a[j] = f2bf(tile[dl][tg + j]);
#pragma unroll
        for (int j = 0; j < 8; j++) c[j] = f2bf(tile[dl][tg + 8 + j]);
        u16* dst = vt + ((long)b * HD_ + d0 + dl) * T_ + t0 + tg;
        *(u16x8*)dst = a;
        *(u16x8*)(dst + 8) = c;
    }
}

// ---------------------------------------------------------------------------
// Attention v5: 128 queries per block (two 16-row q-sets per wave) sharing
// one K/V staging. v3's verified per-set math (QK/mask/defer-max/P-LDS/PV)
// factored into attn_tile_process; set active iff qb0-W <= kt0 <= qb0;
// diag-mask iff kt0==qb0, lb-mask iff kt0==qb0-W.
// ---------------------------------------------------------------------------
#define PLD 72

__device__ __forceinline__ void attn_tile_process(
    const int kt0, const int qb0, const int w, const int lr, const int lg,
    const u16* __restrict__ Kc, const u16* __restrict__ Vc, u16* __restrict__ pw,
    const bf16x8* qfr, float* mrun, float* srun, f32x4* oacc)
{
    const int sw = lr & 7;
    const float scale = 0.08838834764831845f;

    f32x4 s[4];
    __builtin_amdgcn_s_setprio(1);
#pragma unroll
    for (int ct = 0; ct < 4; ct++) {
        s[ct] = {0.f, 0.f, 0.f, 0.f};
#pragma unroll
        for (int kt = 0; kt < 4; kt++) {
            bf16x8 kf = *(const bf16x8*)&Kc[(ct * 16 + lr) * 128 + (((kt * 4 + lg) ^ sw) * 8)];
            s[ct] = __builtin_amdgcn_mfma_f32_16x16x32_bf16(qfr[kt], kf, s[ct], 0, 0, 0);
        }
    }
    __builtin_amdgcn_s_setprio(0);

    float tmax[4] = {-3e38f, -3e38f, -3e38f, -3e38f};
    if (kt0 == qb0) {                    // diagonal tile: causal mask
#pragma unroll
        for (int ct = 0; ct < 4; ct++) {
            const int kpos = kt0 + ct * 16 + lr;
#pragma unroll
            for (int r = 0; r < 4; r++) {
                const int qpos = qb0 + w * 16 + lg * 4 + r;
                float v = s[ct][r] * scale;
                v = (kpos <= qpos) ? v : -3e38f;
                s[ct][r] = v;
                tmax[r] = fmaxf(tmax[r], v);
            }
        }
    } else if (kt0 == qb0 - W_) {        // far-left tile: window lower bound
#pragma unroll
        for (int ct = 0; ct < 4; ct++) {
            const int kpos = kt0 + ct * 16 + lr;
#pragma unroll
            for (int r = 0; r < 4; r++) {
                const int qpos = qb0 + w * 16 + lg * 4 + r;
                float v = s[ct][r] * scale;
                v = (kpos + W_ >= qpos) ? v : -3e38f;
                s[ct][r] = v;
                tmax[r] = fmaxf(tmax[r], v);
            }
        }
    } else {                             // full tile: maskless
#pragma unroll
        for (int ct = 0; ct < 4; ct++)
#pragma unroll
            for (int r = 0; r < 4; r++) {
                float v = s[ct][r] * scale;
                s[ct][r] = v;
                tmax[r] = fmaxf(tmax[r], v);
            }
    }
#pragma unroll
    for (int r = 0; r < 4; r++)
#pragma unroll
        for (int msk = 1; msk < 16; msk <<= 1)
            tmax[r] = fmaxf(tmax[r], __shfl_xor(tmax[r], msk));

    bool defer = (tmax[0] <= mrun[0] + 8.f) && (tmax[1] <= mrun[1] + 8.f) &&
                 (tmax[2] <= mrun[2] + 8.f) && (tmax[3] <= mrun[3] + 8.f);
    if (!__all(defer)) {
        float frv[4];
#pragma unroll
        for (int r = 0; r < 4; r++) {
            float mnew = fmaxf(mrun[r], tmax[r]);
            frv[r] = __expf(mrun[r] - mnew);
            mrun[r] = mnew;
            srun[r] *= frv[r];
        }
#pragma unroll
        for (int dt = 0; dt < 8; dt++) {
            oacc[dt][0] *= frv[0]; oacc[dt][1] *= frv[1];
            oacc[dt][2] *= frv[2]; oacc[dt][3] *= frv[3];
        }
    }

    // pw reuse safety: prior set's P reads must land before our writes
    asm volatile("s_waitcnt lgkmcnt(0)" ::: "memory");
    float psum[4] = {0.f, 0.f, 0.f, 0.f};
#pragma unroll
    for (int ct = 0; ct < 4; ct++)
#pragma unroll
        for (int r = 0; r < 4; r++) {
            float p = __expf(s[ct][r] - mrun[r]);
            psum[r] += p;
            pw[(lg * 4 + r) * PLD + ct * 16 + lr] = f2bf(p);
        }
#pragma unroll
    for (int r = 0; r < 4; r++) {
#pragma unroll
        for (int msk = 1; msk < 16; msk <<= 1)
            psum[r] += __shfl_xor(psum[r], msk);
        srun[r] += psum[r];
    }

    asm volatile("s_waitcnt lgkmcnt(0)" ::: "memory");
    bf16x8 pa0 = *(const bf16x8*)&pw[lr * PLD + lg * 8];
    bf16x8 pa1 = *(const bf16x8*)&pw[lr * PLD + 32 + lg * 8];
    __builtin_amdgcn_s_setprio(1);
#pragma unroll
    for (int dt = 0; dt < 8; dt++) {
        bf16x8 vf0 = *(const bf16x8*)&Vc[(dt * 16 + lr) * 64 + ((lg ^ sw) * 8)];
        bf16x8 vf1 = *(const bf16x8*)&Vc[(dt * 16 + lr) * 64 + (((4 + lg) ^ sw) * 8)];
        oacc[dt] = __builtin_amdgcn_mfma_f32_16x16x32_bf16(pa0, vf0, oacc[dt], 0, 0, 0);
        oacc[dt] = __builtin_amdgcn_mfma_f32_16x16x32_bf16(pa1, vf1, oacc[dt], 0, 0, 0);
    }
    __builtin_amdgcn_s_setprio(0);
}

__global__ __launch_bounds__(256)
void attn_mfma5_kernel(const u16* __restrict__ qb, const u16* __restrict__ kb,
                       const u16* __restrict__ vt, u16* __restrict__ o)
{
    __shared__ u16 Ksh[2][64 * 128];
    __shared__ u16 Vsh[2][128 * 64];
    __shared__ u16 Psh[4 * 16 * PLD];

    const int qt = blockIdx.x, h = blockIdx.y, b = blockIdx.z;
    const int Q0 = qt * 128;
    const int tid = threadIdx.x;
    const int w = tid >> 6, l = tid & 63;
    const int lr = l & 15, lg = l >> 4;

    bf16x8 qfrA[4], qfrB[4];
    {
        const u16* qpA = qb + (((long)b * T_ + Q0 + w * 16 + lr) * HQ_ + h) * HD_;
        const u16* qpB = qpA + (long)64 * HQ_ * HD_;
#pragma unroll
        for (int kt = 0; kt < 4; kt++) {
            qfrA[kt] = *(const bf16x8*)(qpA + kt * 32 + lg * 8);
            qfrB[kt] = *(const bf16x8*)(qpB + kt * 32 + lg * 8);
        }
    }

    int oK[4], oV[4];
#pragma unroll
    for (int i = 0; i < 4; i++) {
        int krow = w * 16 + i * 4 + (l >> 4);
        int kc8 = (l & 15) ^ (krow & 7);
        oK[i] = krow * 128 + kc8 * 8;
        int vrow = w * 32 + i * 8 + (l >> 3);
        int vc8 = (l & 7) ^ (vrow & 7);
        oV[i] = vrow * T_ + vc8 * 8;
    }
    const u16* kbase = kb + (long)b * T_ * HD_;
    const u16* vbase = vt + (long)b * HD_ * T_;

    f32x4 oaccA[8], oaccB[8];
#pragma unroll
    for (int dt = 0; dt < 8; dt++) { oaccA[dt] = {0.f,0.f,0.f,0.f}; oaccB[dt] = {0.f,0.f,0.f,0.f}; }
    float mrunA[4], srunA[4], mrunB[4], srunB[4];
#pragma unroll
    for (int r = 0; r < 4; r++) {
        mrunA[r] = -1e30f; srunA[r] = 0.f;
        mrunB[r] = -1e30f; srunB[r] = 0.f;
    }

    const int kt_lo = (Q0 >= W_) ? (Q0 - W_) : 0;
    const int kt_hi = Q0 + 64;            // diag tile of set B
    const int nt = ((kt_hi - kt_lo) >> 6) + 1;

#pragma unroll
    for (int i = 0; i < 4; i++) {
        GLOAD16(kbase + (long)kt_lo * HD_ + oK[i], &Ksh[0][w * 2048 + i * 512]);
        GLOAD16(vbase + kt_lo + oV[i], &Vsh[0][w * 2048 + i * 512]);
    }

    u16* pw = &Psh[w * 16 * PLD];
    for (int t = 0; t < nt; ++t) {
        const int kt0 = kt_lo + t * 64;
        const int cur = t & 1;
        if (t + 1 < nt) {
            const int ktn = kt0 + 64;
#pragma unroll
            for (int i = 0; i < 4; i++) {
                GLOAD16(kbase + (long)ktn * HD_ + oK[i], &Ksh[cur ^ 1][w * 2048 + i * 512]);
                GLOAD16(vbase + ktn + oV[i], &Vsh[cur ^ 1][w * 2048 + i * 512]);
            }
            asm volatile("s_waitcnt vmcnt(8)" ::: "memory");
        } else {
            asm volatile("s_waitcnt vmcnt(0)" ::: "memory");
        }
        __builtin_amdgcn_s_barrier();
        __builtin_amdgcn_sched_barrier(0);

        const u16* Kc = Ksh[cur];
        const u16* Vc = Vsh[cur];

        if (kt0 <= Q0)
            attn_tile_process(kt0, Q0, w, lr, lg, Kc, Vc, pw, qfrA, mrunA, srunA, oaccA);
        if (kt0 >= Q0 + 64 - W_)
            attn_tile_process(kt0, Q0 + 64, w, lr, lg, Kc, Vc, pw, qfrB, mrunB, srunB, oaccB);

        __syncthreads();   // all reads of buf[cur] done before next overwrite
    }

#pragma unroll
    for (int r = 0; r < 4; r++) {
        const int qposA = Q0 + w * 16 + lg * 4 + r;
        float invA = 1.f / srunA[r];
        u16* opA = o + ((long)b * T_ + qposA) * (HQ_ * HD_) + h * HD_;
        float invB = 1.f / srunB[r];
        u16* opB = opA + (long)64 * (HQ_ * HD_);
#pragma unroll
        for (int dt = 0; dt < 8; dt++) {
            opA[dt * 16 + lr] = f2bf(oaccA[dt][r] * invA);
            opB[dt * 16 + lr] = f2bf(oaccB[dt][r] * invB);
        }
    }
}

// ---------------------------------------------------------------------------
// Depthwise causal conv K=4 over bf16 u [8192,1536] -> bf16 xc
// ---------------------------------------------------------------------------
__global__ void conv_kernel(const u16* __restrict__ u, const float* __restrict__ w,
                            const float* __restrict__ bias, u16* __restrict__ xc)
{
    long idx = (long)blockIdx.x * blockDim.x + threadIdx.x;
    if (idx >= (long)B_ * T_ * HH_) return;
    int ch = (int)(idx % HH_);
    long row = idx / HH_;
    int t = (int)(row % T_);
    float acc = bias[ch];
#pragma unroll
    for (int k = 0; k < KC_; k++) {
        int ts = t - 3 + k;
        if (ts >= 0) acc += bf2f(u[(row - t + ts) * HH_ + ch]) * w[ch * KC_ + k];
    }
    xc[idx] = f2bf(acc);
}

// ---------------------------------------------------------------------------
// Chunked scan over recomputed (alpha, xin) from bf16 fg/ig/xc.
// ---------------------------------------------------------------------------
#define CS_ 64
#define NC_ (T_ / CS_)

__device__ __forceinline__ void alpha_xin(const u16 fg, const u16 ig, const u16 xc,
                                          float sp, float& a, float& xin)
{
    a = expf(-8.0f * sp * sigmoidf_(bf2f(fg)));
    xin = sqrtf(1.f - a * a + 1e-6f) * sigmoidf_(bf2f(ig)) * bf2f(xc);
}

__global__ void scan1_kernel(const u16* __restrict__ fg, const u16* __restrict__ ig,
                             const u16* __restrict__ xc, const float* __restrict__ fb,
                             float* __restrict__ P, float* __restrict__ L)
{
    long idx = (long)blockIdx.x * blockDim.x + threadIdx.x;
    if (idx >= (long)B_ * NC_ * HH_) return;
    int ch = (int)(idx % HH_);
    int chunk = (int)((idx / HH_) % NC_);
    int b = (int)(idx / ((long)HH_ * NC_));
    long base = ((long)b * T_ + chunk * CS_) * HH_ + ch;
    float f = fb[ch];
    float sp = (f > 20.f) ? f : log1pf(expf(f));
    float p = 1.f, lacc = 0.f;
    for (int i = 0; i < CS_; i++) {
        long o = base + (long)i * HH_;
        float a, xin;
        alpha_xin(fg[o], ig[o], xc[o], sp, a, xin);
        lacc = a * lacc + xin;
        p *= a;
    }
    P[idx] = p; L[idx] = lacc;
}
__global__ void scan2_kernel(const float* __restrict__ P, const float* __restrict__ L,
                             float* __restrict__ I)
{
    long idx = (long)blockIdx.x * blockDim.x + threadIdx.x;
    if (idx >= (long)B_ * HH_) return;
    int ch = (int)(idx % HH_);
    int b = (int)(idx / HH_);
    float init = 0.f;
    for (int c = 0; c < NC_; c++) {
        long o = ((long)b * NC_ + c) * HH_ + ch;
        I[o] = init;
        init = P[o] * init + L[o];
    }
}
__global__ void scan3_kernel(const u16* __restrict__ fg, const u16* __restrict__ ig,
                             const u16* __restrict__ xc, const float* __restrict__ fb,
                             const float* __restrict__ I, const u16* __restrict__ gate,
                             u16* __restrict__ glu)
{
    long idx = (long)blockIdx.x * blockDim.x + threadIdx.x;
    if (idx >= (long)B_ * NC_ * HH_) return;
    int ch = (int)(idx % HH_);
    int chunk = (int)((idx / HH_) % NC_);
    int b = (int)(idx / ((long)HH_ * NC_));
    long base = ((long)b * T_ + chunk * CS_) * HH_ + ch;
    float f = fb[ch];
    float sp = (f > 20.f) ? f : log1pf(expf(f));
    float h = I[idx];
    for (int i = 0; i < CS_; i++) {
        long o = base + (long)i * HH_;
        float a, xin;
        alpha_xin(fg[o], ig[o], xc[o], sp, a, xin);
        h = a * h + xin;
        glu[o] = f2bf(gelu_exact(bf2f(gate[o])) * h);
    }
}

// ---------------------------------------------------------------------------
// launch
// ---------------------------------------------------------------------------
static inline long cdivl(long a, long b) { return (a + b - 1) / b; }

extern "C" void kernel_launch(void* const* d_in, const int* in_sizes, int n_in,
                              void* d_out, int out_size, void* d_ws, size_t ws_size,
                              hipStream_t stream)
{
    const float* x_in   = (const float*)d_in[0];
    const float* sn_g   = (const float*)d_in[1];
    const float* q_w    = (const float*)d_in[2];
    const float* kv_w   = (const float*)d_in[3];
    const float* ao_w   = (const float*)d_in[4];
    const float* sgn_g  = (const float*)d_in[5];
    const float* sg_grow   = (const float*)d_in[6];
    const float* sg_shrink = (const float*)d_in[7];
    const float* hn_g   = (const float*)d_in[8];
    const float* h_in_w = (const float*)d_in[9];
    const float* h_conv_w = (const float*)d_in[10];
    const float* h_conv_b = (const float*)d_in[11];
    const float* h_gates_w = (const float*)d_in[12];
    const float* h_gates_b = (const float*)d_in[13];
    const float* h_forget  = (const float*)d_in[14];
    const float* h_out_w   = (const float*)d_in[15];
    const float* hgn_g  = (const float*)d_in[16];
    const float* hg_grow   = (const float*)d_in[17];
    const float* hg_shrink = (const float*)d_in[18];
    float* out = (float*)d_out;

    // ---- workspace layout ----
    char* wsb = (char*)d_ws;
    u16* Wq  = (u16*)wsb;                 // 1,048,576
    u16* Wkv = Wq  + 1048576;             // 262,144
    u16* Wao = Wkv + 262144;              // 1,048,576
    u16* Wsg = Wao + 1048576;             // 4,194,304
    u16* Wss = Wsg + 4194304;             // 2,097,152
    u16* Whi = Wss + 2097152;             // 3,145,728
    u16* Whg = Whi + 3145728;             // 4,718,592
    u16* Who = Whg + 4718592;             // 1,572,864
    u16* Wgg = Who + 1572864;             // 4,194,304
    u16* Wgs = Wgg + 4194304;             // 2,097,152
    char* ab = wsb + 48758784;            // activation arena
    u16*   XN   = (u16*)(ab + 0);                    // [8192,1024] bf16
    char*  S2   = ab + 16777216;
    char*  S3   = ab + 50331648;
    char*  S4   = ab + 75497472;
    char*  S5   = ab + 100663296;
    char*  S6   = ab + 125829120;
    float* PB   = (float*)(ab + 150994944);
    float* LB   = (float*)(ab + 151781376);
    float* IB   = (float*)(ab + 152567808);

    const long M = (long)B_ * T_;   // 8192
    dim3 blk(256);
    dim3 blk5(512);
    const float* NULF = nullptr;
    const u16*   NULB = nullptr;

    // ---- weight conversion (single dispatch) ----
    {
        CvtArgs ca;
        const float* srcs[10] = {q_w, kv_w, ao_w, sg_grow, sg_shrink,
                                 h_in_w, h_gates_w, h_out_w, hg_grow, hg_shrink};
        u16* dsts[10] = {Wq, Wkv, Wao, Wsg, Wss, Whi, Whg, Who, Wgg, Wgs};
        long ns[10] = {1048576, 262144, 1048576, 4194304, 2097152,
                       3145728, 4718592, 1572864, 4194304, 2097152};
        long cum = 0;
        for (int i = 0; i < 10; i++) {
            ca.src[i] = srcs[i]; ca.dst[i] = dsts[i]; ca.cum[i] = cum; cum += ns[i];
        }
        ca.cum[10] = cum;
        cvt_all_kernel<<<dim3(cdivl(cum / 8, 256)), blk, 0, stream>>>(ca);
    }

    // ---- attention sublayer ----
    {
        float* Q  = (float*)S2;                      // [8192,1024] f32
        float* KV = (float*)S3;                      // [8192,256]  f32
        u16*   Kb = (u16*)(S3 + 8388608);            // [B,T,128] bf16
        u16*   Vt = (u16*)(S3 + 10485760);           // [B,128,T] bf16
        u16*   Qb = (u16*)S4;                        // [B,T,HQ,128] bf16
        u16*   AT = (u16*)S5;                        // [8192,1024] bf16
        rmsnorm_kernel<<<dim3(M), blk, 0, stream>>>(x_in, sn_g, XN);
        gemm_big_kernel<0,false><<<dim3(8, 32), blk5, 0, stream>>>(XN, Wq, NULF, NULF, NULB, Q, M, 1024, 1024);
        gemm_bf16_kernel<0,false><<<dim3(2, 64), blk, 0, stream>>>(XN, Wkv, NULF, NULF, NULB, KV, M, 256, 1024);
        rope_bf16_kernel<<<dim3(cdivl((long)B_ * T_ * (HQ_ + 1) * 64, 256)), blk, 0, stream>>>(Q, KV, Qb, Kb);
        vtrans_kernel<<<dim3(T_ / 64, 2, B_), blk, 0, stream>>>(KV, Vt);
        attn_mfma5_kernel<<<dim3(T_ / 128, HQ_, B_), blk, 0, stream>>>(Qb, Kb, Vt, AT);
        gemm_big_kernel<2,false><<<dim3(8, 32), blk5, 0, stream>>>(AT, Wao, NULF, x_in, NULB, out, M, 1024, 1024);
    }

    // ---- MLP 1 ----
    {
        u16* GATE = (u16*)S2;             // [8192,2048] bf16
        rmsnorm_kernel<<<dim3(M), blk, 0, stream>>>(out, sgn_g, XN);
        gemm_big_kernel<0,true><<<dim3(16, 32), blk5, 0, stream>>>(XN, Wsg, NULF, NULF, NULB, GATE, M, 2048, 1024);
        gemm_big_kernel<3,true><<<dim3(16, 32), blk5, 0, stream>>>(XN, Wsg + (size_t)2048 * 1024, NULF, NULF, GATE, GATE, M, 2048, 1024);
        gemm_big_kernel<2,false><<<dim3(8, 32), blk5, 0, stream>>>(GATE, Wss, NULF, out, NULB, out, M, 1024, 2048);
    }

    // ---- hawk ----
    {
        u16* GATEH = (u16*)S2;            // [8192,1536] bf16
        u16* U     = (u16*)S3;            // [8192,1536] bf16 (reused as GLUH)
        u16* XC    = (u16*)S4;            // [8192,1536] bf16
        u16* FG    = (u16*)S5;            // [8192,1536] bf16
        u16* IG    = (u16*)S6;            // [8192,1536] bf16
        rmsnorm_kernel<<<dim3(M), blk, 0, stream>>>(out, hn_g, XN);
        gemm_bf16_kernel<0,true><<<dim3(12, 64), blk, 0, stream>>>(XN, Whi, NULF, NULF, NULB, GATEH, M, 1536, 1024);
        gemm_bf16_kernel<0,true><<<dim3(12, 64), blk, 0, stream>>>(XN, Whi + (size_t)1536 * 1024, NULF, NULF, NULB, U, M, 1536, 1024);
        conv_kernel<<<dim3(cdivl(M * HH_, 256)), blk, 0, stream>>>(U, h_conv_w, h_conv_b, XC);
        gemm_bf16_kernel<1,true><<<dim3(12, 64), blk, 0, stream>>>(XC, Whg, h_gates_b, NULF, NULB, FG, M, 1536, 1536);
        gemm_bf16_kernel<1,true><<<dim3(12, 64), blk, 0, stream>>>(XC, Whg + (size_t)1536 * 1536, h_gates_b + 1536, NULF, NULB, IG, M, 1536, 1536);
        scan1_kernel<<<dim3(cdivl((long)B_ * NC_ * HH_, 256)), blk, 0, stream>>>(FG, IG, XC, h_forget, PB, LB);
        scan2_kernel<<<dim3(cdivl((long)B_ * HH_, 256)), blk, 0, stream>>>(PB, LB, IB);
        scan3_kernel<<<dim3(cdivl((long)B_ * NC_ * HH_, 256)), blk, 0, stream>>>(FG, IG, XC, h_forget, IB, GATEH, U);
        gemm_big_kernel<2,false><<<dim3(8, 32), blk5, 0, stream>>>(U, Who, NULF, out, NULB, out, M, 1024, 1536);
    }

    // ---- MLP 2 ----
    {
        u16* GLU = (u16*)S2;              // [8192,2048] bf16
        rmsnorm_kernel<<<dim3(M), blk, 0, stream>>>(out, hgn_g, XN);
        gemm_big_kernel<0,true><<<dim3(16, 32), blk5, 0, stream>>>(XN, Wgg, NULF, NULF, NULB, GLU, M, 2048, 1024);
        gemm_big_kernel<3,true><<<dim3(16, 32), blk5, 0, stream>>>(XN, Wgg + (size_t)2048 * 1024, NULF, NULF, GLU, GLU, M, 2048, 1024);
        gemm_big_kernel<2,false><<<dim3(8, 32), blk5, 0, stream>>>(GLU, Wgs, NULF, out, NULB, out, M, 1024, 2048);
    }
}

// Round 16
// 949.979 us; speedup vs baseline: 1.3002x; 1.1303x over previous
//
#include <hip/hip_runtime.h>
#include <hip/hip_bf16.h>
#include <math.h>

#define B_  2
#define T_  4096
#define D_  1024
#define HD_ 128
#define HQ_ 8
#define W_  1024
#define HH_ 1536
#define HG_ 2048
#define KC_ 4

typedef float  f32x4  __attribute__((ext_vector_type(4)));
typedef float  f32x2  __attribute__((ext_vector_type(2)));
typedef __bf16 bf16x8 __attribute__((ext_vector_type(8)));
typedef unsigned short u16;
typedef unsigned short u16x2 __attribute__((ext_vector_type(2)));
typedef unsigned short u16x4 __attribute__((ext_vector_type(4)));
typedef unsigned short u16x8 __attribute__((ext_vector_type(8)));

__device__ __forceinline__ u16 f2bf(float f) {
    unsigned int u = __builtin_bit_cast(unsigned int, f);
    u += 0x7fffu + ((u >> 16) & 1u);           // RNE
    return (u16)(u >> 16);
}
__device__ __forceinline__ float bf2f(u16 v) {
    unsigned int u = ((unsigned int)v) << 16;
    return __builtin_bit_cast(float, u);
}
__device__ __forceinline__ float gelu_exact(float x) {
    return 0.5f * x * (1.0f + erff(x * 0.70710678118654752f));
}
__device__ __forceinline__ float sigmoidf_(float x) {
    return 1.0f / (1.0f + expf(-x));
}

#define GLOAD16(gp, lp) __builtin_amdgcn_global_load_lds( \
    (const __attribute__((address_space(1))) void*)(gp),  \
    (__attribute__((address_space(3))) void*)(lp), 16, 0, 0)

// ---------------------------------------------------------------------------
// Fused f32 -> bf16 conversion for all 10 weight matrices (1 dispatch).
// ---------------------------------------------------------------------------
struct CvtArgs {
    const float* src[10];
    u16* dst[10];
    long cum[11];
};
__global__ __launch_bounds__(256)
void cvt_all_kernel(CvtArgs a)
{
    long i = ((long)blockIdx.x * 256 + threadIdx.x) * 8;
    if (i >= a.cum[10]) return;
    int seg = 0;
#pragma unroll
    for (int s = 1; s < 10; s++) if (i >= a.cum[s]) seg = s;
    long off = i - a.cum[seg];
    const float* src = a.src[seg];
    u16* dst = a.dst[seg];
    f32x4 x = *(const f32x4*)(src + off);
    f32x4 y = *(const f32x4*)(src + off + 4);
    u16x4 ua, ub;
    ua.x = f2bf(x.x); ua.y = f2bf(x.y); ua.z = f2bf(x.z); ua.w = f2bf(x.w);
    ub.x = f2bf(y.x); ub.y = f2bf(y.y); ub.z = f2bf(y.z); ub.w = f2bf(y.w);
    *(u16x4*)(dst + off) = ua;
    *(u16x4*)(dst + off + 4) = ub;
}

// ---------------------------------------------------------------------------
// bf16 GEMM v4 "big": 256x128 tile, 512 thr = 8 waves (4M x 2N), BK=32,
// triple-buffered LDS (72 KB), counted vmcnt(3), one barrier per K-step.
// T1 XCD chunked swizzle: contiguous tile range per XCD -> A-panel L2 reuse.
// EPI: 0 none | 1 +bias | 2 +res(f32) | 3 glu: out=gelu(gatebuf)*acc
// ---------------------------------------------------------------------------
template<int EPI, bool OBF>
__global__ __launch_bounds__(512)
void gemm_big_kernel(const u16* __restrict__ A, const u16* __restrict__ Bw,
                     const float* __restrict__ bias, const float* __restrict__ res,
                     const u16* gatebuf, void* outv,
                     int M, int N, int K)
{
    __shared__ u16 lA[3][256 * 32];   // 16 KB each
    __shared__ u16 lB[3][128 * 32];   // 8 KB each
    // XCD chunked swizzle (grids are multiples of 8 -> bijective)
    const int wg0 = blockIdx.x + gridDim.x * blockIdx.y;
    const int cpx = (gridDim.x * gridDim.y) >> 3;
    const int wgs = (wg0 & 7) * cpx + (wg0 >> 3);
    const int n0 = (wgs % gridDim.x) * 128, m0 = (wgs / gridDim.x) * 256;
    const int tid = threadIdx.x, w = tid >> 6, l = tid & 63;
    const int wr = w >> 1, wc = w & 1;
    const int lr = l & 15, lg = l >> 4;

    f32x4 acc[4][4];
#pragma unroll
    for (int i = 0; i < 4; i++)
#pragma unroll
        for (int j = 0; j < 4; j++) acc[i][j] = {0.f, 0.f, 0.f, 0.f};

    const int srow = tid >> 2;
    const int gslot = (((tid) & 3) - ((tid >> 3) & 3)) & 3;
    const u16* gA = A + (long)(m0 + srow) * K + gslot * 8;
    const u16* gB = Bw + (long)(n0 + srow) * K + gslot * 8;
    const int lofs = tid * 8;

#define STAGE_G(buf, kk)                                            \
    {                                                               \
        GLOAD16(gA + (kk),                 &lA[buf][lofs]);         \
        GLOAD16(gA + (long)128 * K + (kk), &lA[buf][4096 + lofs]);  \
        GLOAD16(gB + (kk),                 &lB[buf][lofs]);         \
    }

    const int NT = K >> 5;
    STAGE_G(0, 0);
    STAGE_G(1, 32);

    const int swzr = (lr >> 1) & 3;
    int cur = 0;
    for (int t = 0; t < NT; ++t) {
        if (t == NT - 1) { asm volatile("s_waitcnt vmcnt(0)" ::: "memory"); }
        else             { asm volatile("s_waitcnt vmcnt(3)" ::: "memory"); }
        __builtin_amdgcn_s_barrier();
        __builtin_amdgcn_sched_barrier(0);
        if (t + 2 < NT) {
            int nb = cur + 2; if (nb >= 3) nb -= 3;
            STAGE_G(nb, (t + 2) << 5);
        }
        bf16x8 af[4], bfr[4];
#pragma unroll
        for (int m = 0; m < 4; m++)
            af[m] = *(const bf16x8*)&lA[cur][(wr * 64 + m * 16 + lr) * 32 + (((lg + swzr) & 3) * 8)];
#pragma unroll
        for (int n = 0; n < 4; n++)
            bfr[n] = *(const bf16x8*)&lB[cur][(wc * 64 + n * 16 + lr) * 32 + (((lg + swzr) & 3) * 8)];
        __builtin_amdgcn_s_setprio(1);
#pragma unroll
        for (int m = 0; m < 4; m++)
#pragma unroll
            for (int n = 0; n < 4; n++)
                acc[m][n] = __builtin_amdgcn_mfma_f32_16x16x32_bf16(af[m], bfr[n], acc[m][n], 0, 0, 0);
        __builtin_amdgcn_s_setprio(0);
        cur++; if (cur == 3) cur = 0;
    }
#undef STAGE_G

#pragma unroll
    for (int m = 0; m < 4; m++)
#pragma unroll
        for (int n = 0; n < 4; n++) {
            const int col = n0 + wc * 64 + n * 16 + lr;
            const float bv = (EPI == 1) ? bias[col] : 0.f;
#pragma unroll
            for (int r = 0; r < 4; r++) {
                const int row = m0 + wr * 64 + m * 16 + lg * 4 + r;
                const long idx = (long)row * N + col;
                float v = acc[m][n][r] + bv;
                if (EPI == 2) v += res[idx];
                if (EPI == 3) v = gelu_exact(bf2f(gatebuf[idx])) * v;
                if (OBF) ((u16*)outv)[idx] = f2bf(v);
                else     ((float*)outv)[idx] = v;
            }
        }
}

// ---------------------------------------------------------------------------
// bf16 GEMM v3 (128x128, 256 thr, BK=32, 3-buf 48KB) — KV projection.
// Same T1 swizzle.
// ---------------------------------------------------------------------------
template<int EPI, bool OBF>
__global__ __launch_bounds__(256)
void gemm_bf16_kernel(const u16* __restrict__ A, const u16* __restrict__ Bw,
                      const float* __restrict__ bias, const float* __restrict__ res,
                      const u16* gatebuf, void* outv,
                      int M, int N, int K)
{
    __shared__ u16 lA[3][128 * 32];
    __shared__ u16 lB[3][128 * 32];
    const int wg0 = blockIdx.x + gridDim.x * blockIdx.y;
    const int cpx = (gridDim.x * gridDim.y) >> 3;
    const int wgs = (wg0 & 7) * cpx + (wg0 >> 3);
    const int n0 = (wgs % gridDim.x) * 128, m0 = (wgs / gridDim.x) * 128;
    const int tid = threadIdx.x, w = tid >> 6, l = tid & 63;
    const int wr = w >> 1, wc = w & 1, lr = l & 15, lg = l >> 4;

    f32x4 acc[4][4];
#pragma unroll
    for (int i = 0; i < 4; i++)
#pragma unroll
        for (int j = 0; j < 4; j++) acc[i][j] = {0.f, 0.f, 0.f, 0.f};

    const int srow = w * 16 + (l >> 2);
    const int gslot = ((l & 3) - ((l >> 3) & 3)) & 3;
    const u16* gA = A + (long)(m0 + srow) * K + gslot * 8;
    const u16* gB = Bw + (long)(n0 + srow) * K + gslot * 8;
    const int lofs = w * 512 + l * 8;

#define STAGE_G(buf, kk)                                          \
    {                                                             \
        GLOAD16(gA + (kk),                &lA[buf][lofs]);        \
        GLOAD16(gA + (long)64 * K + (kk), &lA[buf][2048 + lofs]); \
        GLOAD16(gB + (kk),                &lB[buf][lofs]);        \
        GLOAD16(gB + (long)64 * K + (kk), &lB[buf][2048 + lofs]); \
    }

    const int NT = K >> 5;
    STAGE_G(0, 0);
    STAGE_G(1, 32);

    const int swzr = (lr >> 1) & 3;
    int cur = 0;
    for (int t = 0; t < NT; ++t) {
        if (t == NT - 1) { asm volatile("s_waitcnt vmcnt(0)" ::: "memory"); }
        else             { asm volatile("s_waitcnt vmcnt(4)" ::: "memory"); }
        __builtin_amdgcn_s_barrier();
        __builtin_amdgcn_sched_barrier(0);
        if (t + 2 < NT) {
            int nb = cur + 2; if (nb >= 3) nb -= 3;
            STAGE_G(nb, (t + 2) << 5);
        }
        bf16x8 af[4], bfr[4];
#pragma unroll
        for (int m = 0; m < 4; m++)
            af[m] = *(const bf16x8*)&lA[cur][(wr * 64 + m * 16 + lr) * 32 + (((lg + swzr) & 3) * 8)];
#pragma unroll
        for (int n = 0; n < 4; n++)
            bfr[n] = *(const bf16x8*)&lB[cur][(wc * 64 + n * 16 + lr) * 32 + (((lg + swzr) & 3) * 8)];
        __builtin_amdgcn_s_setprio(1);
#pragma unroll
        for (int m = 0; m < 4; m++)
#pragma unroll
            for (int n = 0; n < 4; n++)
                acc[m][n] = __builtin_amdgcn_mfma_f32_16x16x32_bf16(af[m], bfr[n], acc[m][n], 0, 0, 0);
        __builtin_amdgcn_s_setprio(0);
        cur++; if (cur == 3) cur = 0;
    }
#undef STAGE_G

#pragma unroll
    for (int m = 0; m < 4; m++)
#pragma unroll
        for (int n = 0; n < 4; n++) {
            const int col = n0 + wc * 64 + n * 16 + lr;
            const float bv = (EPI == 1) ? bias[col] : 0.f;
#pragma unroll
            for (int r = 0; r < 4; r++) {
                const int row = m0 + wr * 64 + m * 16 + lg * 4 + r;
                const long idx = (long)row * N + col;
                float v = acc[m][n][r] + bv;
                if (EPI == 2) v += res[idx];
                if (EPI == 3) v = gelu_exact(bf2f(gatebuf[idx])) * v;
                if (OBF) ((u16*)outv)[idx] = f2bf(v);
                else     ((float*)outv)[idx] = v;
            }
        }
}

// ---------------------------------------------------------------------------
// RMSNorm -> bf16
// ---------------------------------------------------------------------------
__global__ __launch_bounds__(256)
void rmsnorm_kernel(const float* __restrict__ x, const float* __restrict__ g,
                    u16* __restrict__ out)
{
    const long row = blockIdx.x;
    const int tid = threadIdx.x;
    const float* xp = x + row * D_;
    f32x4 v = *(const f32x4*)(xp + tid * 4);
    float ss = v.x * v.x + v.y * v.y + v.z * v.z + v.w * v.w;
#pragma unroll
    for (int o = 1; o < 64; o <<= 1) ss += __shfl_xor(ss, o);
    __shared__ float ps[4];
    if ((tid & 63) == 0) ps[tid >> 6] = ss;
    __syncthreads();
    float tot = ps[0] + ps[1] + ps[2] + ps[3];
    float inv = rsqrtf(tot) * 32.0f;     // sqrt(1024)=32
    f32x4 gv = *(const f32x4*)(g + tid * 4);
    u16x4 o4;
    o4.x = f2bf(gv.x * v.x * inv); o4.y = f2bf(gv.y * v.y * inv);
    o4.z = f2bf(gv.z * v.z * inv); o4.w = f2bf(gv.w * v.w * inv);
    *(u16x4*)(out + row * D_ + tid * 4) = o4;
}

// ---------------------------------------------------------------------------
// RoPE: f32 Q/KV -> bf16 Qb [B,T,HQ,128], Kb [B,T,128]
// ---------------------------------------------------------------------------
__global__ void rope_bf16_kernel(const float* __restrict__ q, const float* __restrict__ kv,
                                 u16* __restrict__ qb, u16* __restrict__ kb)
{
    const long NQ = (long)B_ * T_ * HQ_ * 64;
    const long NK = (long)B_ * T_ * 64;
    long idx = (long)blockIdx.x * blockDim.x + threadIdx.x;
    if (idx >= NQ + NK) return;
    int i; long t; const float* src; u16* dst;
    if (idx < NQ) {
        i = idx & 63;
        long bth = idx >> 6;
        t = (bth / HQ_) % T_;
        src = q + bth * HD_ + 2 * i;
        dst = qb + bth * HD_ + 2 * i;
    } else {
        long k = idx - NQ;
        i = k & 63;
        long bt = k >> 6;
        t = bt % T_;
        src = kv + bt * (2 * HD_) + 2 * i;
        dst = kb + bt * HD_ + 2 * i;
    }
    float freq = exp2f(-(float)i * 0.20762050593046014f);  // log2(1e4)/64
    float ang = (float)t * freq;
    float sn, cs;
    sincosf(ang, &sn, &cs);
    f32x2 xv = *(const f32x2*)src;
    u16x2 yv;
    yv.x = f2bf(xv.x * cs - xv.y * sn);
    yv.y = f2bf(xv.x * sn + xv.y * cs);
    *(u16x2*)dst = yv;
}

// ---------------------------------------------------------------------------
// V transpose: KV f32 [B,T,2,128] (v half) -> Vt bf16 [B,128,T]
// ---------------------------------------------------------------------------
__global__ __launch_bounds__(256)
void vtrans_kernel(const float* __restrict__ kv, u16* __restrict__ vt)
{
    __shared__ float tile[64][65];
    const int t0 = blockIdx.x * 64, d0 = blockIdx.y * 64, b = blockIdx.z;
    const int tid = threadIdx.x;
    {
        const int tl = tid & 63, dg = tid >> 6;
        const float* vp = kv + (((long)b * T_ + t0 + tl) * 2 + 1) * HD_ + d0 + dg * 16;
#pragma unroll
        for (int j = 0; j < 4; j++) {
            f32x4 v = *(const f32x4*)(vp + j * 4);
            tile[dg * 16 + j * 4 + 0][tl] = v.x;
            tile[dg * 16 + j * 4 + 1][tl] = v.y;
            tile[dg * 16 + j * 4 + 2][tl] = v.z;
            tile[dg * 16 + j * 4 + 3][tl] = v.w;
        }
    }
    __syncthreads();
    {
        const int dl = tid >> 2, tg = (tid & 3) * 16;
        u16x8 a, c;
#pragma unroll
        for (int j = 0; j < 8; j++) a[j] = f2bf(tile[dl][tg + j]);
#pragma unroll
        for (int j = 0; j < 8; j++) c[j] = f2bf(tile[dl][tg + 8 + j]);
        u16* dst = vt + ((long)b * HD_ + d0 + dl) * T_ + t0 + tg;
        *(u16x8*)dst = a;
        *(u16x8*)(dst + 8) = c;
    }
}

// ---------------------------------------------------------------------------
// MFMA sliding-window attention v3 (round-11 best config, verified)
// ---------------------------------------------------------------------------
#define PLD 72

__global__ __launch_bounds__(256)
void attn_mfma3_kernel(const u16* __restrict__ qb, const u16* __restrict__ kb,
                       const u16* __restrict__ vt, u16* __restrict__ o)
{
    __shared__ u16 Ksh[2][64 * 128];
    __shared__ u16 Vsh[2][128 * 64];
    __shared__ u16 Psh[4 * 16 * PLD];

    const int qt = blockIdx.x, h = blockIdx.y, b = blockIdx.z;
    const int q0 = qt * 64;
    const int tid = threadIdx.x;
    const int w = tid >> 6, l = tid & 63;
    const int lr = l & 15, lg = l >> 4;

    bf16x8 qfr[4];
    {
        const u16* qp = qb + (((long)b * T_ + q0 + w * 16 + lr) * HQ_ + h) * HD_;
#pragma unroll
        for (int kt = 0; kt < 4; kt++)
            qfr[kt] = *(const bf16x8*)(qp + kt * 32 + lg * 8);
    }

    int oK[4], oV[4];
#pragma unroll
    for (int i = 0; i < 4; i++) {
        int krow = w * 16 + i * 4 + (l >> 4);
        int kc8 = (l & 15) ^ (krow & 7);
        oK[i] = krow * 128 + kc8 * 8;
        int vrow = w * 32 + i * 8 + (l >> 3);
        int vc8 = (l & 7) ^ (vrow & 7);
        oV[i] = vrow * T_ + vc8 * 8;
    }
    const u16* kbase = kb + (long)b * T_ * HD_;
    const u16* vbase = vt + (long)b * HD_ * T_;

    f32x4 oacc[8];
#pragma unroll
    for (int dt = 0; dt < 8; dt++) oacc[dt] = {0.f, 0.f, 0.f, 0.f};
    float mrun[4], srun[4];
#pragma unroll
    for (int r = 0; r < 4; r++) { mrun[r] = -1e30f; srun[r] = 0.f; }

    const int kt_lo = (q0 >= W_) ? (q0 - W_) : 0;
    const int nt = ((q0 - kt_lo) >> 6) + 1;
    const int sw = lr & 7;
    const float scale = 0.08838834764831845f;

#pragma unroll
    for (int i = 0; i < 4; i++) {
        GLOAD16(kbase + (long)kt_lo * HD_ + oK[i], &Ksh[0][w * 2048 + i * 512]);
        GLOAD16(vbase + kt_lo + oV[i], &Vsh[0][w * 2048 + i * 512]);
    }

    for (int t = 0; t < nt; ++t) {
        const int kt0 = kt_lo + t * 64;
        const int cur = t & 1;
        if (t + 1 < nt) {
            const int ktn = kt0 + 64;
#pragma unroll
            for (int i = 0; i < 4; i++) {
                GLOAD16(kbase + (long)ktn * HD_ + oK[i], &Ksh[cur ^ 1][w * 2048 + i * 512]);
                GLOAD16(vbase + ktn + oV[i], &Vsh[cur ^ 1][w * 2048 + i * 512]);
            }
            asm volatile("s_waitcnt vmcnt(8)" ::: "memory");
        } else {
            asm volatile("s_waitcnt vmcnt(0)" ::: "memory");
        }
        __builtin_amdgcn_s_barrier();
        __builtin_amdgcn_sched_barrier(0);

        const u16* Kc = Ksh[cur];
        const u16* Vc = Vsh[cur];

        f32x4 s[4];
        __builtin_amdgcn_s_setprio(1);
#pragma unroll
        for (int ct = 0; ct < 4; ct++) {
            s[ct] = {0.f, 0.f, 0.f, 0.f};
#pragma unroll
            for (int kt = 0; kt < 4; kt++) {
                bf16x8 kf = *(const bf16x8*)&Kc[(ct * 16 + lr) * 128 + (((kt * 4 + lg) ^ sw) * 8)];
                s[ct] = __builtin_amdgcn_mfma_f32_16x16x32_bf16(qfr[kt], kf, s[ct], 0, 0, 0);
            }
        }
        __builtin_amdgcn_s_setprio(0);

        float tmax[4] = {-3e38f, -3e38f, -3e38f, -3e38f};
        if (kt0 == q0) {
#pragma unroll
            for (int ct = 0; ct < 4; ct++) {
                const int kpos = kt0 + ct * 16 + lr;
#pragma unroll
                for (int r = 0; r < 4; r++) {
                    const int qpos = q0 + w * 16 + lg * 4 + r;
                    float v = s[ct][r] * scale;
                    v = (kpos <= qpos) ? v : -3e38f;
                    s[ct][r] = v;
                    tmax[r] = fmaxf(tmax[r], v);
                }
            }
        } else if (kt0 == q0 - W_) {
#pragma unroll
            for (int ct = 0; ct < 4; ct++) {
                const int kpos = kt0 + ct * 16 + lr;
#pragma unroll
                for (int r = 0; r < 4; r++) {
                    const int qpos = q0 + w * 16 + lg * 4 + r;
                    float v = s[ct][r] * scale;
                    v = (kpos + W_ >= qpos) ? v : -3e38f;
                    s[ct][r] = v;
                    tmax[r] = fmaxf(tmax[r], v);
                }
            }
        } else {
#pragma unroll
            for (int ct = 0; ct < 4; ct++)
#pragma unroll
                for (int r = 0; r < 4; r++) {
                    float v = s[ct][r] * scale;
                    s[ct][r] = v;
                    tmax[r] = fmaxf(tmax[r], v);
                }
        }
#pragma unroll
        for (int r = 0; r < 4; r++)
#pragma unroll
            for (int msk = 1; msk < 16; msk <<= 1)
                tmax[r] = fmaxf(tmax[r], __shfl_xor(tmax[r], msk));

        bool defer = (tmax[0] <= mrun[0] + 8.f) && (tmax[1] <= mrun[1] + 8.f) &&
                     (tmax[2] <= mrun[2] + 8.f) && (tmax[3] <= mrun[3] + 8.f);
        if (!__all(defer)) {
            float frv[4];
#pragma unroll
            for (int r = 0; r < 4; r++) {
                float mnew = fmaxf(mrun[r], tmax[r]);
                frv[r] = __expf(mrun[r] - mnew);
                mrun[r] = mnew;
                srun[r] *= frv[r];
            }
#pragma unroll
            for (int dt = 0; dt < 8; dt++) {
                oacc[dt][0] *= frv[0]; oacc[dt][1] *= frv[1];
                oacc[dt][2] *= frv[2]; oacc[dt][3] *= frv[3];
            }
        }

        u16* pw = &Psh[w * 16 * PLD];
        float psum[4] = {0.f, 0.f, 0.f, 0.f};
#pragma unroll
        for (int ct = 0; ct < 4; ct++)
#pragma unroll
            for (int r = 0; r < 4; r++) {
                float p = __expf(s[ct][r] - mrun[r]);
                psum[r] += p;
                pw[(lg * 4 + r) * PLD + ct * 16 + lr] = f2bf(p);
            }
#pragma unroll
        for (int r = 0; r < 4; r++) {
#pragma unroll
            for (int msk = 1; msk < 16; msk <<= 1)
                psum[r] += __shfl_xor(psum[r], msk);
            srun[r] += psum[r];
        }

        asm volatile("s_waitcnt lgkmcnt(0)" ::: "memory");
        bf16x8 pa0 = *(const bf16x8*)&pw[lr * PLD + lg * 8];
        bf16x8 pa1 = *(const bf16x8*)&pw[lr * PLD + 32 + lg * 8];
        __builtin_amdgcn_s_setprio(1);
#pragma unroll
        for (int dt = 0; dt < 8; dt++) {
            bf16x8 vf0 = *(const bf16x8*)&Vc[(dt * 16 + lr) * 64 + ((lg ^ sw) * 8)];
            bf16x8 vf1 = *(const bf16x8*)&Vc[(dt * 16 + lr) * 64 + (((4 + lg) ^ sw) * 8)];
            oacc[dt] = __builtin_amdgcn_mfma_f32_16x16x32_bf16(pa0, vf0, oacc[dt], 0, 0, 0);
            oacc[dt] = __builtin_amdgcn_mfma_f32_16x16x32_bf16(pa1, vf1, oacc[dt], 0, 0, 0);
        }
        __builtin_amdgcn_s_setprio(0);
        __syncthreads();
    }

#pragma unroll
    for (int r = 0; r < 4; r++) {
        const int qpos = q0 + w * 16 + lg * 4 + r;
        float inv = 1.f / srun[r];
        u16* op = o + ((long)b * T_ + qpos) * (HQ_ * HD_) + h * HD_;
#pragma unroll
        for (int dt = 0; dt < 8; dt++)
            op[dt * 16 + lr] = f2bf(oacc[dt][r] * inv);
    }
}

// ---------------------------------------------------------------------------
// Depthwise causal conv K=4 over bf16 u [8192,1536] -> bf16 xc
// ---------------------------------------------------------------------------
__global__ void conv_kernel(const u16* __restrict__ u, const float* __restrict__ w,
                            const float* __restrict__ bias, u16* __restrict__ xc)
{
    long idx = (long)blockIdx.x * blockDim.x + threadIdx.x;
    if (idx >= (long)B_ * T_ * HH_) return;
    int ch = (int)(idx % HH_);
    long row = idx / HH_;
    int t = (int)(row % T_);
    float acc = bias[ch];
#pragma unroll
    for (int k = 0; k < KC_; k++) {
        int ts = t - 3 + k;
        if (ts >= 0) acc += bf2f(u[(row - t + ts) * HH_ + ch]) * w[ch * KC_ + k];
    }
    xc[idx] = f2bf(acc);
}

// ---------------------------------------------------------------------------
// Chunked scan over recomputed (alpha, xin) from bf16 fg/ig/xc.
// ---------------------------------------------------------------------------
#define CS_ 64
#define NC_ (T_ / CS_)

__device__ __forceinline__ void alpha_xin(const u16 fg, const u16 ig, const u16 xc,
                                          float sp, float& a, float& xin)
{
    a = expf(-8.0f * sp * sigmoidf_(bf2f(fg)));
    xin = sqrtf(1.f - a * a + 1e-6f) * sigmoidf_(bf2f(ig)) * bf2f(xc);
}

__global__ void scan1_kernel(const u16* __restrict__ fg, const u16* __restrict__ ig,
                             const u16* __restrict__ xc, const float* __restrict__ fb,
                             float* __restrict__ P, float* __restrict__ L)
{
    long idx = (long)blockIdx.x * blockDim.x + threadIdx.x;
    if (idx >= (long)B_ * NC_ * HH_) return;
    int ch = (int)(idx % HH_);
    int chunk = (int)((idx / HH_) % NC_);
    int b = (int)(idx / ((long)HH_ * NC_));
    long base = ((long)b * T_ + chunk * CS_) * HH_ + ch;
    float f = fb[ch];
    float sp = (f > 20.f) ? f : log1pf(expf(f));
    float p = 1.f, lacc = 0.f;
    for (int i = 0; i < CS_; i++) {
        long o = base + (long)i * HH_;
        float a, xin;
        alpha_xin(fg[o], ig[o], xc[o], sp, a, xin);
        lacc = a * lacc + xin;
        p *= a;
    }
    P[idx] = p; L[idx] = lacc;
}
__global__ void scan2_kernel(const float* __restrict__ P, const float* __restrict__ L,
                             float* __restrict__ I)
{
    long idx = (long)blockIdx.x * blockDim.x + threadIdx.x;
    if (idx >= (long)B_ * HH_) return;
    int ch = (int)(idx % HH_);
    int b = (int)(idx / HH_);
    float init = 0.f;
    for (int c = 0; c < NC_; c++) {
        long o = ((long)b * NC_ + c) * HH_ + ch;
        I[o] = init;
        init = P[o] * init + L[o];
    }
}
__global__ void scan3_kernel(const u16* __restrict__ fg, const u16* __restrict__ ig,
                             const u16* __restrict__ xc, const float* __restrict__ fb,
                             const float* __restrict__ I, const u16* __restrict__ gate,
                             u16* __restrict__ glu)
{
    long idx = (long)blockIdx.x * blockDim.x + threadIdx.x;
    if (idx >= (long)B_ * NC_ * HH_) return;
    int ch = (int)(idx % HH_);
    int chunk = (int)((idx / HH_) % NC_);
    int b = (int)(idx / ((long)HH_ * NC_));
    long base = ((long)b * T_ + chunk * CS_) * HH_ + ch;
    float f = fb[ch];
    float sp = (f > 20.f) ? f : log1pf(expf(f));
    float h = I[idx];
    for (int i = 0; i < CS_; i++) {
        long o = base + (long)i * HH_;
        float a, xin;
        alpha_xin(fg[o], ig[o], xc[o], sp, a, xin);
        h = a * h + xin;
        glu[o] = f2bf(gelu_exact(bf2f(gate[o])) * h);
    }
}

// ---------------------------------------------------------------------------
// launch (round-11 best assignment: gemm_big everywhere except KV)
// ---------------------------------------------------------------------------
static inline long cdivl(long a, long b) { return (a + b - 1) / b; }

extern "C" void kernel_launch(void* const* d_in, const int* in_sizes, int n_in,
                              void* d_out, int out_size, void* d_ws, size_t ws_size,
                              hipStream_t stream)
{
    const float* x_in   = (const float*)d_in[0];
    const float* sn_g   = (const float*)d_in[1];
    const float* q_w    = (const float*)d_in[2];
    const float* kv_w   = (const float*)d_in[3];
    const float* ao_w   = (const float*)d_in[4];
    const float* sgn_g  = (const float*)d_in[5];
    const float* sg_grow   = (const float*)d_in[6];
    const float* sg_shrink = (const float*)d_in[7];
    const float* hn_g   = (const float*)d_in[8];
    const float* h_in_w = (const float*)d_in[9];
    const float* h_conv_w = (const float*)d_in[10];
    const float* h_conv_b = (const float*)d_in[11];
    const float* h_gates_w = (const float*)d_in[12];
    const float* h_gates_b = (const float*)d_in[13];
    const float* h_forget  = (const float*)d_in[14];
    const float* h_out_w   = (const float*)d_in[15];
    const float* hgn_g  = (const float*)d_in[16];
    const float* hg_grow   = (const float*)d_in[17];
    const float* hg_shrink = (const float*)d_in[18];
    float* out = (float*)d_out;

    // ---- workspace layout ----
    char* wsb = (char*)d_ws;
    u16* Wq  = (u16*)wsb;                 // 1,048,576
    u16* Wkv = Wq  + 1048576;             // 262,144
    u16* Wao = Wkv + 262144;              // 1,048,576
    u16* Wsg = Wao + 1048576;             // 4,194,304
    u16* Wss = Wsg + 4194304;             // 2,097,152
    u16* Whi = Wss + 2097152;             // 3,145,728
    u16* Whg = Whi + 3145728;             // 4,718,592
    u16* Who = Whg + 4718592;             // 1,572,864
    u16* Wgg = Who + 1572864;             // 4,194,304
    u16* Wgs = Wgg + 4194304;             // 2,097,152
    char* ab = wsb + 48758784;            // activation arena
    u16*   XN   = (u16*)(ab + 0);                    // [8192,1024] bf16
    char*  S2   = ab + 16777216;
    char*  S3   = ab + 50331648;
    char*  S4   = ab + 75497472;
    char*  S5   = ab + 100663296;
    char*  S6   = ab + 125829120;
    float* PB   = (float*)(ab + 150994944);
    float* LB   = (float*)(ab + 151781376);
    float* IB   = (float*)(ab + 152567808);

    const long M = (long)B_ * T_;   // 8192
    dim3 blk(256);
    dim3 blk5(512);
    const float* NULF = nullptr;
    const u16*   NULB = nullptr;

    // ---- weight conversion (single dispatch) ----
    {
        CvtArgs ca;
        const float* srcs[10] = {q_w, kv_w, ao_w, sg_grow, sg_shrink,
                                 h_in_w, h_gates_w, h_out_w, hg_grow, hg_shrink};
        u16* dsts[10] = {Wq, Wkv, Wao, Wsg, Wss, Whi, Whg, Who, Wgg, Wgs};
        long ns[10] = {1048576, 262144, 1048576, 4194304, 2097152,
                       3145728, 4718592, 1572864, 4194304, 2097152};
        long cum = 0;
        for (int i = 0; i < 10; i++) {
            ca.src[i] = srcs[i]; ca.dst[i] = dsts[i]; ca.cum[i] = cum; cum += ns[i];
        }
        ca.cum[10] = cum;
        cvt_all_kernel<<<dim3(cdivl(cum / 8, 256)), blk, 0, stream>>>(ca);
    }

    // ---- attention sublayer ----
    {
        float* Q  = (float*)S2;                      // [8192,1024] f32
        float* KV = (float*)S3;                      // [8192,256]  f32
        u16*   Kb = (u16*)(S3 + 8388608);            // [B,T,128] bf16
        u16*   Vt = (u16*)(S3 + 10485760);           // [B,128,T] bf16
        u16*   Qb = (u16*)S4;                        // [B,T,HQ,128] bf16
        u16*   AT = (u16*)S5;                        // [8192,1024] bf16
        rmsnorm_kernel<<<dim3(M), blk, 0, stream>>>(x_in, sn_g, XN);
        gemm_big_kernel<0,false><<<dim3(8, 32), blk5, 0, stream>>>(XN, Wq, NULF, NULF, NULB, Q, M, 1024, 1024);
        gemm_bf16_kernel<0,false><<<dim3(2, 64), blk, 0, stream>>>(XN, Wkv, NULF, NULF, NULB, KV, M, 256, 1024);
        rope_bf16_kernel<<<dim3(cdivl((long)B_ * T_ * (HQ_ + 1) * 64, 256)), blk, 0, stream>>>(Q, KV, Qb, Kb);
        vtrans_kernel<<<dim3(T_ / 64, 2, B_), blk, 0, stream>>>(KV, Vt);
        attn_mfma3_kernel<<<dim3(T_ / 64, HQ_, B_), blk, 0, stream>>>(Qb, Kb, Vt, AT);
        gemm_big_kernel<2,false><<<dim3(8, 32), blk5, 0, stream>>>(AT, Wao, NULF, x_in, NULB, out, M, 1024, 1024);
    }

    // ---- MLP 1 ----
    {
        u16* GATE = (u16*)S2;             // [8192,2048] bf16
        rmsnorm_kernel<<<dim3(M), blk, 0, stream>>>(out, sgn_g, XN);
        gemm_big_kernel<0,true><<<dim3(16, 32), blk5, 0, stream>>>(XN, Wsg, NULF, NULF, NULB, GATE, M, 2048, 1024);
        gemm_big_kernel<3,true><<<dim3(16, 32), blk5, 0, stream>>>(XN, Wsg + (size_t)2048 * 1024, NULF, NULF, GATE, GATE, M, 2048, 1024);
        gemm_big_kernel<2,false><<<dim3(8, 32), blk5, 0, stream>>>(GATE, Wss, NULF, out, NULB, out, M, 1024, 2048);
    }

    // ---- hawk ----
    {
        u16* GATEH = (u16*)S2;            // [8192,1536] bf16
        u16* U     = (u16*)S3;            // [8192,1536] bf16 (reused as GLUH)
        u16* XC    = (u16*)S4;            // [8192,1536] bf16
        u16* FG    = (u16*)S5;            // [8192,1536] bf16
        u16* IG    = (u16*)S6;            // [8192,1536] bf16
        rmsnorm_kernel<<<dim3(M), blk, 0, stream>>>(out, hn_g, XN);
        gemm_big_kernel<0,true><<<dim3(12, 32), blk5, 0, stream>>>(XN, Whi, NULF, NULF, NULB, GATEH, M, 1536, 1024);
        gemm_big_kernel<0,true><<<dim3(12, 32), blk5, 0, stream>>>(XN, Whi + (size_t)1536 * 1024, NULF, NULF, NULB, U, M, 1536, 1024);
        conv_kernel<<<dim3(cdivl(M * HH_, 256)), blk, 0, stream>>>(U, h_conv_w, h_conv_b, XC);
        gemm_big_kernel<1,true><<<dim3(12, 32), blk5, 0, stream>>>(XC, Whg, h_gates_b, NULF, NULB, FG, M, 1536, 1536);
        gemm_big_kernel<1,true><<<dim3(12, 32), blk5, 0, stream>>>(XC, Whg + (size_t)1536 * 1536, h_gates_b + 1536, NULF, NULB, IG, M, 1536, 1536);
        scan1_kernel<<<dim3(cdivl((long)B_ * NC_ * HH_, 256)), blk, 0, stream>>>(FG, IG, XC, h_forget, PB, LB);
        scan2_kernel<<<dim3(cdivl((long)B_ * HH_, 256)), blk, 0, stream>>>(PB, LB, IB);
        scan3_kernel<<<dim3(cdivl((long)B_ * NC_ * HH_, 256)), blk, 0, stream>>>(FG, IG, XC, h_forget, IB, GATEH, U);
        gemm_big_kernel<2,false><<<dim3(8, 32), blk5, 0, stream>>>(U, Who, NULF, out, NULB, out, M, 1024, 1536);
    }

    // ---- MLP 2 ----
    {
        u16* GLU = (u16*)S2;              // [8192,2048] bf16
        rmsnorm_kernel<<<dim3(M), blk, 0, stream>>>(out, hgn_g, XN);
        gemm_big_kernel<0,true><<<dim3(16, 32), blk5, 0, stream>>>(XN, Wgg, NULF, NULF, NULB, GLU, M, 2048, 1024);
        gemm_big_kernel<3,true><<<dim3(16, 32), blk5, 0, stream>>>(XN, Wgg + (size_t)2048 * 1024, NULF, NULF, GLU, GLU, M, 2048, 1024);
        gemm_big_kernel<2,false><<<dim3(8, 32), blk5, 0, stream>>>(GLU, Wgs, NULF, out, NULB, out, M, 1024, 2048);
    }
}

// Round 17
// 933.930 us; speedup vs baseline: 1.3225x; 1.0172x over previous
//
#include <hip/hip_runtime.h>
#include <hip/hip_bf16.h>
#include <math.h>

#define B_  2
#define T_  4096
#define D_  1024
#define HD_ 128
#define HQ_ 8
#define W_  1024
#define HH_ 1536
#define HG_ 2048
#define KC_ 4

typedef float  f32x4  __attribute__((ext_vector_type(4)));
typedef float  f32x2  __attribute__((ext_vector_type(2)));
typedef __bf16 bf16x8 __attribute__((ext_vector_type(8)));
typedef unsigned short u16;
typedef unsigned short u16x2 __attribute__((ext_vector_type(2)));
typedef unsigned short u16x4 __attribute__((ext_vector_type(4)));
typedef unsigned short u16x8 __attribute__((ext_vector_type(8)));

__device__ __forceinline__ u16 f2bf(float f) {
    unsigned int u = __builtin_bit_cast(unsigned int, f);
    u += 0x7fffu + ((u >> 16) & 1u);           // RNE
    return (u16)(u >> 16);
}
__device__ __forceinline__ float bf2f(u16 v) {
    unsigned int u = ((unsigned int)v) << 16;
    return __builtin_bit_cast(float, u);
}
__device__ __forceinline__ float gelu_exact(float x) {
    return 0.5f * x * (1.0f + erff(x * 0.70710678118654752f));
}
__device__ __forceinline__ float sigmoidf_(float x) {
    return 1.0f / (1.0f + expf(-x));
}

#define GLOAD16(gp, lp) __builtin_amdgcn_global_load_lds( \
    (const __attribute__((address_space(1))) void*)(gp),  \
    (__attribute__((address_space(3))) void*)(lp), 16, 0, 0)

// ---------------------------------------------------------------------------
// Fused f32 -> bf16 conversion for all 10 weight matrices (1 dispatch).
// ---------------------------------------------------------------------------
struct CvtArgs {
    const float* src[10];
    u16* dst[10];
    long cum[11];
};
__global__ __launch_bounds__(256)
void cvt_all_kernel(CvtArgs a)
{
    long i = ((long)blockIdx.x * 256 + threadIdx.x) * 8;
    if (i >= a.cum[10]) return;
    int seg = 0;
#pragma unroll
    for (int s = 1; s < 10; s++) if (i >= a.cum[s]) seg = s;
    long off = i - a.cum[seg];
    const float* src = a.src[seg];
    u16* dst = a.dst[seg];
    f32x4 x = *(const f32x4*)(src + off);
    f32x4 y = *(const f32x4*)(src + off + 4);
    u16x4 ua, ub;
    ua.x = f2bf(x.x); ua.y = f2bf(x.y); ua.z = f2bf(x.z); ua.w = f2bf(x.w);
    ub.x = f2bf(y.x); ub.y = f2bf(y.y); ub.z = f2bf(y.z); ub.w = f2bf(y.w);
    *(u16x4*)(dst + off) = ua;
    *(u16x4*)(dst + off + 4) = ub;
}

// ---------------------------------------------------------------------------
// bf16 GEMM v4 "big": 256x128 tile, 512 thr = 8 waves (4M x 2N), BK=32,
// triple-buffered LDS (72 KB), counted vmcnt(3), one barrier per K-step.
// T1 XCD chunked swizzle. Used for N=2048 (grid 512 = 2 blocks/CU).
// EPI: 0 none | 1 +bias | 2 +res(f32) | 3 glu: out=gelu(gatebuf)*acc
// ---------------------------------------------------------------------------
template<int EPI, bool OBF>
__global__ __launch_bounds__(512)
void gemm_big_kernel(const u16* __restrict__ A, const u16* __restrict__ Bw,
                     const float* __restrict__ bias, const float* __restrict__ res,
                     const u16* gatebuf, void* outv,
                     int M, int N, int K)
{
    __shared__ u16 lA[3][256 * 32];   // 16 KB each
    __shared__ u16 lB[3][128 * 32];   // 8 KB each
    const int wg0 = blockIdx.x + gridDim.x * blockIdx.y;
    const int cpx = (gridDim.x * gridDim.y) >> 3;
    const int wgs = (wg0 & 7) * cpx + (wg0 >> 3);
    const int n0 = (wgs % gridDim.x) * 128, m0 = (wgs / gridDim.x) * 256;
    const int tid = threadIdx.x, w = tid >> 6, l = tid & 63;
    const int wr = w >> 1, wc = w & 1;
    const int lr = l & 15, lg = l >> 4;

    f32x4 acc[4][4];
#pragma unroll
    for (int i = 0; i < 4; i++)
#pragma unroll
        for (int j = 0; j < 4; j++) acc[i][j] = {0.f, 0.f, 0.f, 0.f};

    const int srow = tid >> 2;
    const int gslot = (((tid) & 3) - ((tid >> 3) & 3)) & 3;
    const u16* gA = A + (long)(m0 + srow) * K + gslot * 8;
    const u16* gB = Bw + (long)(n0 + srow) * K + gslot * 8;
    const int lofs = tid * 8;

#define STAGE_G(buf, kk)                                            \
    {                                                               \
        GLOAD16(gA + (kk),                 &lA[buf][lofs]);         \
        GLOAD16(gA + (long)128 * K + (kk), &lA[buf][4096 + lofs]);  \
        GLOAD16(gB + (kk),                 &lB[buf][lofs]);         \
    }

    const int NT = K >> 5;
    STAGE_G(0, 0);
    STAGE_G(1, 32);

    const int swzr = (lr >> 1) & 3;
    int cur = 0;
    for (int t = 0; t < NT; ++t) {
        if (t == NT - 1) { asm volatile("s_waitcnt vmcnt(0)" ::: "memory"); }
        else             { asm volatile("s_waitcnt vmcnt(3)" ::: "memory"); }
        __builtin_amdgcn_s_barrier();
        __builtin_amdgcn_sched_barrier(0);
        if (t + 2 < NT) {
            int nb = cur + 2; if (nb >= 3) nb -= 3;
            STAGE_G(nb, (t + 2) << 5);
        }
        bf16x8 af[4], bfr[4];
#pragma unroll
        for (int m = 0; m < 4; m++)
            af[m] = *(const bf16x8*)&lA[cur][(wr * 64 + m * 16 + lr) * 32 + (((lg + swzr) & 3) * 8)];
#pragma unroll
        for (int n = 0; n < 4; n++)
            bfr[n] = *(const bf16x8*)&lB[cur][(wc * 64 + n * 16 + lr) * 32 + (((lg + swzr) & 3) * 8)];
        __builtin_amdgcn_s_setprio(1);
#pragma unroll
        for (int m = 0; m < 4; m++)
#pragma unroll
            for (int n = 0; n < 4; n++)
                acc[m][n] = __builtin_amdgcn_mfma_f32_16x16x32_bf16(af[m], bfr[n], acc[m][n], 0, 0, 0);
        __builtin_amdgcn_s_setprio(0);
        cur++; if (cur == 3) cur = 0;
    }
#undef STAGE_G

#pragma unroll
    for (int m = 0; m < 4; m++)
#pragma unroll
        for (int n = 0; n < 4; n++) {
            const int col = n0 + wc * 64 + n * 16 + lr;
            const float bv = (EPI == 1) ? bias[col] : 0.f;
#pragma unroll
            for (int r = 0; r < 4; r++) {
                const int row = m0 + wr * 64 + m * 16 + lg * 4 + r;
                const long idx = (long)row * N + col;
                float v = acc[m][n][r] + bv;
                if (EPI == 2) v += res[idx];
                if (EPI == 3) v = gelu_exact(bf2f(gatebuf[idx])) * v;
                if (OBF) ((u16*)outv)[idx] = f2bf(v);
                else     ((float*)outv)[idx] = v;
            }
        }
}

// ---------------------------------------------------------------------------
// bf16 GEMM v3 (128x128, 256 thr, BK=32, 3-buf 48KB, 3 blocks/CU) with T1
// swizzle. Used for N<=1536 (grids 512-768 = 2-3 blocks/CU -> cross-block
// overlap that the 256x128 tile loses at grid 256).
// ---------------------------------------------------------------------------
template<int EPI, bool OBF>
__global__ __launch_bounds__(256)
void gemm_bf16_kernel(const u16* __restrict__ A, const u16* __restrict__ Bw,
                      const float* __restrict__ bias, const float* __restrict__ res,
                      const u16* gatebuf, void* outv,
                      int M, int N, int K)
{
    __shared__ u16 lA[3][128 * 32];
    __shared__ u16 lB[3][128 * 32];
    const int wg0 = blockIdx.x + gridDim.x * blockIdx.y;
    const int cpx = (gridDim.x * gridDim.y) >> 3;
    const int wgs = (wg0 & 7) * cpx + (wg0 >> 3);
    const int n0 = (wgs % gridDim.x) * 128, m0 = (wgs / gridDim.x) * 128;
    const int tid = threadIdx.x, w = tid >> 6, l = tid & 63;
    const int wr = w >> 1, wc = w & 1, lr = l & 15, lg = l >> 4;

    f32x4 acc[4][4];
#pragma unroll
    for (int i = 0; i < 4; i++)
#pragma unroll
        for (int j = 0; j < 4; j++) acc[i][j] = {0.f, 0.f, 0.f, 0.f};

    const int srow = w * 16 + (l >> 2);
    const int gslot = ((l & 3) - ((l >> 3) & 3)) & 3;
    const u16* gA = A + (long)(m0 + srow) * K + gslot * 8;
    const u16* gB = Bw + (long)(n0 + srow) * K + gslot * 8;
    const int lofs = w * 512 + l * 8;

#define STAGE_G(buf, kk)                                          \
    {                                                             \
        GLOAD16(gA + (kk),                &lA[buf][lofs]);        \
        GLOAD16(gA + (long)64 * K + (kk), &lA[buf][2048 + lofs]); \
        GLOAD16(gB + (kk),                &lB[buf][lofs]);        \
        GLOAD16(gB + (long)64 * K + (kk), &lB[buf][2048 + lofs]); \
    }

    const int NT = K >> 5;
    STAGE_G(0, 0);
    STAGE_G(1, 32);

    const int swzr = (lr >> 1) & 3;
    int cur = 0;
    for (int t = 0; t < NT; ++t) {
        if (t == NT - 1) { asm volatile("s_waitcnt vmcnt(0)" ::: "memory"); }
        else             { asm volatile("s_waitcnt vmcnt(4)" ::: "memory"); }
        __builtin_amdgcn_s_barrier();
        __builtin_amdgcn_sched_barrier(0);
        if (t + 2 < NT) {
            int nb = cur + 2; if (nb >= 3) nb -= 3;
            STAGE_G(nb, (t + 2) << 5);
        }
        bf16x8 af[4], bfr[4];
#pragma unroll
        for (int m = 0; m < 4; m++)
            af[m] = *(const bf16x8*)&lA[cur][(wr * 64 + m * 16 + lr) * 32 + (((lg + swzr) & 3) * 8)];
#pragma unroll
        for (int n = 0; n < 4; n++)
            bfr[n] = *(const bf16x8*)&lB[cur][(wc * 64 + n * 16 + lr) * 32 + (((lg + swzr) & 3) * 8)];
        __builtin_amdgcn_s_setprio(1);
#pragma unroll
        for (int m = 0; m < 4; m++)
#pragma unroll
            for (int n = 0; n < 4; n++)
                acc[m][n] = __builtin_amdgcn_mfma_f32_16x16x32_bf16(af[m], bfr[n], acc[m][n], 0, 0, 0);
        __builtin_amdgcn_s_setprio(0);
        cur++; if (cur == 3) cur = 0;
    }
#undef STAGE_G

#pragma unroll
    for (int m = 0; m < 4; m++)
#pragma unroll
        for (int n = 0; n < 4; n++) {
            const int col = n0 + wc * 64 + n * 16 + lr;
            const float bv = (EPI == 1) ? bias[col] : 0.f;
#pragma unroll
            for (int r = 0; r < 4; r++) {
                const int row = m0 + wr * 64 + m * 16 + lg * 4 + r;
                const long idx = (long)row * N + col;
                float v = acc[m][n][r] + bv;
                if (EPI == 2) v += res[idx];
                if (EPI == 3) v = gelu_exact(bf2f(gatebuf[idx])) * v;
                if (OBF) ((u16*)outv)[idx] = f2bf(v);
                else     ((float*)outv)[idx] = v;
            }
        }
}

// ---------------------------------------------------------------------------
// RMSNorm -> bf16
// ---------------------------------------------------------------------------
__global__ __launch_bounds__(256)
void rmsnorm_kernel(const float* __restrict__ x, const float* __restrict__ g,
                    u16* __restrict__ out)
{
    const long row = blockIdx.x;
    const int tid = threadIdx.x;
    const float* xp = x + row * D_;
    f32x4 v = *(const f32x4*)(xp + tid * 4);
    float ss = v.x * v.x + v.y * v.y + v.z * v.z + v.w * v.w;
#pragma unroll
    for (int o = 1; o < 64; o <<= 1) ss += __shfl_xor(ss, o);
    __shared__ float ps[4];
    if ((tid & 63) == 0) ps[tid >> 6] = ss;
    __syncthreads();
    float tot = ps[0] + ps[1] + ps[2] + ps[3];
    float inv = rsqrtf(tot) * 32.0f;     // sqrt(1024)=32
    f32x4 gv = *(const f32x4*)(g + tid * 4);
    u16x4 o4;
    o4.x = f2bf(gv.x * v.x * inv); o4.y = f2bf(gv.y * v.y * inv);
    o4.z = f2bf(gv.z * v.z * inv); o4.w = f2bf(gv.w * v.w * inv);
    *(u16x4*)(out + row * D_ + tid * 4) = o4;
}

// ---------------------------------------------------------------------------
// RoPE: f32 Q/KV -> bf16 Qb [B,T,HQ,128], Kb [B,T,128]
// ---------------------------------------------------------------------------
__global__ void rope_bf16_kernel(const float* __restrict__ q, const float* __restrict__ kv,
                                 u16* __restrict__ qb, u16* __restrict__ kb)
{
    const long NQ = (long)B_ * T_ * HQ_ * 64;
    const long NK = (long)B_ * T_ * 64;
    long idx = (long)blockIdx.x * blockDim.x + threadIdx.x;
    if (idx >= NQ + NK) return;
    int i; long t; const float* src; u16* dst;
    if (idx < NQ) {
        i = idx & 63;
        long bth = idx >> 6;
        t = (bth / HQ_) % T_;
        src = q + bth * HD_ + 2 * i;
        dst = qb + bth * HD_ + 2 * i;
    } else {
        long k = idx - NQ;
        i = k & 63;
        long bt = k >> 6;
        t = bt % T_;
        src = kv + bt * (2 * HD_) + 2 * i;
        dst = kb + bt * HD_ + 2 * i;
    }
    float freq = exp2f(-(float)i * 0.20762050593046014f);  // log2(1e4)/64
    float ang = (float)t * freq;
    float sn, cs;
    sincosf(ang, &sn, &cs);
    f32x2 xv = *(const f32x2*)src;
    u16x2 yv;
    yv.x = f2bf(xv.x * cs - xv.y * sn);
    yv.y = f2bf(xv.x * sn + xv.y * cs);
    *(u16x2*)dst = yv;
}

// ---------------------------------------------------------------------------
// V transpose: KV f32 [B,T,2,128] (v half) -> Vt bf16 [B,128,T]
// ---------------------------------------------------------------------------
__global__ __launch_bounds__(256)
void vtrans_kernel(const float* __restrict__ kv, u16* __restrict__ vt)
{
    __shared__ float tile[64][65];
    const int t0 = blockIdx.x * 64, d0 = blockIdx.y * 64, b = blockIdx.z;
    const int tid = threadIdx.x;
    {
        const int tl = tid & 63, dg = tid >> 6;
        const float* vp = kv + (((long)b * T_ + t0 + tl) * 2 + 1) * HD_ + d0 + dg * 16;
#pragma unroll
        for (int j = 0; j < 4; j++) {
            f32x4 v = *(const f32x4*)(vp + j * 4);
            tile[dg * 16 + j * 4 + 0][tl] = v.x;
            tile[dg * 16 + j * 4 + 1][tl] = v.y;
            tile[dg * 16 + j * 4 + 2][tl] = v.z;
            tile[dg * 16 + j * 4 + 3][tl] = v.w;
        }
    }
    __syncthreads();
    {
        const int dl = tid >> 2, tg = (tid & 3) * 16;
        u16x8 a, c;
#pragma unroll
        for (int j = 0; j < 8; j++) a[j] = f2bf(tile[dl][tg + j]);
#pragma unroll
        for (int j = 0; j < 8; j++) c[j] = f2bf(tile[dl][tg + 8 + j]);
        u16* dst = vt + ((long)b * HD_ + d0 + dl) * T_ + t0 + tg;
        *(u16x8*)dst = a;
        *(u16x8*)(dst + 8) = c;
    }
}

// ---------------------------------------------------------------------------
// MFMA sliding-window attention v3 (verified best)
// ---------------------------------------------------------------------------
#define PLD 72

__global__ __launch_bounds__(256)
void attn_mfma3_kernel(const u16* __restrict__ qb, const u16* __restrict__ kb,
                       const u16* __restrict__ vt, u16* __restrict__ o)
{
    __shared__ u16 Ksh[2][64 * 128];
    __shared__ u16 Vsh[2][128 * 64];
    __shared__ u16 Psh[4 * 16 * PLD];

    const int qt = blockIdx.x, h = blockIdx.y, b = blockIdx.z;
    const int q0 = qt * 64;
    const int tid = threadIdx.x;
    const int w = tid >> 6, l = tid & 63;
    const int lr = l & 15, lg = l >> 4;

    bf16x8 qfr[4];
    {
        const u16* qp = qb + (((long)b * T_ + q0 + w * 16 + lr) * HQ_ + h) * HD_;
#pragma unroll
        for (int kt = 0; kt < 4; kt++)
            qfr[kt] = *(const bf16x8*)(qp + kt * 32 + lg * 8);
    }

    int oK[4], oV[4];
#pragma unroll
    for (int i = 0; i < 4; i++) {
        int krow = w * 16 + i * 4 + (l >> 4);
        int kc8 = (l & 15) ^ (krow & 7);
        oK[i] = krow * 128 + kc8 * 8;
        int vrow = w * 32 + i * 8 + (l >> 3);
        int vc8 = (l & 7) ^ (vrow & 7);
        oV[i] = vrow * T_ + vc8 * 8;
    }
    const u16* kbase = kb + (long)b * T_ * HD_;
    const u16* vbase = vt + (long)b * HD_ * T_;

    f32x4 oacc[8];
#pragma unroll
    for (int dt = 0; dt < 8; dt++) oacc[dt] = {0.f, 0.f, 0.f, 0.f};
    float mrun[4], srun[4];
#pragma unroll
    for (int r = 0; r < 4; r++) { mrun[r] = -1e30f; srun[r] = 0.f; }

    const int kt_lo = (q0 >= W_) ? (q0 - W_) : 0;
    const int nt = ((q0 - kt_lo) >> 6) + 1;
    const int sw = lr & 7;
    const float scale = 0.08838834764831845f;

#pragma unroll
    for (int i = 0; i < 4; i++) {
        GLOAD16(kbase + (long)kt_lo * HD_ + oK[i], &Ksh[0][w * 2048 + i * 512]);
        GLOAD16(vbase + kt_lo + oV[i], &Vsh[0][w * 2048 + i * 512]);
    }

    for (int t = 0; t < nt; ++t) {
        const int kt0 = kt_lo + t * 64;
        const int cur = t & 1;
        if (t + 1 < nt) {
            const int ktn = kt0 + 64;
#pragma unroll
            for (int i = 0; i < 4; i++) {
                GLOAD16(kbase + (long)ktn * HD_ + oK[i], &Ksh[cur ^ 1][w * 2048 + i * 512]);
                GLOAD16(vbase + ktn + oV[i], &Vsh[cur ^ 1][w * 2048 + i * 512]);
            }
            asm volatile("s_waitcnt vmcnt(8)" ::: "memory");
        } else {
            asm volatile("s_waitcnt vmcnt(0)" ::: "memory");
        }
        __builtin_amdgcn_s_barrier();
        __builtin_amdgcn_sched_barrier(0);

        const u16* Kc = Ksh[cur];
        const u16* Vc = Vsh[cur];

        f32x4 s[4];
        __builtin_amdgcn_s_setprio(1);
#pragma unroll
        for (int ct = 0; ct < 4; ct++) {
            s[ct] = {0.f, 0.f, 0.f, 0.f};
#pragma unroll
            for (int kt = 0; kt < 4; kt++) {
                bf16x8 kf = *(const bf16x8*)&Kc[(ct * 16 + lr) * 128 + (((kt * 4 + lg) ^ sw) * 8)];
                s[ct] = __builtin_amdgcn_mfma_f32_16x16x32_bf16(qfr[kt], kf, s[ct], 0, 0, 0);
            }
        }
        __builtin_amdgcn_s_setprio(0);

        float tmax[4] = {-3e38f, -3e38f, -3e38f, -3e38f};
        if (kt0 == q0) {
#pragma unroll
            for (int ct = 0; ct < 4; ct++) {
                const int kpos = kt0 + ct * 16 + lr;
#pragma unroll
                for (int r = 0; r < 4; r++) {
                    const int qpos = q0 + w * 16 + lg * 4 + r;
                    float v = s[ct][r] * scale;
                    v = (kpos <= qpos) ? v : -3e38f;
                    s[ct][r] = v;
                    tmax[r] = fmaxf(tmax[r], v);
                }
            }
        } else if (kt0 == q0 - W_) {
#pragma unroll
            for (int ct = 0; ct < 4; ct++) {
                const int kpos = kt0 + ct * 16 + lr;
#pragma unroll
                for (int r = 0; r < 4; r++) {
                    const int qpos = q0 + w * 16 + lg * 4 + r;
                    float v = s[ct][r] * scale;
                    v = (kpos + W_ >= qpos) ? v : -3e38f;
                    s[ct][r] = v;
                    tmax[r] = fmaxf(tmax[r], v);
                }
            }
        } else {
#pragma unroll
            for (int ct = 0; ct < 4; ct++)
#pragma unroll
                for (int r = 0; r < 4; r++) {
                    float v = s[ct][r] * scale;
                    s[ct][r] = v;
                    tmax[r] = fmaxf(tmax[r], v);
                }
        }
#pragma unroll
        for (int r = 0; r < 4; r++)
#pragma unroll
            for (int msk = 1; msk < 16; msk <<= 1)
                tmax[r] = fmaxf(tmax[r], __shfl_xor(tmax[r], msk));

        bool defer = (tmax[0] <= mrun[0] + 8.f) && (tmax[1] <= mrun[1] + 8.f) &&
                     (tmax[2] <= mrun[2] + 8.f) && (tmax[3] <= mrun[3] + 8.f);
        if (!__all(defer)) {
            float frv[4];
#pragma unroll
            for (int r = 0; r < 4; r++) {
                float mnew = fmaxf(mrun[r], tmax[r]);
                frv[r] = __expf(mrun[r] - mnew);
                mrun[r] = mnew;
                srun[r] *= frv[r];
            }
#pragma unroll
            for (int dt = 0; dt < 8; dt++) {
                oacc[dt][0] *= frv[0]; oacc[dt][1] *= frv[1];
                oacc[dt][2] *= frv[2]; oacc[dt][3] *= frv[3];
            }
        }

        u16* pw = &Psh[w * 16 * PLD];
        float psum[4] = {0.f, 0.f, 0.f, 0.f};
#pragma unroll
        for (int ct = 0; ct < 4; ct++)
#pragma unroll
            for (int r = 0; r < 4; r++) {
                float p = __expf(s[ct][r] - mrun[r]);
                psum[r] += p;
                pw[(lg * 4 + r) * PLD + ct * 16 + lr] = f2bf(p);
            }
#pragma unroll
        for (int r = 0; r < 4; r++) {
#pragma unroll
            for (int msk = 1; msk < 16; msk <<= 1)
                psum[r] += __shfl_xor(psum[r], msk);
            srun[r] += psum[r];
        }

        asm volatile("s_waitcnt lgkmcnt(0)" ::: "memory");
        bf16x8 pa0 = *(const bf16x8*)&pw[lr * PLD + lg * 8];
        bf16x8 pa1 = *(const bf16x8*)&pw[lr * PLD + 32 + lg * 8];
        __builtin_amdgcn_s_setprio(1);
#pragma unroll
        for (int dt = 0; dt < 8; dt++) {
            bf16x8 vf0 = *(const bf16x8*)&Vc[(dt * 16 + lr) * 64 + ((lg ^ sw) * 8)];
            bf16x8 vf1 = *(const bf16x8*)&Vc[(dt * 16 + lr) * 64 + (((4 + lg) ^ sw) * 8)];
            oacc[dt] = __builtin_amdgcn_mfma_f32_16x16x32_bf16(pa0, vf0, oacc[dt], 0, 0, 0);
            oacc[dt] = __builtin_amdgcn_mfma_f32_16x16x32_bf16(pa1, vf1, oacc[dt], 0, 0, 0);
        }
        __builtin_amdgcn_s_setprio(0);
        __syncthreads();
    }

#pragma unroll
    for (int r = 0; r < 4; r++) {
        const int qpos = q0 + w * 16 + lg * 4 + r;
        float inv = 1.f / srun[r];
        u16* op = o + ((long)b * T_ + qpos) * (HQ_ * HD_) + h * HD_;
#pragma unroll
        for (int dt = 0; dt < 8; dt++)
            op[dt * 16 + lr] = f2bf(oacc[dt][r] * inv);
    }
}

// ---------------------------------------------------------------------------
// Depthwise causal conv K=4 over bf16 u [8192,1536] -> bf16 xc
// ---------------------------------------------------------------------------
__global__ void conv_kernel(const u16* __restrict__ u, const float* __restrict__ w,
                            const float* __restrict__ bias, u16* __restrict__ xc)
{
    long idx = (long)blockIdx.x * blockDim.x + threadIdx.x;
    if (idx >= (long)B_ * T_ * HH_) return;
    int ch = (int)(idx % HH_);
    long row = idx / HH_;
    int t = (int)(row % T_);
    float acc = bias[ch];
#pragma unroll
    for (int k = 0; k < KC_; k++) {
        int ts = t - 3 + k;
        if (ts >= 0) acc += bf2f(u[(row - t + ts) * HH_ + ch]) * w[ch * KC_ + k];
    }
    xc[idx] = f2bf(acc);
}

// ---------------------------------------------------------------------------
// Chunked scan over recomputed (alpha, xin) from bf16 fg/ig/xc.
// ---------------------------------------------------------------------------
#define CS_ 64
#define NC_ (T_ / CS_)

__device__ __forceinline__ void alpha_xin(const u16 fg, const u16 ig, const u16 xc,
                                          float sp, float& a, float& xin)
{
    a = expf(-8.0f * sp * sigmoidf_(bf2f(fg)));
    xin = sqrtf(1.f - a * a + 1e-6f) * sigmoidf_(bf2f(ig)) * bf2f(xc);
}

__global__ void scan1_kernel(const u16* __restrict__ fg, const u16* __restrict__ ig,
                             const u16* __restrict__ xc, const float* __restrict__ fb,
                             float* __restrict__ P, float* __restrict__ L)
{
    long idx = (long)blockIdx.x * blockDim.x + threadIdx.x;
    if (idx >= (long)B_ * NC_ * HH_) return;
    int ch = (int)(idx % HH_);
    int chunk = (int)((idx / HH_) % NC_);
    int b = (int)(idx / ((long)HH_ * NC_));
    long base = ((long)b * T_ + chunk * CS_) * HH_ + ch;
    float f = fb[ch];
    float sp = (f > 20.f) ? f : log1pf(expf(f));
    float p = 1.f, lacc = 0.f;
    for (int i = 0; i < CS_; i++) {
        long o = base + (long)i * HH_;
        float a, xin;
        alpha_xin(fg[o], ig[o], xc[o], sp, a, xin);
        lacc = a * lacc + xin;
        p *= a;
    }
    P[idx] = p; L[idx] = lacc;
}
__global__ void scan2_kernel(const float* __restrict__ P, const float* __restrict__ L,
                             float* __restrict__ I)
{
    long idx = (long)blockIdx.x * blockDim.x + threadIdx.x;
    if (idx >= (long)B_ * HH_) return;
    int ch = (int)(idx % HH_);
    int b = (int)(idx / HH_);
    float init = 0.f;
    for (int c = 0; c < NC_; c++) {
        long o = ((long)b * NC_ + c) * HH_ + ch;
        I[o] = init;
        init = P[o] * init + L[o];
    }
}
__global__ void scan3_kernel(const u16* __restrict__ fg, const u16* __restrict__ ig,
                             const u16* __restrict__ xc, const float* __restrict__ fb,
                             const float* __restrict__ I, const u16* __restrict__ gate,
                             u16* __restrict__ glu)
{
    long idx = (long)blockIdx.x * blockDim.x + threadIdx.x;
    if (idx >= (long)B_ * NC_ * HH_) return;
    int ch = (int)(idx % HH_);
    int chunk = (int)((idx / HH_) % NC_);
    int b = (int)(idx / ((long)HH_ * NC_));
    long base = ((long)b * T_ + chunk * CS_) * HH_ + ch;
    float f = fb[ch];
    float sp = (f > 20.f) ? f : log1pf(expf(f));
    float h = I[idx];
    for (int i = 0; i < CS_; i++) {
        long o = base + (long)i * HH_;
        float a, xin;
        alpha_xin(fg[o], ig[o], xc[o], sp, a, xin);
        h = a * h + xin;
        glu[o] = f2bf(gelu_exact(bf2f(gate[o])) * h);
    }
}

// ---------------------------------------------------------------------------
// launch: N=2048 -> gemm_big (grid 512); N<=1536 -> gemm_bf16 (grid 512-768)
// ---------------------------------------------------------------------------
static inline long cdivl(long a, long b) { return (a + b - 1) / b; }

extern "C" void kernel_launch(void* const* d_in, const int* in_sizes, int n_in,
                              void* d_out, int out_size, void* d_ws, size_t ws_size,
                              hipStream_t stream)
{
    const float* x_in   = (const float*)d_in[0];
    const float* sn_g   = (const float*)d_in[1];
    const float* q_w    = (const float*)d_in[2];
    const float* kv_w   = (const float*)d_in[3];
    const float* ao_w   = (const float*)d_in[4];
    const float* sgn_g  = (const float*)d_in[5];
    const float* sg_grow   = (const float*)d_in[6];
    const float* sg_shrink = (const float*)d_in[7];
    const float* hn_g   = (const float*)d_in[8];
    const float* h_in_w = (const float*)d_in[9];
    const float* h_conv_w = (const float*)d_in[10];
    const float* h_conv_b = (const float*)d_in[11];
    const float* h_gates_w = (const float*)d_in[12];
    const float* h_gates_b = (const float*)d_in[13];
    const float* h_forget  = (const float*)d_in[14];
    const float* h_out_w   = (const float*)d_in[15];
    const float* hgn_g  = (const float*)d_in[16];
    const float* hg_grow   = (const float*)d_in[17];
    const float* hg_shrink = (const float*)d_in[18];
    float* out = (float*)d_out;

    // ---- workspace layout ----
    char* wsb = (char*)d_ws;
    u16* Wq  = (u16*)wsb;                 // 1,048,576
    u16* Wkv = Wq  + 1048576;             // 262,144
    u16* Wao = Wkv + 262144;              // 1,048,576
    u16* Wsg = Wao + 1048576;             // 4,194,304
    u16* Wss = Wsg + 4194304;             // 2,097,152
    u16* Whi = Wss + 2097152;             // 3,145,728
    u16* Whg = Whi + 3145728;             // 4,718,592
    u16* Who = Whg + 4718592;             // 1,572,864
    u16* Wgg = Who + 1572864;             // 4,194,304
    u16* Wgs = Wgg + 4194304;             // 2,097,152
    char* ab = wsb + 48758784;            // activation arena
    u16*   XN   = (u16*)(ab + 0);                    // [8192,1024] bf16
    char*  S2   = ab + 16777216;
    char*  S3   = ab + 50331648;
    char*  S4   = ab + 75497472;
    char*  S5   = ab + 100663296;
    char*  S6   = ab + 125829120;
    float* PB   = (float*)(ab + 150994944);
    float* LB   = (float*)(ab + 151781376);
    float* IB   = (float*)(ab + 152567808);

    const long M = (long)B_ * T_;   // 8192
    dim3 blk(256);
    dim3 blk5(512);
    const float* NULF = nullptr;
    const u16*   NULB = nullptr;

    // ---- weight conversion (single dispatch) ----
    {
        CvtArgs ca;
        const float* srcs[10] = {q_w, kv_w, ao_w, sg_grow, sg_shrink,
                                 h_in_w, h_gates_w, h_out_w, hg_grow, hg_shrink};
        u16* dsts[10] = {Wq, Wkv, Wao, Wsg, Wss, Whi, Whg, Who, Wgg, Wgs};
        long ns[10] = {1048576, 262144, 1048576, 4194304, 2097152,
                       3145728, 4718592, 1572864, 4194304, 2097152};
        long cum = 0;
        for (int i = 0; i < 10; i++) {
            ca.src[i] = srcs[i]; ca.dst[i] = dsts[i]; ca.cum[i] = cum; cum += ns[i];
        }
        ca.cum[10] = cum;
        cvt_all_kernel<<<dim3(cdivl(cum / 8, 256)), blk, 0, stream>>>(ca);
    }

    // ---- attention sublayer ----
    {
        float* Q  = (float*)S2;                      // [8192,1024] f32
        float* KV = (float*)S3;                      // [8192,256]  f32
        u16*   Kb = (u16*)(S3 + 8388608);            // [B,T,128] bf16
        u16*   Vt = (u16*)(S3 + 10485760);           // [B,128,T] bf16
        u16*   Qb = (u16*)S4;                        // [B,T,HQ,128] bf16
        u16*   AT = (u16*)S5;                        // [8192,1024] bf16
        rmsnorm_kernel<<<dim3(M), blk, 0, stream>>>(x_in, sn_g, XN);
        gemm_bf16_kernel<0,false><<<dim3(8, 64), blk, 0, stream>>>(XN, Wq, NULF, NULF, NULB, Q, M, 1024, 1024);
        gemm_bf16_kernel<0,false><<<dim3(2, 64), blk, 0, stream>>>(XN, Wkv, NULF, NULF, NULB, KV, M, 256, 1024);
        rope_bf16_kernel<<<dim3(cdivl((long)B_ * T_ * (HQ_ + 1) * 64, 256)), blk, 0, stream>>>(Q, KV, Qb, Kb);
        vtrans_kernel<<<dim3(T_ / 64, 2, B_), blk, 0, stream>>>(KV, Vt);
        attn_mfma3_kernel<<<dim3(T_ / 64, HQ_, B_), blk, 0, stream>>>(Qb, Kb, Vt, AT);
        gemm_bf16_kernel<2,false><<<dim3(8, 64), blk, 0, stream>>>(AT, Wao, NULF, x_in, NULB, out, M, 1024, 1024);
    }

    // ---- MLP 1 ----
    {
        u16* GATE = (u16*)S2;             // [8192,2048] bf16
        rmsnorm_kernel<<<dim3(M), blk, 0, stream>>>(out, sgn_g, XN);
        gemm_big_kernel<0,true><<<dim3(16, 32), blk5, 0, stream>>>(XN, Wsg, NULF, NULF, NULB, GATE, M, 2048, 1024);
        gemm_big_kernel<3,true><<<dim3(16, 32), blk5, 0, stream>>>(XN, Wsg + (size_t)2048 * 1024, NULF, NULF, GATE, GATE, M, 2048, 1024);
        gemm_bf16_kernel<2,false><<<dim3(8, 64), blk, 0, stream>>>(GATE, Wss, NULF, out, NULB, out, M, 1024, 2048);
    }

    // ---- hawk ----
    {
        u16* GATEH = (u16*)S2;            // [8192,1536] bf16
        u16* U     = (u16*)S3;            // [8192,1536] bf16 (reused as GLUH)
        u16* XC    = (u16*)S4;            // [8192,1536] bf16
        u16* FG    = (u16*)S5;            // [8192,1536] bf16
        u16* IG    = (u16*)S6;            // [8192,1536] bf16
        rmsnorm_kernel<<<dim3(M), blk, 0, stream>>>(out, hn_g, XN);
        gemm_bf16_kernel<0,true><<<dim3(12, 64), blk, 0, stream>>>(XN, Whi, NULF, NULF, NULB, GATEH, M, 1536, 1024);
        gemm_bf16_kernel<0,true><<<dim3(12, 64), blk, 0, stream>>>(XN, Whi + (size_t)1536 * 1024, NULF, NULF, NULB, U, M, 1536, 1024);
        conv_kernel<<<dim3(cdivl(M * HH_, 256)), blk, 0, stream>>>(U, h_conv_w, h_conv_b, XC);
        gemm_bf16_kernel<1,true><<<dim3(12, 64), blk, 0, stream>>>(XC, Whg, h_gates_b, NULF, NULB, FG, M, 1536, 1536);
        gemm_bf16_kernel<1,true><<<dim3(12, 64), blk, 0, stream>>>(XC, Whg + (size_t)1536 * 1536, h_gates_b + 1536, NULF, NULB, IG, M, 1536, 1536);
        scan1_kernel<<<dim3(cdivl((long)B_ * NC_ * HH_, 256)), blk, 0, stream>>>(FG, IG, XC, h_forget, PB, LB);
        scan2_kernel<<<dim3(cdivl((long)B_ * HH_, 256)), blk, 0, stream>>>(PB, LB, IB);
        scan3_kernel<<<dim3(cdivl((long)B_ * NC_ * HH_, 256)), blk, 0, stream>>>(FG, IG, XC, h_forget, IB, GATEH, U);
        gemm_bf16_kernel<2,false><<<dim3(8, 64), blk, 0, stream>>>(U, Who, NULF, out, NULB, out, M, 1024, 1536);
    }

    // ---- MLP 2 ----
    {
        u16* GLU = (u16*)S2;              // [8192,2048] bf16
        rmsnorm_kernel<<<dim3(M), blk, 0, stream>>>(out, hgn_g, XN);
        gemm_big_kernel<0,true><<<dim3(16, 32), blk5, 0, stream>>>(XN, Wgg, NULF, NULF, NULB, GLU, M, 2048, 1024);
        gemm_big_kernel<3,true><<<dim3(16, 32), blk5, 0, stream>>>(XN, Wgg + (size_t)2048 * 1024, NULF, NULF, GLU, GLU, M, 2048, 1024);
        gemm_bf16_kernel<2,false><<<dim3(8, 64), blk, 0, stream>>>(GLU, Wgs, NULF, out, NULB, out, M, 1024, 2048);
    }
}

// Round 18
// 891.033 us; speedup vs baseline: 1.3862x; 1.0481x over previous
//
#include <hip/hip_runtime.h>
#include <hip/hip_bf16.h>
#include <math.h>

#define B_  2
#define T_  4096
#define D_  1024
#define HD_ 128
#define HQ_ 8
#define W_  1024
#define HH_ 1536
#define HG_ 2048
#define KC_ 4

typedef float  f32x4  __attribute__((ext_vector_type(4)));
typedef float  f32x2  __attribute__((ext_vector_type(2)));
typedef __bf16 bf16x8 __attribute__((ext_vector_type(8)));
typedef unsigned short u16;
typedef unsigned short u16x2 __attribute__((ext_vector_type(2)));
typedef unsigned short u16x4 __attribute__((ext_vector_type(4)));
typedef unsigned short u16x8 __attribute__((ext_vector_type(8)));

__device__ __forceinline__ u16 f2bf(float f) {
    unsigned int u = __builtin_bit_cast(unsigned int, f);
    u += 0x7fffu + ((u >> 16) & 1u);           // RNE
    return (u16)(u >> 16);
}
__device__ __forceinline__ float bf2f(u16 v) {
    unsigned int u = ((unsigned int)v) << 16;
    return __builtin_bit_cast(float, u);
}
__device__ __forceinline__ float gelu_exact(float x) {
    return 0.5f * x * (1.0f + erff(x * 0.70710678118654752f));
}
__device__ __forceinline__ float sigmoidf_(float x) {
    return 1.0f / (1.0f + expf(-x));
}

#define GLOAD16(gp, lp) __builtin_amdgcn_global_load_lds( \
    (const __attribute__((address_space(1))) void*)(gp),  \
    (__attribute__((address_space(3))) void*)(lp), 16, 0, 0)

// ---------------------------------------------------------------------------
// Fused f32 -> bf16 conversion for all 10 weight matrices (1 dispatch).
// ---------------------------------------------------------------------------
struct CvtArgs {
    const float* src[10];
    u16* dst[10];
    long cum[11];
};
__global__ __launch_bounds__(256)
void cvt_all_kernel(CvtArgs a)
{
    long i = ((long)blockIdx.x * 256 + threadIdx.x) * 8;
    if (i >= a.cum[10]) return;
    int seg = 0;
#pragma unroll
    for (int s = 1; s < 10; s++) if (i >= a.cum[s]) seg = s;
    long off = i - a.cum[seg];
    const float* src = a.src[seg];
    u16* dst = a.dst[seg];
    f32x4 x = *(const f32x4*)(src + off);
    f32x4 y = *(const f32x4*)(src + off + 4);
    u16x4 ua, ub;
    ua.x = f2bf(x.x); ua.y = f2bf(x.y); ua.z = f2bf(x.z); ua.w = f2bf(x.w);
    ub.x = f2bf(y.x); ub.y = f2bf(y.y); ub.z = f2bf(y.z); ub.w = f2bf(y.w);
    *(u16x4*)(dst + off) = ua;
    *(u16x4*)(dst + off + 4) = ub;
}

// ---------------------------------------------------------------------------
// bf16 GEMM v4 "big": 256x128 tile, 512 thr, BK=32, 3-buf (72 KB),
// counted vmcnt(3), T1 XCD chunked swizzle. For N=2048 grows.
// ---------------------------------------------------------------------------
template<int EPI, bool OBF>
__global__ __launch_bounds__(512)
void gemm_big_kernel(const u16* __restrict__ A, const u16* __restrict__ Bw,
                     const float* __restrict__ bias, const float* __restrict__ res,
                     const u16* gatebuf, void* outv,
                     int M, int N, int K)
{
    __shared__ u16 lA[3][256 * 32];
    __shared__ u16 lB[3][128 * 32];
    const int wg0 = blockIdx.x + gridDim.x * blockIdx.y;
    const int cpx = (gridDim.x * gridDim.y) >> 3;
    const int wgs = (wg0 & 7) * cpx + (wg0 >> 3);
    const int n0 = (wgs % gridDim.x) * 128, m0 = (wgs / gridDim.x) * 256;
    const int tid = threadIdx.x, w = tid >> 6, l = tid & 63;
    const int wr = w >> 1, wc = w & 1;
    const int lr = l & 15, lg = l >> 4;

    f32x4 acc[4][4];
#pragma unroll
    for (int i = 0; i < 4; i++)
#pragma unroll
        for (int j = 0; j < 4; j++) acc[i][j] = {0.f, 0.f, 0.f, 0.f};

    const int srow = tid >> 2;
    const int gslot = (((tid) & 3) - ((tid >> 3) & 3)) & 3;
    const u16* gA = A + (long)(m0 + srow) * K + gslot * 8;
    const u16* gB = Bw + (long)(n0 + srow) * K + gslot * 8;
    const int lofs = tid * 8;

#define STAGE_G(buf, kk)                                            \
    {                                                               \
        GLOAD16(gA + (kk),                 &lA[buf][lofs]);         \
        GLOAD16(gA + (long)128 * K + (kk), &lA[buf][4096 + lofs]);  \
        GLOAD16(gB + (kk),                 &lB[buf][lofs]);         \
    }

    const int NT = K >> 5;
    STAGE_G(0, 0);
    STAGE_G(1, 32);

    const int swzr = (lr >> 1) & 3;
    int cur = 0;
    for (int t = 0; t < NT; ++t) {
        if (t == NT - 1) { asm volatile("s_waitcnt vmcnt(0)" ::: "memory"); }
        else             { asm volatile("s_waitcnt vmcnt(3)" ::: "memory"); }
        __builtin_amdgcn_s_barrier();
        __builtin_amdgcn_sched_barrier(0);
        if (t + 2 < NT) {
            int nb = cur + 2; if (nb >= 3) nb -= 3;
            STAGE_G(nb, (t + 2) << 5);
        }
        bf16x8 af[4], bfr[4];
#pragma unroll
        for (int m = 0; m < 4; m++)
            af[m] = *(const bf16x8*)&lA[cur][(wr * 64 + m * 16 + lr) * 32 + (((lg + swzr) & 3) * 8)];
#pragma unroll
        for (int n = 0; n < 4; n++)
            bfr[n] = *(const bf16x8*)&lB[cur][(wc * 64 + n * 16 + lr) * 32 + (((lg + swzr) & 3) * 8)];
        __builtin_amdgcn_s_setprio(1);
#pragma unroll
        for (int m = 0; m < 4; m++)
#pragma unroll
            for (int n = 0; n < 4; n++)
                acc[m][n] = __builtin_amdgcn_mfma_f32_16x16x32_bf16(af[m], bfr[n], acc[m][n], 0, 0, 0);
        __builtin_amdgcn_s_setprio(0);
        cur++; if (cur == 3) cur = 0;
    }
#undef STAGE_G

#pragma unroll
    for (int m = 0; m < 4; m++)
#pragma unroll
        for (int n = 0; n < 4; n++) {
            const int col = n0 + wc * 64 + n * 16 + lr;
            const float bv = (EPI == 1) ? bias[col] : 0.f;
#pragma unroll
            for (int r = 0; r < 4; r++) {
                const int row = m0 + wr * 64 + m * 16 + lg * 4 + r;
                const long idx = (long)row * N + col;
                float v = acc[m][n][r] + bv;
                if (EPI == 2) v += res[idx];
                if (EPI == 3) v = gelu_exact(bf2f(gatebuf[idx])) * v;
                if (OBF) ((u16*)outv)[idx] = f2bf(v);
                else     ((float*)outv)[idx] = v;
            }
        }
}

// ---------------------------------------------------------------------------
// bf16 GEMM v3 (128x128, 256 thr, BK=32, 3-buf 48KB, 3 blocks/CU) + T1.
// ---------------------------------------------------------------------------
template<int EPI, bool OBF>
__global__ __launch_bounds__(256)
void gemm_bf16_kernel(const u16* __restrict__ A, const u16* __restrict__ Bw,
                      const float* __restrict__ bias, const float* __restrict__ res,
                      const u16* gatebuf, void* outv,
                      int M, int N, int K)
{
    __shared__ u16 lA[3][128 * 32];
    __shared__ u16 lB[3][128 * 32];
    const int wg0 = blockIdx.x + gridDim.x * blockIdx.y;
    const int cpx = (gridDim.x * gridDim.y) >> 3;
    const int wgs = (wg0 & 7) * cpx + (wg0 >> 3);
    const int n0 = (wgs % gridDim.x) * 128, m0 = (wgs / gridDim.x) * 128;
    const int tid = threadIdx.x, w = tid >> 6, l = tid & 63;
    const int wr = w >> 1, wc = w & 1, lr = l & 15, lg = l >> 4;

    f32x4 acc[4][4];
#pragma unroll
    for (int i = 0; i < 4; i++)
#pragma unroll
        for (int j = 0; j < 4; j++) acc[i][j] = {0.f, 0.f, 0.f, 0.f};

    const int srow = w * 16 + (l >> 2);
    const int gslot = ((l & 3) - ((l >> 3) & 3)) & 3;
    const u16* gA = A + (long)(m0 + srow) * K + gslot * 8;
    const u16* gB = Bw + (long)(n0 + srow) * K + gslot * 8;
    const int lofs = w * 512 + l * 8;

#define STAGE_G(buf, kk)                                          \
    {                                                             \
        GLOAD16(gA + (kk),                &lA[buf][lofs]);        \
        GLOAD16(gA + (long)64 * K + (kk), &lA[buf][2048 + lofs]); \
        GLOAD16(gB + (kk),                &lB[buf][lofs]);        \
        GLOAD16(gB + (long)64 * K + (kk), &lB[buf][2048 + lofs]); \
    }

    const int NT = K >> 5;
    STAGE_G(0, 0);
    STAGE_G(1, 32);

    const int swzr = (lr >> 1) & 3;
    int cur = 0;
    for (int t = 0; t < NT; ++t) {
        if (t == NT - 1) { asm volatile("s_waitcnt vmcnt(0)" ::: "memory"); }
        else             { asm volatile("s_waitcnt vmcnt(4)" ::: "memory"); }
        __builtin_amdgcn_s_barrier();
        __builtin_amdgcn_sched_barrier(0);
        if (t + 2 < NT) {
            int nb = cur + 2; if (nb >= 3) nb -= 3;
            STAGE_G(nb, (t + 2) << 5);
        }
        bf16x8 af[4], bfr[4];
#pragma unroll
        for (int m = 0; m < 4; m++)
            af[m] = *(const bf16x8*)&lA[cur][(wr * 64 + m * 16 + lr) * 32 + (((lg + swzr) & 3) * 8)];
#pragma unroll
        for (int n = 0; n < 4; n++)
            bfr[n] = *(const bf16x8*)&lB[cur][(wc * 64 + n * 16 + lr) * 32 + (((lg + swzr) & 3) * 8)];
        __builtin_amdgcn_s_setprio(1);
#pragma unroll
        for (int m = 0; m < 4; m++)
#pragma unroll
            for (int n = 0; n < 4; n++)
                acc[m][n] = __builtin_amdgcn_mfma_f32_16x16x32_bf16(af[m], bfr[n], acc[m][n], 0, 0, 0);
        __builtin_amdgcn_s_setprio(0);
        cur++; if (cur == 3) cur = 0;
    }
#undef STAGE_G

#pragma unroll
    for (int m = 0; m < 4; m++)
#pragma unroll
        for (int n = 0; n < 4; n++) {
            const int col = n0 + wc * 64 + n * 16 + lr;
            const float bv = (EPI == 1) ? bias[col] : 0.f;
#pragma unroll
            for (int r = 0; r < 4; r++) {
                const int row = m0 + wr * 64 + m * 16 + lg * 4 + r;
                const long idx = (long)row * N + col;
                float v = acc[m][n][r] + bv;
                if (EPI == 2) v += res[idx];
                if (EPI == 3) v = gelu_exact(bf2f(gatebuf[idx])) * v;
                if (OBF) ((u16*)outv)[idx] = f2bf(v);
                else     ((float*)outv)[idx] = v;
            }
        }
}

// ---------------------------------------------------------------------------
// RMSNorm -> bf16
// ---------------------------------------------------------------------------
__global__ __launch_bounds__(256)
void rmsnorm_kernel(const float* __restrict__ x, const float* __restrict__ g,
                    u16* __restrict__ out)
{
    const long row = blockIdx.x;
    const int tid = threadIdx.x;
    const float* xp = x + row * D_;
    f32x4 v = *(const f32x4*)(xp + tid * 4);
    float ss = v.x * v.x + v.y * v.y + v.z * v.z + v.w * v.w;
#pragma unroll
    for (int o = 1; o < 64; o <<= 1) ss += __shfl_xor(ss, o);
    __shared__ float ps[4];
    if ((tid & 63) == 0) ps[tid >> 6] = ss;
    __syncthreads();
    float tot = ps[0] + ps[1] + ps[2] + ps[3];
    float inv = rsqrtf(tot) * 32.0f;     // sqrt(1024)=32
    f32x4 gv = *(const f32x4*)(g + tid * 4);
    u16x4 o4;
    o4.x = f2bf(gv.x * v.x * inv); o4.y = f2bf(gv.y * v.y * inv);
    o4.z = f2bf(gv.z * v.z * inv); o4.w = f2bf(gv.w * v.w * inv);
    *(u16x4*)(out + row * D_ + tid * 4) = o4;
}

// ---------------------------------------------------------------------------
// RoPE over merged QKV f32 [B,T,1280] (q cols 0..1023, k 1024..1151):
// writes bf16 Qb [B,T,HQ,128], Kb [B,T,128]
// ---------------------------------------------------------------------------
__global__ void rope_bf16_kernel(const float* __restrict__ qkv,
                                 u16* __restrict__ qb, u16* __restrict__ kb)
{
    const long NQ = (long)B_ * T_ * HQ_ * 64;
    const long NK = (long)B_ * T_ * 64;
    long idx = (long)blockIdx.x * blockDim.x + threadIdx.x;
    if (idx >= NQ + NK) return;
    int i; long t; const float* src; u16* dst;
    if (idx < NQ) {
        i = idx & 63;
        long bth = idx >> 6;         // bt*HQ + h
        long bt = bth >> 3;          // HQ = 8
        int h = (int)(bth & 7);
        t = bt % T_;
        src = qkv + bt * 1280 + h * HD_ + 2 * i;
        dst = qb + bth * HD_ + 2 * i;
    } else {
        long k = idx - NQ;
        i = k & 63;
        long bt = k >> 6;
        t = bt % T_;
        src = qkv + bt * 1280 + 1024 + 2 * i;
        dst = kb + bt * HD_ + 2 * i;
    }
    float freq = exp2f(-(float)i * 0.20762050593046014f);  // log2(1e4)/64
    float ang = (float)t * freq;
    float sn, cs;
    sincosf(ang, &sn, &cs);
    f32x2 xv = *(const f32x2*)src;
    u16x2 yv;
    yv.x = f2bf(xv.x * cs - xv.y * sn);
    yv.y = f2bf(xv.x * sn + xv.y * cs);
    *(u16x2*)dst = yv;
}

// ---------------------------------------------------------------------------
// V transpose: QKV f32 [B,T,1280] (v cols 1152..1279) -> Vt bf16 [B,128,T]
// ---------------------------------------------------------------------------
__global__ __launch_bounds__(256)
void vtrans_kernel(const float* __restrict__ qkv, u16* __restrict__ vt)
{
    __shared__ float tile[64][65];
    const int t0 = blockIdx.x * 64, d0 = blockIdx.y * 64, b = blockIdx.z;
    const int tid = threadIdx.x;
    {
        const int tl = tid & 63, dg = tid >> 6;
        const float* vp = qkv + (long)((long)b * T_ + t0 + tl) * 1280 + 1152 + d0 + dg * 16;
#pragma unroll
        for (int j = 0; j < 4; j++) {
            f32x4 v = *(const f32x4*)(vp + j * 4);
            tile[dg * 16 + j * 4 + 0][tl] = v.x;
            tile[dg * 16 + j * 4 + 1][tl] = v.y;
            tile[dg * 16 + j * 4 + 2][tl] = v.z;
            tile[dg * 16 + j * 4 + 3][tl] = v.w;
        }
    }
    __syncthreads();
    {
        const int dl = tid >> 2, tg = (tid & 3) * 16;
        u16x8 a, c;
#pragma unroll
        for (int j = 0; j < 8; j++) a[j] = f2bf(tile[dl][tg + j]);
#pragma unroll
        for (int j = 0; j < 8; j++) c[j] = f2bf(tile[dl][tg + 8 + j]);
        u16* dst = vt + ((long)b * HD_ + d0 + dl) * T_ + t0 + tg;
        *(u16x8*)dst = a;
        *(u16x8*)(dst + 8) = c;
    }
}

// ---------------------------------------------------------------------------
// MFMA sliding-window attention v6 = v3 + deferred-path shfl elimination:
// tmax reduce only on non-deferred tiles; srun kept as per-thread partial,
// reduced once at the end. Decision logic identical to v3.
// ---------------------------------------------------------------------------
#define PLD 72

__global__ __launch_bounds__(256)
void attn_mfma6_kernel(const u16* __restrict__ qb, const u16* __restrict__ kb,
                       const u16* __restrict__ vt, u16* __restrict__ o)
{
    __shared__ u16 Ksh[2][64 * 128];
    __shared__ u16 Vsh[2][128 * 64];
    __shared__ u16 Psh[4 * 16 * PLD];

    const int qt = blockIdx.x, h = blockIdx.y, b = blockIdx.z;
    const int q0 = qt * 64;
    const int tid = threadIdx.x;
    const int w = tid >> 6, l = tid & 63;
    const int lr = l & 15, lg = l >> 4;

    bf16x8 qfr[4];
    {
        const u16* qp = qb + (((long)b * T_ + q0 + w * 16 + lr) * HQ_ + h) * HD_;
#pragma unroll
        for (int kt = 0; kt < 4; kt++)
            qfr[kt] = *(const bf16x8*)(qp + kt * 32 + lg * 8);
    }

    int oK[4], oV[4];
#pragma unroll
    for (int i = 0; i < 4; i++) {
        int krow = w * 16 + i * 4 + (l >> 4);
        int kc8 = (l & 15) ^ (krow & 7);
        oK[i] = krow * 128 + kc8 * 8;
        int vrow = w * 32 + i * 8 + (l >> 3);
        int vc8 = (l & 7) ^ (vrow & 7);
        oV[i] = vrow * T_ + vc8 * 8;
    }
    const u16* kbase = kb + (long)b * T_ * HD_;
    const u16* vbase = vt + (long)b * HD_ * T_;

    f32x4 oacc[8];
#pragma unroll
    for (int dt = 0; dt < 8; dt++) oacc[dt] = {0.f, 0.f, 0.f, 0.f};
    float mrun[4], srun[4];   // srun = per-thread partial (reduced at end)
#pragma unroll
    for (int r = 0; r < 4; r++) { mrun[r] = -1e30f; srun[r] = 0.f; }

    const int kt_lo = (q0 >= W_) ? (q0 - W_) : 0;
    const int nt = ((q0 - kt_lo) >> 6) + 1;
    const int sw = lr & 7;
    const float scale = 0.08838834764831845f;

#pragma unroll
    for (int i = 0; i < 4; i++) {
        GLOAD16(kbase + (long)kt_lo * HD_ + oK[i], &Ksh[0][w * 2048 + i * 512]);
        GLOAD16(vbase + kt_lo + oV[i], &Vsh[0][w * 2048 + i * 512]);
    }

    for (int t = 0; t < nt; ++t) {
        const int kt0 = kt_lo + t * 64;
        const int cur = t & 1;
        if (t + 1 < nt) {
            const int ktn = kt0 + 64;
#pragma unroll
            for (int i = 0; i < 4; i++) {
                GLOAD16(kbase + (long)ktn * HD_ + oK[i], &Ksh[cur ^ 1][w * 2048 + i * 512]);
                GLOAD16(vbase + ktn + oV[i], &Vsh[cur ^ 1][w * 2048 + i * 512]);
            }
            asm volatile("s_waitcnt vmcnt(8)" ::: "memory");
        } else {
            asm volatile("s_waitcnt vmcnt(0)" ::: "memory");
        }
        __builtin_amdgcn_s_barrier();
        __builtin_amdgcn_sched_barrier(0);

        const u16* Kc = Ksh[cur];
        const u16* Vc = Vsh[cur];

        f32x4 s[4];
        __builtin_amdgcn_s_setprio(1);
#pragma unroll
        for (int ct = 0; ct < 4; ct++) {
            s[ct] = {0.f, 0.f, 0.f, 0.f};
#pragma unroll
            for (int kt = 0; kt < 4; kt++) {
                bf16x8 kf = *(const bf16x8*)&Kc[(ct * 16 + lr) * 128 + (((kt * 4 + lg) ^ sw) * 8)];
                s[ct] = __builtin_amdgcn_mfma_f32_16x16x32_bf16(qfr[kt], kf, s[ct], 0, 0, 0);
            }
        }
        __builtin_amdgcn_s_setprio(0);

        // scale + mask + PER-THREAD max (no reduce yet)
        float tm[4] = {-3e38f, -3e38f, -3e38f, -3e38f};
        if (kt0 == q0) {
#pragma unroll
            for (int ct = 0; ct < 4; ct++) {
                const int kpos = kt0 + ct * 16 + lr;
#pragma unroll
                for (int r = 0; r < 4; r++) {
                    const int qpos = q0 + w * 16 + lg * 4 + r;
                    float v = s[ct][r] * scale;
                    v = (kpos <= qpos) ? v : -3e38f;
                    s[ct][r] = v;
                    tm[r] = fmaxf(tm[r], v);
                }
            }
        } else if (kt0 == q0 - W_) {
#pragma unroll
            for (int ct = 0; ct < 4; ct++) {
                const int kpos = kt0 + ct * 16 + lr;
#pragma unroll
                for (int r = 0; r < 4; r++) {
                    const int qpos = q0 + w * 16 + lg * 4 + r;
                    float v = s[ct][r] * scale;
                    v = (kpos + W_ >= qpos) ? v : -3e38f;
                    s[ct][r] = v;
                    tm[r] = fmaxf(tm[r], v);
                }
            }
        } else {
#pragma unroll
            for (int ct = 0; ct < 4; ct++)
#pragma unroll
                for (int r = 0; r < 4; r++) {
                    float v = s[ct][r] * scale;
                    s[ct][r] = v;
                    tm[r] = fmaxf(tm[r], v);
                }
        }

        // defer decision on per-thread maxes: __all over the wave implies
        // row-max <= mrun+8 for every row (identical decision to v3).
        bool defer = (tm[0] <= mrun[0] + 8.f) && (tm[1] <= mrun[1] + 8.f) &&
                     (tm[2] <= mrun[2] + 8.f) && (tm[3] <= mrun[3] + 8.f);
        if (!__all(defer)) {
            // full row-max reduce only on this rare path
#pragma unroll
            for (int r = 0; r < 4; r++)
#pragma unroll
                for (int msk = 1; msk < 16; msk <<= 1)
                    tm[r] = fmaxf(tm[r], __shfl_xor(tm[r], msk));
            float frv[4];
#pragma unroll
            for (int r = 0; r < 4; r++) {
                float mnew = fmaxf(mrun[r], tm[r]);
                frv[r] = __expf(mrun[r] - mnew);
                mrun[r] = mnew;
                srun[r] *= frv[r];      // partial scales linearly
            }
#pragma unroll
            for (int dt = 0; dt < 8; dt++) {
                oacc[dt][0] *= frv[0]; oacc[dt][1] *= frv[1];
                oacc[dt][2] *= frv[2]; oacc[dt][3] *= frv[3];
            }
        }

        u16* pw = &Psh[w * 16 * PLD];
#pragma unroll
        for (int ct = 0; ct < 4; ct++)
#pragma unroll
            for (int r = 0; r < 4; r++) {
                float p = __expf(s[ct][r] - mrun[r]);
                srun[r] += p;           // per-thread partial, no shfl
                pw[(lg * 4 + r) * PLD + ct * 16 + lr] = f2bf(p);
            }

        asm volatile("s_waitcnt lgkmcnt(0)" ::: "memory");
        bf16x8 pa0 = *(const bf16x8*)&pw[lr * PLD + lg * 8];
        bf16x8 pa1 = *(const bf16x8*)&pw[lr * PLD + 32 + lg * 8];
        __builtin_amdgcn_s_setprio(1);
#pragma unroll
        for (int dt = 0; dt < 8; dt++) {
            bf16x8 vf0 = *(const bf16x8*)&Vc[(dt * 16 + lr) * 64 + ((lg ^ sw) * 8)];
            bf16x8 vf1 = *(const bf16x8*)&Vc[(dt * 16 + lr) * 64 + (((4 + lg) ^ sw) * 8)];
            oacc[dt] = __builtin_amdgcn_mfma_f32_16x16x32_bf16(pa0, vf0, oacc[dt], 0, 0, 0);
            oacc[dt] = __builtin_amdgcn_mfma_f32_16x16x32_bf16(pa1, vf1, oacc[dt], 0, 0, 0);
        }
        __builtin_amdgcn_s_setprio(0);
        __syncthreads();
    }

    // final row-sum reduce (once): row group = 16 lanes (same lg)
#pragma unroll
    for (int r = 0; r < 4; r++)
#pragma unroll
        for (int msk = 1; msk < 16; msk <<= 1)
            srun[r] += __shfl_xor(srun[r], msk);

#pragma unroll
    for (int r = 0; r < 4; r++) {
        const int qpos = q0 + w * 16 + lg * 4 + r;
        float inv = 1.f / srun[r];
        u16* op = o + ((long)b * T_ + qpos) * (HQ_ * HD_) + h * HD_;
#pragma unroll
        for (int dt = 0; dt < 8; dt++)
            op[dt * 16 + lr] = f2bf(oacc[dt][r] * inv);
    }
}

// ---------------------------------------------------------------------------
// Depthwise causal conv K=4 over bf16 u [8192,1536] -> bf16 xc
// ---------------------------------------------------------------------------
__global__ void conv_kernel(const u16* __restrict__ u, const float* __restrict__ w,
                            const float* __restrict__ bias, u16* __restrict__ xc)
{
    long idx = (long)blockIdx.x * blockDim.x + threadIdx.x;
    if (idx >= (long)B_ * T_ * HH_) return;
    int ch = (int)(idx % HH_);
    long row = idx / HH_;
    int t = (int)(row % T_);
    float acc = bias[ch];
#pragma unroll
    for (int k = 0; k < KC_; k++) {
        int ts = t - 3 + k;
        if (ts >= 0) acc += bf2f(u[(row - t + ts) * HH_ + ch]) * w[ch * KC_ + k];
    }
    xc[idx] = f2bf(acc);
}

// ---------------------------------------------------------------------------
// Chunked scan; fg/ig packed in GATES [8192, 3072] (fg cols 0..1535,
// ig cols 1536..3071); xc contiguous [8192,1536].
// ---------------------------------------------------------------------------
#define CS_ 64
#define NC_ (T_ / CS_)

__device__ __forceinline__ void alpha_xin(const u16 fg, const u16 ig, const u16 xc,
                                          float sp, float& a, float& xin)
{
    a = expf(-8.0f * sp * sigmoidf_(bf2f(fg)));
    xin = sqrtf(1.f - a * a + 1e-6f) * sigmoidf_(bf2f(ig)) * bf2f(xc);
}

__global__ void scan1_kernel(const u16* __restrict__ gates,
                             const u16* __restrict__ xc, const float* __restrict__ fb,
                             float* __restrict__ P, float* __restrict__ L)
{
    long idx = (long)blockIdx.x * blockDim.x + threadIdx.x;
    if (idx >= (long)B_ * NC_ * HH_) return;
    int ch = (int)(idx % HH_);
    int chunk = (int)((idx / HH_) % NC_);
    int b = (int)(idx / ((long)HH_ * NC_));
    long row0 = (long)b * T_ + chunk * CS_;
    float f = fb[ch];
    float sp = (f > 20.f) ? f : log1pf(expf(f));
    float p = 1.f, lacc = 0.f;
    for (int i = 0; i < CS_; i++) {
        long rg = (row0 + i) * 3072;
        long rx = (row0 + i) * HH_;
        float a, xin;
        alpha_xin(gates[rg + ch], gates[rg + 1536 + ch], xc[rx + ch], sp, a, xin);
        lacc = a * lacc + xin;
        p *= a;
    }
    P[idx] = p; L[idx] = lacc;
}
__global__ void scan2_kernel(const float* __restrict__ P, const float* __restrict__ L,
                             float* __restrict__ I)
{
    long idx = (long)blockIdx.x * blockDim.x + threadIdx.x;
    if (idx >= (long)B_ * HH_) return;
    int ch = (int)(idx % HH_);
    int b = (int)(idx / HH_);
    float init = 0.f;
    for (int c = 0; c < NC_; c++) {
        long o = ((long)b * NC_ + c) * HH_ + ch;
        I[o] = init;
        init = P[o] * init + L[o];
    }
}
__global__ void scan3_kernel(const u16* __restrict__ gates,
                             const u16* __restrict__ xc, const float* __restrict__ fb,
                             const float* __restrict__ I, const u16* __restrict__ gate,
                             u16* __restrict__ glu)
{
    long idx = (long)blockIdx.x * blockDim.x + threadIdx.x;
    if (idx >= (long)B_ * NC_ * HH_) return;
    int ch = (int)(idx % HH_);
    int chunk = (int)((idx / HH_) % NC_);
    int b = (int)(idx / ((long)HH_ * NC_));
    long row0 = (long)b * T_ + chunk * CS_;
    float f = fb[ch];
    float sp = (f > 20.f) ? f : log1pf(expf(f));
    float h = I[idx];
    for (int i = 0; i < CS_; i++) {
        long rg = (row0 + i) * 3072;
        long rx = (row0 + i) * HH_;
        float a, xin;
        alpha_xin(gates[rg + ch], gates[rg + 1536 + ch], xc[rx + ch], sp, a, xin);
        h = a * h + xin;
        glu[rx + ch] = f2bf(gelu_exact(bf2f(gate[rx + ch])) * h);
    }
}

// ---------------------------------------------------------------------------
// launch
// ---------------------------------------------------------------------------
static inline long cdivl(long a, long b) { return (a + b - 1) / b; }

extern "C" void kernel_launch(void* const* d_in, const int* in_sizes, int n_in,
                              void* d_out, int out_size, void* d_ws, size_t ws_size,
                              hipStream_t stream)
{
    const float* x_in   = (const float*)d_in[0];
    const float* sn_g   = (const float*)d_in[1];
    const float* q_w    = (const float*)d_in[2];
    const float* kv_w   = (const float*)d_in[3];
    const float* ao_w   = (const float*)d_in[4];
    const float* sgn_g  = (const float*)d_in[5];
    const float* sg_grow   = (const float*)d_in[6];
    const float* sg_shrink = (const float*)d_in[7];
    const float* hn_g   = (const float*)d_in[8];
    const float* h_in_w = (const float*)d_in[9];
    const float* h_conv_w = (const float*)d_in[10];
    const float* h_conv_b = (const float*)d_in[11];
    const float* h_gates_w = (const float*)d_in[12];
    const float* h_gates_b = (const float*)d_in[13];
    const float* h_forget  = (const float*)d_in[14];
    const float* h_out_w   = (const float*)d_in[15];
    const float* hgn_g  = (const float*)d_in[16];
    const float* hg_grow   = (const float*)d_in[17];
    const float* hg_shrink = (const float*)d_in[18];
    float* out = (float*)d_out;

    // ---- workspace layout ----
    char* wsb = (char*)d_ws;
    u16* Wq  = (u16*)wsb;                 // 1,048,576  (contig with Wkv -> [1280,1024])
    u16* Wkv = Wq  + 1048576;             // 262,144
    u16* Wao = Wkv + 262144;              // 1,048,576
    u16* Wsg = Wao + 1048576;             // 4,194,304
    u16* Wss = Wsg + 4194304;             // 2,097,152
    u16* Whi = Wss + 2097152;             // 3,145,728
    u16* Whg = Whi + 3145728;             // 4,718,592
    u16* Who = Whg + 4718592;             // 1,572,864
    u16* Wgg = Who + 1572864;             // 4,194,304
    u16* Wgs = Wgg + 4194304;             // 2,097,152
    char* ab = wsb + 48758784;            // activation arena
    u16*   XN   = (u16*)(ab + 0);                    // [8192,1024] bf16
    char*  S2   = ab + 16777216;
    float* PB   = (float*)(ab + 150994944);
    float* LB   = (float*)(ab + 151781376);
    float* IB   = (float*)(ab + 152567808);

    const long M = (long)B_ * T_;   // 8192
    dim3 blk(256);
    dim3 blk5(512);
    const float* NULF = nullptr;
    const u16*   NULB = nullptr;

    // ---- weight conversion (single dispatch) ----
    {
        CvtArgs ca;
        const float* srcs[10] = {q_w, kv_w, ao_w, sg_grow, sg_shrink,
                                 h_in_w, h_gates_w, h_out_w, hg_grow, hg_shrink};
        u16* dsts[10] = {Wq, Wkv, Wao, Wsg, Wss, Whi, Whg, Who, Wgg, Wgs};
        long ns[10] = {1048576, 262144, 1048576, 4194304, 2097152,
                       3145728, 4718592, 1572864, 4194304, 2097152};
        long cum = 0;
        for (int i = 0; i < 10; i++) {
            ca.src[i] = srcs[i]; ca.dst[i] = dsts[i]; ca.cum[i] = cum; cum += ns[i];
        }
        ca.cum[10] = cum;
        cvt_all_kernel<<<dim3(cdivl(cum / 8, 256)), blk, 0, stream>>>(ca);
    }

    // ---- attention sublayer ----
    {
        float* QKV = (float*)(ab + 16777216);        // [8192,1280] f32, 41.94 MB
        u16*   Kb  = (u16*)(ab + 58720256);          // [B,T,128] bf16
        u16*   Vt  = (u16*)(ab + 60817408);          // [B,128,T] bf16
        u16*   Qb  = (u16*)(ab + 62914560);          // [B,T,HQ,128] bf16
        u16*   AT  = (u16*)(ab + 79691776);          // [8192,1024] bf16
        rmsnorm_kernel<<<dim3(M), blk, 0, stream>>>(x_in, sn_g, XN);
        gemm_bf16_kernel<0,false><<<dim3(10, 64), blk, 0, stream>>>(XN, Wq, NULF, NULF, NULB, QKV, M, 1280, 1024);
        rope_bf16_kernel<<<dim3(cdivl((long)B_ * T_ * (HQ_ + 1) * 64, 256)), blk, 0, stream>>>(QKV, Qb, Kb);
        vtrans_kernel<<<dim3(T_ / 64, 2, B_), blk, 0, stream>>>(QKV, Vt);
        attn_mfma6_kernel<<<dim3(T_ / 64, HQ_, B_), blk, 0, stream>>>(Qb, Kb, Vt, AT);
        gemm_bf16_kernel<2,false><<<dim3(8, 64), blk, 0, stream>>>(AT, Wao, NULF, x_in, NULB, out, M, 1024, 1024);
    }

    // ---- MLP 1 ----
    {
        u16* GATE = (u16*)S2;             // [8192,2048] bf16
        rmsnorm_kernel<<<dim3(M), blk, 0, stream>>>(out, sgn_g, XN);
        gemm_big_kernel<0,true><<<dim3(16, 32), blk5, 0, stream>>>(XN, Wsg, NULF, NULF, NULB, GATE, M, 2048, 1024);
        gemm_big_kernel<3,true><<<dim3(16, 32), blk5, 0, stream>>>(XN, Wsg + (size_t)2048 * 1024, NULF, NULF, GATE, GATE, M, 2048, 1024);
        gemm_bf16_kernel<2,false><<<dim3(8, 64), blk, 0, stream>>>(GATE, Wss, NULF, out, NULB, out, M, 1024, 2048);
    }

    // ---- hawk ----
    {
        u16* GATEH = (u16*)(ab + 16777216);   // [8192,1536] bf16, ends 41.94M
        u16* U     = (u16*)(ab + 41943040);   // [8192,1536] -> later GLUH
        u16* XC    = (u16*)(ab + 67108864);   // [8192,1536]
        u16* GATES = (u16*)(ab + 92274688);   // [8192,3072] fg|ig, ends 142.6M
        rmsnorm_kernel<<<dim3(M), blk, 0, stream>>>(out, hn_g, XN);
        gemm_bf16_kernel<0,true><<<dim3(12, 64), blk, 0, stream>>>(XN, Whi, NULF, NULF, NULB, GATEH, M, 1536, 1024);
        gemm_bf16_kernel<0,true><<<dim3(12, 64), blk, 0, stream>>>(XN, Whi + (size_t)1536 * 1024, NULF, NULF, NULB, U, M, 1536, 1024);
        conv_kernel<<<dim3(cdivl(M * HH_, 256)), blk, 0, stream>>>(U, h_conv_w, h_conv_b, XC);
        gemm_bf16_kernel<1,true><<<dim3(24, 64), blk, 0, stream>>>(XC, Whg, h_gates_b, NULF, NULB, GATES, M, 3072, 1536);
        scan1_kernel<<<dim3(cdivl((long)B_ * NC_ * HH_, 256)), blk, 0, stream>>>(GATES, XC, h_forget, PB, LB);
        scan2_kernel<<<dim3(cdivl((long)B_ * HH_, 256)), blk, 0, stream>>>(PB, LB, IB);
        scan3_kernel<<<dim3(cdivl((long)B_ * NC_ * HH_, 256)), blk, 0, stream>>>(GATES, XC, h_forget, IB, GATEH, U);
        gemm_bf16_kernel<2,false><<<dim3(8, 64), blk, 0, stream>>>(U, Who, NULF, out, NULB, out, M, 1024, 1536);
    }

    // ---- MLP 2 ----
    {
        u16* GLU = (u16*)S2;              // [8192,2048] bf16
        rmsnorm_kernel<<<dim3(M), blk, 0, stream>>>(out, hgn_g, XN);
        gemm_big_kernel<0,true><<<dim3(16, 32), blk5, 0, stream>>>(XN, Wgg, NULF, NULF, NULB, GLU, M, 2048, 1024);
        gemm_big_kernel<3,true><<<dim3(16, 32), blk5, 0, stream>>>(XN, Wgg + (size_t)2048 * 1024, NULF, NULF, GLU, GLU, M, 2048, 1024);
        gemm_bf16_kernel<2,false><<<dim3(8, 64), blk, 0, stream>>>(GLU, Wgs, NULF, out, NULB, out, M, 1024, 2048);
    }
}

// Round 19
// 889.916 us; speedup vs baseline: 1.3879x; 1.0013x over previous
//
#include <hip/hip_runtime.h>
#include <hip/hip_bf16.h>
#include <math.h>

#define B_  2
#define T_  4096
#define D_  1024
#define HD_ 128
#define HQ_ 8
#define W_  1024
#define HH_ 1536
#define HG_ 2048
#define KC_ 4

typedef float  f32x4  __attribute__((ext_vector_type(4)));
typedef float  f32x2  __attribute__((ext_vector_type(2)));
typedef __bf16 bf16x8 __attribute__((ext_vector_type(8)));
typedef unsigned short u16;
typedef unsigned short u16x2 __attribute__((ext_vector_type(2)));
typedef unsigned short u16x4 __attribute__((ext_vector_type(4)));
typedef unsigned short u16x8 __attribute__((ext_vector_type(8)));

__device__ __forceinline__ u16 f2bf(float f) {
    unsigned int u = __builtin_bit_cast(unsigned int, f);
    u += 0x7fffu + ((u >> 16) & 1u);           // RNE
    return (u16)(u >> 16);
}
__device__ __forceinline__ float bf2f(u16 v) {
    unsigned int u = ((unsigned int)v) << 16;
    return __builtin_bit_cast(float, u);
}
__device__ __forceinline__ float gelu_exact(float x) {
    return 0.5f * x * (1.0f + erff(x * 0.70710678118654752f));
}
__device__ __forceinline__ float sigmoidf_(float x) {
    return 1.0f / (1.0f + expf(-x));
}

#define GLOAD16(gp, lp) __builtin_amdgcn_global_load_lds( \
    (const __attribute__((address_space(1))) void*)(gp),  \
    (__attribute__((address_space(3))) void*)(lp), 16, 0, 0)

// ---------------------------------------------------------------------------
// Fused f32 -> bf16 conversion for all 10 weight matrices (1 dispatch).
// ---------------------------------------------------------------------------
struct CvtArgs {
    const float* src[10];
    u16* dst[10];
    long cum[11];
};
__global__ __launch_bounds__(256)
void cvt_all_kernel(CvtArgs a)
{
    long i = ((long)blockIdx.x * 256 + threadIdx.x) * 8;
    if (i >= a.cum[10]) return;
    int seg = 0;
#pragma unroll
    for (int s = 1; s < 10; s++) if (i >= a.cum[s]) seg = s;
    long off = i - a.cum[seg];
    const float* src = a.src[seg];
    u16* dst = a.dst[seg];
    f32x4 x = *(const f32x4*)(src + off);
    f32x4 y = *(const f32x4*)(src + off + 4);
    u16x4 ua, ub;
    ua.x = f2bf(x.x); ua.y = f2bf(x.y); ua.z = f2bf(x.z); ua.w = f2bf(x.w);
    ub.x = f2bf(y.x); ub.y = f2bf(y.y); ub.z = f2bf(y.z); ub.w = f2bf(y.w);
    *(u16x4*)(dst + off) = ua;
    *(u16x4*)(dst + off + 4) = ub;
}

// ---------------------------------------------------------------------------
// bf16 GEMM v4 "big": 256x128 tile, 512 thr, BK=32, 3-buf (72 KB),
// counted vmcnt(3), T1 XCD chunked swizzle. For N=2048 grows + gates GEMM.
// ---------------------------------------------------------------------------
template<int EPI, bool OBF>
__global__ __launch_bounds__(512)
void gemm_big_kernel(const u16* __restrict__ A, const u16* __restrict__ Bw,
                     const float* __restrict__ bias, const float* __restrict__ res,
                     const u16* gatebuf, void* outv,
                     int M, int N, int K)
{
    __shared__ u16 lA[3][256 * 32];
    __shared__ u16 lB[3][128 * 32];
    const int wg0 = blockIdx.x + gridDim.x * blockIdx.y;
    const int cpx = (gridDim.x * gridDim.y) >> 3;
    const int wgs = (wg0 & 7) * cpx + (wg0 >> 3);
    const int n0 = (wgs % gridDim.x) * 128, m0 = (wgs / gridDim.x) * 256;
    const int tid = threadIdx.x, w = tid >> 6, l = tid & 63;
    const int wr = w >> 1, wc = w & 1;
    const int lr = l & 15, lg = l >> 4;

    f32x4 acc[4][4];
#pragma unroll
    for (int i = 0; i < 4; i++)
#pragma unroll
        for (int j = 0; j < 4; j++) acc[i][j] = {0.f, 0.f, 0.f, 0.f};

    const int srow = tid >> 2;
    const int gslot = (((tid) & 3) - ((tid >> 3) & 3)) & 3;
    const u16* gA = A + (long)(m0 + srow) * K + gslot * 8;
    const u16* gB = Bw + (long)(n0 + srow) * K + gslot * 8;
    const int lofs = tid * 8;

#define STAGE_G(buf, kk)                                            \
    {                                                               \
        GLOAD16(gA + (kk),                 &lA[buf][lofs]);         \
        GLOAD16(gA + (long)128 * K + (kk), &lA[buf][4096 + lofs]);  \
        GLOAD16(gB + (kk),                 &lB[buf][lofs]);         \
    }

    const int NT = K >> 5;
    STAGE_G(0, 0);
    STAGE_G(1, 32);

    const int swzr = (lr >> 1) & 3;
    int cur = 0;
    for (int t = 0; t < NT; ++t) {
        if (t == NT - 1) { asm volatile("s_waitcnt vmcnt(0)" ::: "memory"); }
        else             { asm volatile("s_waitcnt vmcnt(3)" ::: "memory"); }
        __builtin_amdgcn_s_barrier();
        __builtin_amdgcn_sched_barrier(0);
        if (t + 2 < NT) {
            int nb = cur + 2; if (nb >= 3) nb -= 3;
            STAGE_G(nb, (t + 2) << 5);
        }
        bf16x8 af[4], bfr[4];
#pragma unroll
        for (int m = 0; m < 4; m++)
            af[m] = *(const bf16x8*)&lA[cur][(wr * 64 + m * 16 + lr) * 32 + (((lg + swzr) & 3) * 8)];
#pragma unroll
        for (int n = 0; n < 4; n++)
            bfr[n] = *(const bf16x8*)&lB[cur][(wc * 64 + n * 16 + lr) * 32 + (((lg + swzr) & 3) * 8)];
        __builtin_amdgcn_s_setprio(1);
#pragma unroll
        for (int m = 0; m < 4; m++)
#pragma unroll
            for (int n = 0; n < 4; n++)
                acc[m][n] = __builtin_amdgcn_mfma_f32_16x16x32_bf16(af[m], bfr[n], acc[m][n], 0, 0, 0);
        __builtin_amdgcn_s_setprio(0);
        cur++; if (cur == 3) cur = 0;
    }
#undef STAGE_G

#pragma unroll
    for (int m = 0; m < 4; m++)
#pragma unroll
        for (int n = 0; n < 4; n++) {
            const int col = n0 + wc * 64 + n * 16 + lr;
            const float bv = (EPI == 1) ? bias[col] : 0.f;
#pragma unroll
            for (int r = 0; r < 4; r++) {
                const int row = m0 + wr * 64 + m * 16 + lg * 4 + r;
                const long idx = (long)row * N + col;
                float v = acc[m][n][r] + bv;
                if (EPI == 2) v += res[idx];
                if (EPI == 3) v = gelu_exact(bf2f(gatebuf[idx])) * v;
                if (OBF) ((u16*)outv)[idx] = f2bf(v);
                else     ((float*)outv)[idx] = v;
            }
        }
}

// ---------------------------------------------------------------------------
// bf16 GEMM v3 (128x128, 256 thr, BK=32, 3-buf 48KB, 3 blocks/CU) + T1.
// ---------------------------------------------------------------------------
template<int EPI, bool OBF>
__global__ __launch_bounds__(256)
void gemm_bf16_kernel(const u16* __restrict__ A, const u16* __restrict__ Bw,
                      const float* __restrict__ bias, const float* __restrict__ res,
                      const u16* gatebuf, void* outv,
                      int M, int N, int K)
{
    __shared__ u16 lA[3][128 * 32];
    __shared__ u16 lB[3][128 * 32];
    const int wg0 = blockIdx.x + gridDim.x * blockIdx.y;
    const int cpx = (gridDim.x * gridDim.y) >> 3;
    const int wgs = (wg0 & 7) * cpx + (wg0 >> 3);
    const int n0 = (wgs % gridDim.x) * 128, m0 = (wgs / gridDim.x) * 128;
    const int tid = threadIdx.x, w = tid >> 6, l = tid & 63;
    const int wr = w >> 1, wc = w & 1, lr = l & 15, lg = l >> 4;

    f32x4 acc[4][4];
#pragma unroll
    for (int i = 0; i < 4; i++)
#pragma unroll
        for (int j = 0; j < 4; j++) acc[i][j] = {0.f, 0.f, 0.f, 0.f};

    const int srow = w * 16 + (l >> 2);
    const int gslot = ((l & 3) - ((l >> 3) & 3)) & 3;
    const u16* gA = A + (long)(m0 + srow) * K + gslot * 8;
    const u16* gB = Bw + (long)(n0 + srow) * K + gslot * 8;
    const int lofs = w * 512 + l * 8;

#define STAGE_G(buf, kk)                                          \
    {                                                             \
        GLOAD16(gA + (kk),                &lA[buf][lofs]);        \
        GLOAD16(gA + (long)64 * K + (kk), &lA[buf][2048 + lofs]); \
        GLOAD16(gB + (kk),                &lB[buf][lofs]);        \
        GLOAD16(gB + (long)64 * K + (kk), &lB[buf][2048 + lofs]); \
    }

    const int NT = K >> 5;
    STAGE_G(0, 0);
    STAGE_G(1, 32);

    const int swzr = (lr >> 1) & 3;
    int cur = 0;
    for (int t = 0; t < NT; ++t) {
        if (t == NT - 1) { asm volatile("s_waitcnt vmcnt(0)" ::: "memory"); }
        else             { asm volatile("s_waitcnt vmcnt(4)" ::: "memory"); }
        __builtin_amdgcn_s_barrier();
        __builtin_amdgcn_sched_barrier(0);
        if (t + 2 < NT) {
            int nb = cur + 2; if (nb >= 3) nb -= 3;
            STAGE_G(nb, (t + 2) << 5);
        }
        bf16x8 af[4], bfr[4];
#pragma unroll
        for (int m = 0; m < 4; m++)
            af[m] = *(const bf16x8*)&lA[cur][(wr * 64 + m * 16 + lr) * 32 + (((lg + swzr) & 3) * 8)];
#pragma unroll
        for (int n = 0; n < 4; n++)
            bfr[n] = *(const bf16x8*)&lB[cur][(wc * 64 + n * 16 + lr) * 32 + (((lg + swzr) & 3) * 8)];
        __builtin_amdgcn_s_setprio(1);
#pragma unroll
        for (int m = 0; m < 4; m++)
#pragma unroll
            for (int n = 0; n < 4; n++)
                acc[m][n] = __builtin_amdgcn_mfma_f32_16x16x32_bf16(af[m], bfr[n], acc[m][n], 0, 0, 0);
        __builtin_amdgcn_s_setprio(0);
        cur++; if (cur == 3) cur = 0;
    }
#undef STAGE_G

#pragma unroll
    for (int m = 0; m < 4; m++)
#pragma unroll
        for (int n = 0; n < 4; n++) {
            const int col = n0 + wc * 64 + n * 16 + lr;
            const float bv = (EPI == 1) ? bias[col] : 0.f;
#pragma unroll
            for (int r = 0; r < 4; r++) {
                const int row = m0 + wr * 64 + m * 16 + lg * 4 + r;
                const long idx = (long)row * N + col;
                float v = acc[m][n][r] + bv;
                if (EPI == 2) v += res[idx];
                if (EPI == 3) v = gelu_exact(bf2f(gatebuf[idx])) * v;
                if (OBF) ((u16*)outv)[idx] = f2bf(v);
                else     ((float*)outv)[idx] = v;
            }
        }
}

// ---------------------------------------------------------------------------
// RMSNorm -> bf16
// ---------------------------------------------------------------------------
__global__ __launch_bounds__(256)
void rmsnorm_kernel(const float* __restrict__ x, const float* __restrict__ g,
                    u16* __restrict__ out)
{
    const long row = blockIdx.x;
    const int tid = threadIdx.x;
    const float* xp = x + row * D_;
    f32x4 v = *(const f32x4*)(xp + tid * 4);
    float ss = v.x * v.x + v.y * v.y + v.z * v.z + v.w * v.w;
#pragma unroll
    for (int o = 1; o < 64; o <<= 1) ss += __shfl_xor(ss, o);
    __shared__ float ps[4];
    if ((tid & 63) == 0) ps[tid >> 6] = ss;
    __syncthreads();
    float tot = ps[0] + ps[1] + ps[2] + ps[3];
    float inv = rsqrtf(tot) * 32.0f;     // sqrt(1024)=32
    f32x4 gv = *(const f32x4*)(g + tid * 4);
    u16x4 o4;
    o4.x = f2bf(gv.x * v.x * inv); o4.y = f2bf(gv.y * v.y * inv);
    o4.z = f2bf(gv.z * v.z * inv); o4.w = f2bf(gv.w * v.w * inv);
    *(u16x4*)(out + row * D_ + tid * 4) = o4;
}

// ---------------------------------------------------------------------------
// RoPE over merged bf16 QKV [B,T,1280] (q cols 0..1023, k 1024..1151):
// writes bf16 Qb [B,T,HQ,128], Kb [B,T,128]
// ---------------------------------------------------------------------------
__global__ void rope_bf16_kernel(const u16* __restrict__ qkv,
                                 u16* __restrict__ qb, u16* __restrict__ kb)
{
    const long NQ = (long)B_ * T_ * HQ_ * 64;
    const long NK = (long)B_ * T_ * 64;
    long idx = (long)blockIdx.x * blockDim.x + threadIdx.x;
    if (idx >= NQ + NK) return;
    int i; long t; const u16* src; u16* dst;
    if (idx < NQ) {
        i = idx & 63;
        long bth = idx >> 6;         // bt*HQ + h
        long bt = bth >> 3;          // HQ = 8
        int h = (int)(bth & 7);
        t = bt % T_;
        src = qkv + bt * 1280 + h * HD_ + 2 * i;
        dst = qb + bth * HD_ + 2 * i;
    } else {
        long k = idx - NQ;
        i = k & 63;
        long bt = k >> 6;
        t = bt % T_;
        src = qkv + bt * 1280 + 1024 + 2 * i;
        dst = kb + bt * HD_ + 2 * i;
    }
    float freq = exp2f(-(float)i * 0.20762050593046014f);  // log2(1e4)/64
    float ang = (float)t * freq;
    float sn, cs;
    sincosf(ang, &sn, &cs);
    u16x2 xv = *(const u16x2*)src;
    float x0 = bf2f(xv.x), x1 = bf2f(xv.y);
    u16x2 yv;
    yv.x = f2bf(x0 * cs - x1 * sn);
    yv.y = f2bf(x0 * sn + x1 * cs);
    *(u16x2*)dst = yv;
}

// ---------------------------------------------------------------------------
// V transpose: bf16 QKV [B,T,1280] (v cols 1152..1279) -> Vt bf16 [B,128,T]
// ---------------------------------------------------------------------------
__global__ __launch_bounds__(256)
void vtrans_kernel(const u16* __restrict__ qkv, u16* __restrict__ vt)
{
    __shared__ u16 tile[64][72];
    const int t0 = blockIdx.x * 64, d0 = blockIdx.y * 64, b = blockIdx.z;
    const int tid = threadIdx.x;
    {
        const int tl = tid & 63, dg = tid >> 6;
        const u16* vp = qkv + (long)((long)b * T_ + t0 + tl) * 1280 + 1152 + d0 + dg * 16;
        u16x8 a = *(const u16x8*)vp;
        u16x8 c = *(const u16x8*)(vp + 8);
#pragma unroll
        for (int j = 0; j < 8; j++) tile[dg * 16 + j][tl] = a[j];
#pragma unroll
        for (int j = 0; j < 8; j++) tile[dg * 16 + 8 + j][tl] = c[j];
    }
    __syncthreads();
    {
        const int dl = tid >> 2, tg = (tid & 3) * 16;
        u16x8 a, c;
#pragma unroll
        for (int j = 0; j < 8; j++) a[j] = tile[dl][tg + j];
#pragma unroll
        for (int j = 0; j < 8; j++) c[j] = tile[dl][tg + 8 + j];
        u16* dst = vt + ((long)b * HD_ + d0 + dl) * T_ + t0 + tg;
        *(u16x8*)dst = a;
        *(u16x8*)(dst + 8) = c;
    }
}

// ---------------------------------------------------------------------------
// MFMA sliding-window attention v6 (verified round-18)
// ---------------------------------------------------------------------------
#define PLD 72

__global__ __launch_bounds__(256)
void attn_mfma6_kernel(const u16* __restrict__ qb, const u16* __restrict__ kb,
                       const u16* __restrict__ vt, u16* __restrict__ o)
{
    __shared__ u16 Ksh[2][64 * 128];
    __shared__ u16 Vsh[2][128 * 64];
    __shared__ u16 Psh[4 * 16 * PLD];

    const int qt = blockIdx.x, h = blockIdx.y, b = blockIdx.z;
    const int q0 = qt * 64;
    const int tid = threadIdx.x;
    const int w = tid >> 6, l = tid & 63;
    const int lr = l & 15, lg = l >> 4;

    bf16x8 qfr[4];
    {
        const u16* qp = qb + (((long)b * T_ + q0 + w * 16 + lr) * HQ_ + h) * HD_;
#pragma unroll
        for (int kt = 0; kt < 4; kt++)
            qfr[kt] = *(const bf16x8*)(qp + kt * 32 + lg * 8);
    }

    int oK[4], oV[4];
#pragma unroll
    for (int i = 0; i < 4; i++) {
        int krow = w * 16 + i * 4 + (l >> 4);
        int kc8 = (l & 15) ^ (krow & 7);
        oK[i] = krow * 128 + kc8 * 8;
        int vrow = w * 32 + i * 8 + (l >> 3);
        int vc8 = (l & 7) ^ (vrow & 7);
        oV[i] = vrow * T_ + vc8 * 8;
    }
    const u16* kbase = kb + (long)b * T_ * HD_;
    const u16* vbase = vt + (long)b * HD_ * T_;

    f32x4 oacc[8];
#pragma unroll
    for (int dt = 0; dt < 8; dt++) oacc[dt] = {0.f, 0.f, 0.f, 0.f};
    float mrun[4], srun[4];
#pragma unroll
    for (int r = 0; r < 4; r++) { mrun[r] = -1e30f; srun[r] = 0.f; }

    const int kt_lo = (q0 >= W_) ? (q0 - W_) : 0;
    const int nt = ((q0 - kt_lo) >> 6) + 1;
    const int sw = lr & 7;
    const float scale = 0.08838834764831845f;

#pragma unroll
    for (int i = 0; i < 4; i++) {
        GLOAD16(kbase + (long)kt_lo * HD_ + oK[i], &Ksh[0][w * 2048 + i * 512]);
        GLOAD16(vbase + kt_lo + oV[i], &Vsh[0][w * 2048 + i * 512]);
    }

    for (int t = 0; t < nt; ++t) {
        const int kt0 = kt_lo + t * 64;
        const int cur = t & 1;
        if (t + 1 < nt) {
            const int ktn = kt0 + 64;
#pragma unroll
            for (int i = 0; i < 4; i++) {
                GLOAD16(kbase + (long)ktn * HD_ + oK[i], &Ksh[cur ^ 1][w * 2048 + i * 512]);
                GLOAD16(vbase + ktn + oV[i], &Vsh[cur ^ 1][w * 2048 + i * 512]);
            }
            asm volatile("s_waitcnt vmcnt(8)" ::: "memory");
        } else {
            asm volatile("s_waitcnt vmcnt(0)" ::: "memory");
        }
        __builtin_amdgcn_s_barrier();
        __builtin_amdgcn_sched_barrier(0);

        const u16* Kc = Ksh[cur];
        const u16* Vc = Vsh[cur];

        f32x4 s[4];
        __builtin_amdgcn_s_setprio(1);
#pragma unroll
        for (int ct = 0; ct < 4; ct++) {
            s[ct] = {0.f, 0.f, 0.f, 0.f};
#pragma unroll
            for (int kt = 0; kt < 4; kt++) {
                bf16x8 kf = *(const bf16x8*)&Kc[(ct * 16 + lr) * 128 + (((kt * 4 + lg) ^ sw) * 8)];
                s[ct] = __builtin_amdgcn_mfma_f32_16x16x32_bf16(qfr[kt], kf, s[ct], 0, 0, 0);
            }
        }
        __builtin_amdgcn_s_setprio(0);

        float tm[4] = {-3e38f, -3e38f, -3e38f, -3e38f};
        if (kt0 == q0) {
#pragma unroll
            for (int ct = 0; ct < 4; ct++) {
                const int kpos = kt0 + ct * 16 + lr;
#pragma unroll
                for (int r = 0; r < 4; r++) {
                    const int qpos = q0 + w * 16 + lg * 4 + r;
                    float v = s[ct][r] * scale;
                    v = (kpos <= qpos) ? v : -3e38f;
                    s[ct][r] = v;
                    tm[r] = fmaxf(tm[r], v);
                }
            }
        } else if (kt0 == q0 - W_) {
#pragma unroll
            for (int ct = 0; ct < 4; ct++) {
                const int kpos = kt0 + ct * 16 + lr;
#pragma unroll
                for (int r = 0; r < 4; r++) {
                    const int qpos = q0 + w * 16 + lg * 4 + r;
                    float v = s[ct][r] * scale;
                    v = (kpos + W_ >= qpos) ? v : -3e38f;
                    s[ct][r] = v;
                    tm[r] = fmaxf(tm[r], v);
                }
            }
        } else {
#pragma unroll
            for (int ct = 0; ct < 4; ct++)
#pragma unroll
                for (int r = 0; r < 4; r++) {
                    float v = s[ct][r] * scale;
                    s[ct][r] = v;
                    tm[r] = fmaxf(tm[r], v);
                }
        }

        bool defer = (tm[0] <= mrun[0] + 8.f) && (tm[1] <= mrun[1] + 8.f) &&
                     (tm[2] <= mrun[2] + 8.f) && (tm[3] <= mrun[3] + 8.f);
        if (!__all(defer)) {
#pragma unroll
            for (int r = 0; r < 4; r++)
#pragma unroll
                for (int msk = 1; msk < 16; msk <<= 1)
                    tm[r] = fmaxf(tm[r], __shfl_xor(tm[r], msk));
            float frv[4];
#pragma unroll
            for (int r = 0; r < 4; r++) {
                float mnew = fmaxf(mrun[r], tm[r]);
                frv[r] = __expf(mrun[r] - mnew);
                mrun[r] = mnew;
                srun[r] *= frv[r];
            }
#pragma unroll
            for (int dt = 0; dt < 8; dt++) {
                oacc[dt][0] *= frv[0]; oacc[dt][1] *= frv[1];
                oacc[dt][2] *= frv[2]; oacc[dt][3] *= frv[3];
            }
        }

        u16* pw = &Psh[w * 16 * PLD];
#pragma unroll
        for (int ct = 0; ct < 4; ct++)
#pragma unroll
            for (int r = 0; r < 4; r++) {
                float p = __expf(s[ct][r] - mrun[r]);
                srun[r] += p;
                pw[(lg * 4 + r) * PLD + ct * 16 + lr] = f2bf(p);
            }

        asm volatile("s_waitcnt lgkmcnt(0)" ::: "memory");
        bf16x8 pa0 = *(const bf16x8*)&pw[lr * PLD + lg * 8];
        bf16x8 pa1 = *(const bf16x8*)&pw[lr * PLD + 32 + lg * 8];
        __builtin_amdgcn_s_setprio(1);
#pragma unroll
        for (int dt = 0; dt < 8; dt++) {
            bf16x8 vf0 = *(const bf16x8*)&Vc[(dt * 16 + lr) * 64 + ((lg ^ sw) * 8)];
            bf16x8 vf1 = *(const bf16x8*)&Vc[(dt * 16 + lr) * 64 + (((4 + lg) ^ sw) * 8)];
            oacc[dt] = __builtin_amdgcn_mfma_f32_16x16x32_bf16(pa0, vf0, oacc[dt], 0, 0, 0);
            oacc[dt] = __builtin_amdgcn_mfma_f32_16x16x32_bf16(pa1, vf1, oacc[dt], 0, 0, 0);
        }
        __builtin_amdgcn_s_setprio(0);
        __syncthreads();
    }

#pragma unroll
    for (int r = 0; r < 4; r++)
#pragma unroll
        for (int msk = 1; msk < 16; msk <<= 1)
            srun[r] += __shfl_xor(srun[r], msk);

#pragma unroll
    for (int r = 0; r < 4; r++) {
        const int qpos = q0 + w * 16 + lg * 4 + r;
        float inv = 1.f / srun[r];
        u16* op = o + ((long)b * T_ + qpos) * (HQ_ * HD_) + h * HD_;
#pragma unroll
        for (int dt = 0; dt < 8; dt++)
            op[dt * 16 + lr] = f2bf(oacc[dt][r] * inv);
    }
}

// ---------------------------------------------------------------------------
// Depthwise causal conv K=4 over bf16 u [8192,1536] -> bf16 xc
// ---------------------------------------------------------------------------
__global__ void conv_kernel(const u16* __restrict__ u, const float* __restrict__ w,
                            const float* __restrict__ bias, u16* __restrict__ xc)
{
    long idx = (long)blockIdx.x * blockDim.x + threadIdx.x;
    if (idx >= (long)B_ * T_ * HH_) return;
    int ch = (int)(idx % HH_);
    long row = idx / HH_;
    int t = (int)(row % T_);
    float acc = bias[ch];
#pragma unroll
    for (int k = 0; k < KC_; k++) {
        int ts = t - 3 + k;
        if (ts >= 0) acc += bf2f(u[(row - t + ts) * HH_ + ch]) * w[ch * KC_ + k];
    }
    xc[idx] = f2bf(acc);
}

// ---------------------------------------------------------------------------
// Chunked scan; fg/ig packed in GATES [8192, 3072].
// ---------------------------------------------------------------------------
#define CS_ 64
#define NC_ (T_ / CS_)

__device__ __forceinline__ void alpha_xin(const u16 fg, const u16 ig, const u16 xc,
                                          float sp, float& a, float& xin)
{
    a = expf(-8.0f * sp * sigmoidf_(bf2f(fg)));
    xin = sqrtf(1.f - a * a + 1e-6f) * sigmoidf_(bf2f(ig)) * bf2f(xc);
}

__global__ void scan1_kernel(const u16* __restrict__ gates,
                             const u16* __restrict__ xc, const float* __restrict__ fb,
                             float* __restrict__ P, float* __restrict__ L)
{
    long idx = (long)blockIdx.x * blockDim.x + threadIdx.x;
    if (idx >= (long)B_ * NC_ * HH_) return;
    int ch = (int)(idx % HH_);
    int chunk = (int)((idx / HH_) % NC_);
    int b = (int)(idx / ((long)HH_ * NC_));
    long row0 = (long)b * T_ + chunk * CS_;
    float f = fb[ch];
    float sp = (f > 20.f) ? f : log1pf(expf(f));
    float p = 1.f, lacc = 0.f;
    for (int i = 0; i < CS_; i++) {
        long rg = (row0 + i) * 3072;
        long rx = (row0 + i) * HH_;
        float a, xin;
        alpha_xin(gates[rg + ch], gates[rg + 1536 + ch], xc[rx + ch], sp, a, xin);
        lacc = a * lacc + xin;
        p *= a;
    }
    P[idx] = p; L[idx] = lacc;
}
__global__ void scan2_kernel(const float* __restrict__ P, const float* __restrict__ L,
                             float* __restrict__ I)
{
    long idx = (long)blockIdx.x * blockDim.x + threadIdx.x;
    if (idx >= (long)B_ * HH_) return;
    int ch = (int)(idx % HH_);
    int b = (int)(idx / HH_);
    float init = 0.f;
    for (int c = 0; c < NC_; c++) {
        long o = ((long)b * NC_ + c) * HH_ + ch;
        I[o] = init;
        init = P[o] * init + L[o];
    }
}
__global__ void scan3_kernel(const u16* __restrict__ gates,
                             const u16* __restrict__ xc, const float* __restrict__ fb,
                             const float* __restrict__ I, const u16* __restrict__ gate,
                             u16* __restrict__ glu)
{
    long idx = (long)blockIdx.x * blockDim.x + threadIdx.x;
    if (idx >= (long)B_ * NC_ * HH_) return;
    int ch = (int)(idx % HH_);
    int chunk = (int)((idx / HH_) % NC_);
    int b = (int)(idx / ((long)HH_ * NC_));
    long row0 = (long)b * T_ + chunk * CS_;
    float f = fb[ch];
    float sp = (f > 20.f) ? f : log1pf(expf(f));
    float h = I[idx];
    for (int i = 0; i < CS_; i++) {
        long rg = (row0 + i) * 3072;
        long rx = (row0 + i) * HH_;
        float a, xin;
        alpha_xin(gates[rg + ch], gates[rg + 1536 + ch], xc[rx + ch], sp, a, xin);
        h = a * h + xin;
        glu[rx + ch] = f2bf(gelu_exact(bf2f(gate[rx + ch])) * h);
    }
}

// ---------------------------------------------------------------------------
// launch
// ---------------------------------------------------------------------------
static inline long cdivl(long a, long b) { return (a + b - 1) / b; }

extern "C" void kernel_launch(void* const* d_in, const int* in_sizes, int n_in,
                              void* d_out, int out_size, void* d_ws, size_t ws_size,
                              hipStream_t stream)
{
    const float* x_in   = (const float*)d_in[0];
    const float* sn_g   = (const float*)d_in[1];
    const float* q_w    = (const float*)d_in[2];
    const float* kv_w   = (const float*)d_in[3];
    const float* ao_w   = (const float*)d_in[4];
    const float* sgn_g  = (const float*)d_in[5];
    const float* sg_grow   = (const float*)d_in[6];
    const float* sg_shrink = (const float*)d_in[7];
    const float* hn_g   = (const float*)d_in[8];
    const float* h_in_w = (const float*)d_in[9];
    const float* h_conv_w = (const float*)d_in[10];
    const float* h_conv_b = (const float*)d_in[11];
    const float* h_gates_w = (const float*)d_in[12];
    const float* h_gates_b = (const float*)d_in[13];
    const float* h_forget  = (const float*)d_in[14];
    const float* h_out_w   = (const float*)d_in[15];
    const float* hgn_g  = (const float*)d_in[16];
    const float* hg_grow   = (const float*)d_in[17];
    const float* hg_shrink = (const float*)d_in[18];
    float* out = (float*)d_out;

    // ---- workspace layout ----
    char* wsb = (char*)d_ws;
    u16* Wq  = (u16*)wsb;                 // contig with Wkv -> [1280,1024]
    u16* Wkv = Wq  + 1048576;
    u16* Wao = Wkv + 262144;
    u16* Wsg = Wao + 1048576;
    u16* Wss = Wsg + 4194304;
    u16* Whi = Wss + 2097152;
    u16* Whg = Whi + 3145728;
    u16* Who = Whg + 4718592;
    u16* Wgg = Who + 1572864;
    u16* Wgs = Wgg + 4194304;
    char* ab = wsb + 48758784;            // activation arena
    u16*   XN   = (u16*)(ab + 0);                    // [8192,1024] bf16
    char*  S2   = ab + 16777216;
    float* PB   = (float*)(ab + 150994944);
    float* LB   = (float*)(ab + 151781376);
    float* IB   = (float*)(ab + 152567808);

    const long M = (long)B_ * T_;   // 8192
    dim3 blk(256);
    dim3 blk5(512);
    const float* NULF = nullptr;
    const u16*   NULB = nullptr;

    // ---- weight conversion (single dispatch) ----
    {
        CvtArgs ca;
        const float* srcs[10] = {q_w, kv_w, ao_w, sg_grow, sg_shrink,
                                 h_in_w, h_gates_w, h_out_w, hg_grow, hg_shrink};
        u16* dsts[10] = {Wq, Wkv, Wao, Wsg, Wss, Whi, Whg, Who, Wgg, Wgs};
        long ns[10] = {1048576, 262144, 1048576, 4194304, 2097152,
                       3145728, 4718592, 1572864, 4194304, 2097152};
        long cum = 0;
        for (int i = 0; i < 10; i++) {
            ca.src[i] = srcs[i]; ca.dst[i] = dsts[i]; ca.cum[i] = cum; cum += ns[i];
        }
        ca.cum[10] = cum;
        cvt_all_kernel<<<dim3(cdivl(cum / 8, 256)), blk, 0, stream>>>(ca);
    }

    // ---- attention sublayer ----
    {
        u16*   QKVb = (u16*)(ab + 16777216);         // [8192,1280] bf16, 21 MB
        u16*   Kb   = (u16*)(ab + 58720256);         // [B,T,128] bf16
        u16*   Vt   = (u16*)(ab + 60817408);         // [B,128,T] bf16
        u16*   Qb   = (u16*)(ab + 62914560);         // [B,T,HQ,128] bf16
        u16*   AT   = (u16*)(ab + 79691776);         // [8192,1024] bf16
        rmsnorm_kernel<<<dim3(M), blk, 0, stream>>>(x_in, sn_g, XN);
        gemm_bf16_kernel<0,true><<<dim3(10, 64), blk, 0, stream>>>(XN, Wq, NULF, NULF, NULB, QKVb, M, 1280, 1024);
        rope_bf16_kernel<<<dim3(cdivl((long)B_ * T_ * (HQ_ + 1) * 64, 256)), blk, 0, stream>>>(QKVb, Qb, Kb);
        vtrans_kernel<<<dim3(T_ / 64, 2, B_), blk, 0, stream>>>(QKVb, Vt);
        attn_mfma6_kernel<<<dim3(T_ / 64, HQ_, B_), blk, 0, stream>>>(Qb, Kb, Vt, AT);
        gemm_bf16_kernel<2,false><<<dim3(8, 64), blk, 0, stream>>>(AT, Wao, NULF, x_in, NULB, out, M, 1024, 1024);
    }

    // ---- MLP 1 ----
    {
        u16* GATE = (u16*)S2;             // [8192,2048] bf16
        rmsnorm_kernel<<<dim3(M), blk, 0, stream>>>(out, sgn_g, XN);
        gemm_big_kernel<0,true><<<dim3(16, 32), blk5, 0, stream>>>(XN, Wsg, NULF, NULF, NULB, GATE, M, 2048, 1024);
        gemm_big_kernel<3,true><<<dim3(16, 32), blk5, 0, stream>>>(XN, Wsg + (size_t)2048 * 1024, NULF, NULF, GATE, GATE, M, 2048, 1024);
        gemm_bf16_kernel<2,false><<<dim3(8, 64), blk, 0, stream>>>(GATE, Wss, NULF, out, NULB, out, M, 1024, 2048);
    }

    // ---- hawk ----
    {
        u16* GATEH = (u16*)(ab + 16777216);   // [8192,1536] bf16
        u16* U     = (u16*)(ab + 41943040);   // [8192,1536] -> later GLUH
        u16* XC    = (u16*)(ab + 67108864);   // [8192,1536]
        u16* GATES = (u16*)(ab + 92274688);   // [8192,3072] fg|ig
        rmsnorm_kernel<<<dim3(M), blk, 0, stream>>>(out, hn_g, XN);
        gemm_bf16_kernel<0,true><<<dim3(12, 64), blk, 0, stream>>>(XN, Whi, NULF, NULF, NULB, GATEH, M, 1536, 1024);
        gemm_bf16_kernel<0,true><<<dim3(12, 64), blk, 0, stream>>>(XN, Whi + (size_t)1536 * 1024, NULF, NULF, NULB, U, M, 1536, 1024);
        conv_kernel<<<dim3(cdivl(M * HH_, 256)), blk, 0, stream>>>(U, h_conv_w, h_conv_b, XC);
        gemm_big_kernel<1,true><<<dim3(24, 32), blk5, 0, stream>>>(XC, Whg, h_gates_b, NULF, NULB, GATES, M, 3072, 1536);
        scan1_kernel<<<dim3(cdivl((long)B_ * NC_ * HH_, 256)), blk, 0, stream>>>(GATES, XC, h_forget, PB, LB);
        scan2_kernel<<<dim3(cdivl((long)B_ * HH_, 256)), blk, 0, stream>>>(PB, LB, IB);
        scan3_kernel<<<dim3(cdivl((long)B_ * NC_ * HH_, 256)), blk, 0, stream>>>(GATES, XC, h_forget, IB, GATEH, U);
        gemm_bf16_kernel<2,false><<<dim3(8, 64), blk, 0, stream>>>(U, Who, NULF, out, NULB, out, M, 1024, 1536);
    }

    // ---- MLP 2 ----
    {
        u16* GLU = (u16*)S2;              // [8192,2048] bf16
        rmsnorm_kernel<<<dim3(M), blk, 0, stream>>>(out, hgn_g, XN);
        gemm_big_kernel<0,true><<<dim3(16, 32), blk5, 0, stream>>>(XN, Wgg, NULF, NULF, NULB, GLU, M, 2048, 1024);
        gemm_big_kernel<3,true><<<dim3(16, 32), blk5, 0, stream>>>(XN, Wgg + (size_t)2048 * 1024, NULF, NULF, GLU, GLU, M, 2048, 1024);
        gemm_bf16_kernel<2,false><<<dim3(8, 64), blk, 0, stream>>>(GLU, Wgs, NULF, out, NULB, out, M, 1024, 2048);
    }
}

// Round 20
// 884.168 us; speedup vs baseline: 1.3969x; 1.0065x over previous
//
#include <hip/hip_runtime.h>
#include <hip/hip_bf16.h>
#include <math.h>

#define B_  2
#define T_  4096
#define D_  1024
#define HD_ 128
#define HQ_ 8
#define W_  1024
#define HH_ 1536
#define HG_ 2048
#define KC_ 4

typedef float  f32x4  __attribute__((ext_vector_type(4)));
typedef float  f32x2  __attribute__((ext_vector_type(2)));
typedef __bf16 bf16x8 __attribute__((ext_vector_type(8)));
typedef unsigned short u16;
typedef unsigned short u16x2 __attribute__((ext_vector_type(2)));
typedef unsigned short u16x4 __attribute__((ext_vector_type(4)));
typedef unsigned short u16x8 __attribute__((ext_vector_type(8)));

__device__ __forceinline__ u16 f2bf(float f) {
    unsigned int u = __builtin_bit_cast(unsigned int, f);
    u += 0x7fffu + ((u >> 16) & 1u);           // RNE
    return (u16)(u >> 16);
}
__device__ __forceinline__ float bf2f(u16 v) {
    unsigned int u = ((unsigned int)v) << 16;
    return __builtin_bit_cast(float, u);
}
__device__ __forceinline__ float gelu_exact(float x) {
    return 0.5f * x * (1.0f + erff(x * 0.70710678118654752f));
}
__device__ __forceinline__ float sigmoidf_(float x) {
    return 1.0f / (1.0f + expf(-x));
}

#define GLOAD16(gp, lp) __builtin_amdgcn_global_load_lds( \
    (const __attribute__((address_space(1))) void*)(gp),  \
    (__attribute__((address_space(3))) void*)(lp), 16, 0, 0)

// ---------------------------------------------------------------------------
// Fused f32 -> bf16 conversion for all 10 weight matrices (1 dispatch).
// ---------------------------------------------------------------------------
struct CvtArgs {
    const float* src[10];
    u16* dst[10];
    long cum[11];
};
__global__ __launch_bounds__(256)
void cvt_all_kernel(CvtArgs a)
{
    long i = ((long)blockIdx.x * 256 + threadIdx.x) * 8;
    if (i >= a.cum[10]) return;
    int seg = 0;
#pragma unroll
    for (int s = 1; s < 10; s++) if (i >= a.cum[s]) seg = s;
    long off = i - a.cum[seg];
    const float* src = a.src[seg];
    u16* dst = a.dst[seg];
    f32x4 x = *(const f32x4*)(src + off);
    f32x4 y = *(const f32x4*)(src + off + 4);
    u16x4 ua, ub;
    ua.x = f2bf(x.x); ua.y = f2bf(x.y); ua.z = f2bf(x.z); ua.w = f2bf(x.w);
    ub.x = f2bf(y.x); ub.y = f2bf(y.y); ub.z = f2bf(y.z); ub.w = f2bf(y.w);
    *(u16x4*)(dst + off) = ua;
    *(u16x4*)(dst + off + 4) = ub;
}

// ---------------------------------------------------------------------------
// bf16 GEMM v4 "big": 256x128 tile, 512 thr, BK=32, 3-buf (72 KB),
// counted vmcnt(3), T1 XCD chunked swizzle. N=2048/3072 sites.
// ---------------------------------------------------------------------------
template<int EPI, bool OBF>
__global__ __launch_bounds__(512)
void gemm_big_kernel(const u16* __restrict__ A, const u16* __restrict__ Bw,
                     const float* __restrict__ bias, const float* __restrict__ res,
                     const u16* gatebuf, void* outv,
                     int M, int N, int K)
{
    __shared__ u16 lA[3][256 * 32];
    __shared__ u16 lB[3][128 * 32];
    const int wg0 = blockIdx.x + gridDim.x * blockIdx.y;
    const int cpx = (gridDim.x * gridDim.y) >> 3;
    const int wgs = (wg0 & 7) * cpx + (wg0 >> 3);
    const int n0 = (wgs % gridDim.x) * 128, m0 = (wgs / gridDim.x) * 256;
    const int tid = threadIdx.x, w = tid >> 6, l = tid & 63;
    const int wr = w >> 1, wc = w & 1;
    const int lr = l & 15, lg = l >> 4;

    f32x4 acc[4][4];
#pragma unroll
    for (int i = 0; i < 4; i++)
#pragma unroll
        for (int j = 0; j < 4; j++) acc[i][j] = {0.f, 0.f, 0.f, 0.f};

    const int srow = tid >> 2;
    const int gslot = (((tid) & 3) - ((tid >> 3) & 3)) & 3;
    const u16* gA = A + (long)(m0 + srow) * K + gslot * 8;
    const u16* gB = Bw + (long)(n0 + srow) * K + gslot * 8;
    const int lofs = tid * 8;

#define STAGE_G(buf, kk)                                            \
    {                                                               \
        GLOAD16(gA + (kk),                 &lA[buf][lofs]);         \
        GLOAD16(gA + (long)128 * K + (kk), &lA[buf][4096 + lofs]);  \
        GLOAD16(gB + (kk),                 &lB[buf][lofs]);         \
    }

    const int NT = K >> 5;
    STAGE_G(0, 0);
    STAGE_G(1, 32);

    const int swzr = (lr >> 1) & 3;
    int cur = 0;
    for (int t = 0; t < NT; ++t) {
        if (t == NT - 1) { asm volatile("s_waitcnt vmcnt(0)" ::: "memory"); }
        else             { asm volatile("s_waitcnt vmcnt(3)" ::: "memory"); }
        __builtin_amdgcn_s_barrier();
        __builtin_amdgcn_sched_barrier(0);
        if (t + 2 < NT) {
            int nb = cur + 2; if (nb >= 3) nb -= 3;
            STAGE_G(nb, (t + 2) << 5);
        }
        bf16x8 af[4], bfr[4];
#pragma unroll
        for (int m = 0; m < 4; m++)
            af[m] = *(const bf16x8*)&lA[cur][(wr * 64 + m * 16 + lr) * 32 + (((lg + swzr) & 3) * 8)];
#pragma unroll
        for (int n = 0; n < 4; n++)
            bfr[n] = *(const bf16x8*)&lB[cur][(wc * 64 + n * 16 + lr) * 32 + (((lg + swzr) & 3) * 8)];
        __builtin_amdgcn_s_setprio(1);
#pragma unroll
        for (int m = 0; m < 4; m++)
#pragma unroll
            for (int n = 0; n < 4; n++)
                acc[m][n] = __builtin_amdgcn_mfma_f32_16x16x32_bf16(af[m], bfr[n], acc[m][n], 0, 0, 0);
        __builtin_amdgcn_s_setprio(0);
        cur++; if (cur == 3) cur = 0;
    }
#undef STAGE_G

#pragma unroll
    for (int m = 0; m < 4; m++)
#pragma unroll
        for (int n = 0; n < 4; n++) {
            const int col = n0 + wc * 64 + n * 16 + lr;
            const float bv = (EPI == 1) ? bias[col] : 0.f;
#pragma unroll
            for (int r = 0; r < 4; r++) {
                const int row = m0 + wr * 64 + m * 16 + lg * 4 + r;
                const long idx = (long)row * N + col;
                float v = acc[m][n][r] + bv;
                if (EPI == 2) v += res[idx];
                if (EPI == 3) v = gelu_exact(bf2f(gatebuf[idx])) * v;
                if (OBF) ((u16*)outv)[idx] = f2bf(v);
                else     ((float*)outv)[idx] = v;
            }
        }
}

// ---------------------------------------------------------------------------
// bf16 GEMM v3 (128x128, 256 thr, BK=32, 3-buf 48KB, 3 blocks/CU) + T1.
// lda = A row stride (elements); lda==K for dense A.
// ---------------------------------------------------------------------------
template<int EPI, bool OBF>
__global__ __launch_bounds__(256)
void gemm_bf16_kernel(const u16* __restrict__ A, const u16* __restrict__ Bw,
                      const float* __restrict__ bias, const float* __restrict__ res,
                      const u16* gatebuf, void* outv,
                      int M, int N, int K, int lda)
{
    __shared__ u16 lA[3][128 * 32];
    __shared__ u16 lB[3][128 * 32];
    const int wg0 = blockIdx.x + gridDim.x * blockIdx.y;
    const int cpx = (gridDim.x * gridDim.y) >> 3;
    const int wgs = (wg0 & 7) * cpx + (wg0 >> 3);
    const int n0 = (wgs % gridDim.x) * 128, m0 = (wgs / gridDim.x) * 128;
    const int tid = threadIdx.x, w = tid >> 6, l = tid & 63;
    const int wr = w >> 1, wc = w & 1, lr = l & 15, lg = l >> 4;

    f32x4 acc[4][4];
#pragma unroll
    for (int i = 0; i < 4; i++)
#pragma unroll
        for (int j = 0; j < 4; j++) acc[i][j] = {0.f, 0.f, 0.f, 0.f};

    const int srow = w * 16 + (l >> 2);
    const int gslot = ((l & 3) - ((l >> 3) & 3)) & 3;
    const u16* gA = A + (long)(m0 + srow) * lda + gslot * 8;
    const u16* gB = Bw + (long)(n0 + srow) * K + gslot * 8;
    const int lofs = w * 512 + l * 8;

#define STAGE_G(buf, kk)                                            \
    {                                                               \
        GLOAD16(gA + (kk),                  &lA[buf][lofs]);        \
        GLOAD16(gA + (long)64 * lda + (kk), &lA[buf][2048 + lofs]); \
        GLOAD16(gB + (kk),                  &lB[buf][lofs]);        \
        GLOAD16(gB + (long)64 * K + (kk),   &lB[buf][2048 + lofs]); \
    }

    const int NT = K >> 5;
    STAGE_G(0, 0);
    STAGE_G(1, 32);

    const int swzr = (lr >> 1) & 3;
    int cur = 0;
    for (int t = 0; t < NT; ++t) {
        if (t == NT - 1) { asm volatile("s_waitcnt vmcnt(0)" ::: "memory"); }
        else             { asm volatile("s_waitcnt vmcnt(4)" ::: "memory"); }
        __builtin_amdgcn_s_barrier();
        __builtin_amdgcn_sched_barrier(0);
        if (t + 2 < NT) {
            int nb = cur + 2; if (nb >= 3) nb -= 3;
            STAGE_G(nb, (t + 2) << 5);
        }
        bf16x8 af[4], bfr[4];
#pragma unroll
        for (int m = 0; m < 4; m++)
            af[m] = *(const bf16x8*)&lA[cur][(wr * 64 + m * 16 + lr) * 32 + (((lg + swzr) & 3) * 8)];
#pragma unroll
        for (int n = 0; n < 4; n++)
            bfr[n] = *(const bf16x8*)&lB[cur][(wc * 64 + n * 16 + lr) * 32 + (((lg + swzr) & 3) * 8)];
        __builtin_amdgcn_s_setprio(1);
#pragma unroll
        for (int m = 0; m < 4; m++)
#pragma unroll
            for (int n = 0; n < 4; n++)
                acc[m][n] = __builtin_amdgcn_mfma_f32_16x16x32_bf16(af[m], bfr[n], acc[m][n], 0, 0, 0);
        __builtin_amdgcn_s_setprio(0);
        cur++; if (cur == 3) cur = 0;
    }
#undef STAGE_G

#pragma unroll
    for (int m = 0; m < 4; m++)
#pragma unroll
        for (int n = 0; n < 4; n++) {
            const int col = n0 + wc * 64 + n * 16 + lr;
            const float bv = (EPI == 1) ? bias[col] : 0.f;
#pragma unroll
            for (int r = 0; r < 4; r++) {
                const int row = m0 + wr * 64 + m * 16 + lg * 4 + r;
                const long idx = (long)row * N + col;
                float v = acc[m][n][r] + bv;
                if (EPI == 2) v += res[idx];
                if (EPI == 3) v = gelu_exact(bf2f(gatebuf[idx])) * v;
                if (OBF) ((u16*)outv)[idx] = f2bf(v);
                else     ((float*)outv)[idx] = v;
            }
        }
}

// ---------------------------------------------------------------------------
// RMSNorm -> bf16
// ---------------------------------------------------------------------------
__global__ __launch_bounds__(256)
void rmsnorm_kernel(const float* __restrict__ x, const float* __restrict__ g,
                    u16* __restrict__ out)
{
    const long row = blockIdx.x;
    const int tid = threadIdx.x;
    const float* xp = x + row * D_;
    f32x4 v = *(const f32x4*)(xp + tid * 4);
    float ss = v.x * v.x + v.y * v.y + v.z * v.z + v.w * v.w;
#pragma unroll
    for (int o = 1; o < 64; o <<= 1) ss += __shfl_xor(ss, o);
    __shared__ float ps[4];
    if ((tid & 63) == 0) ps[tid >> 6] = ss;
    __syncthreads();
    float tot = ps[0] + ps[1] + ps[2] + ps[3];
    float inv = rsqrtf(tot) * 32.0f;     // sqrt(1024)=32
    f32x4 gv = *(const f32x4*)(g + tid * 4);
    u16x4 o4;
    o4.x = f2bf(gv.x * v.x * inv); o4.y = f2bf(gv.y * v.y * inv);
    o4.z = f2bf(gv.z * v.z * inv); o4.w = f2bf(gv.w * v.w * inv);
    *(u16x4*)(out + row * D_ + tid * 4) = o4;
}

// ---------------------------------------------------------------------------
// RoPE over merged bf16 QKV [B,T,1280]
// ---------------------------------------------------------------------------
__global__ void rope_bf16_kernel(const u16* __restrict__ qkv,
                                 u16* __restrict__ qb, u16* __restrict__ kb)
{
    const long NQ = (long)B_ * T_ * HQ_ * 64;
    const long NK = (long)B_ * T_ * 64;
    long idx = (long)blockIdx.x * blockDim.x + threadIdx.x;
    if (idx >= NQ + NK) return;
    int i; long t; const u16* src; u16* dst;
    if (idx < NQ) {
        i = idx & 63;
        long bth = idx >> 6;
        long bt = bth >> 3;
        int h = (int)(bth & 7);
        t = bt % T_;
        src = qkv + bt * 1280 + h * HD_ + 2 * i;
        dst = qb + bth * HD_ + 2 * i;
    } else {
        long k = idx - NQ;
        i = k & 63;
        long bt = k >> 6;
        t = bt % T_;
        src = qkv + bt * 1280 + 1024 + 2 * i;
        dst = kb + bt * HD_ + 2 * i;
    }
    float freq = exp2f(-(float)i * 0.20762050593046014f);
    float ang = (float)t * freq;
    float sn, cs;
    sincosf(ang, &sn, &cs);
    u16x2 xv = *(const u16x2*)src;
    float x0 = bf2f(xv.x), x1 = bf2f(xv.y);
    u16x2 yv;
    yv.x = f2bf(x0 * cs - x1 * sn);
    yv.y = f2bf(x0 * sn + x1 * cs);
    *(u16x2*)dst = yv;
}

// ---------------------------------------------------------------------------
// V transpose: bf16 QKV [B,T,1280] (v cols 1152..1279) -> Vt bf16 [B,128,T]
// ---------------------------------------------------------------------------
__global__ __launch_bounds__(256)
void vtrans_kernel(const u16* __restrict__ qkv, u16* __restrict__ vt)
{
    __shared__ u16 tile[64][72];
    const int t0 = blockIdx.x * 64, d0 = blockIdx.y * 64, b = blockIdx.z;
    const int tid = threadIdx.x;
    {
        const int tl = tid & 63, dg = tid >> 6;
        const u16* vp = qkv + (long)((long)b * T_ + t0 + tl) * 1280 + 1152 + d0 + dg * 16;
        u16x8 a = *(const u16x8*)vp;
        u16x8 c = *(const u16x8*)(vp + 8);
#pragma unroll
        for (int j = 0; j < 8; j++) tile[dg * 16 + j][tl] = a[j];
#pragma unroll
        for (int j = 0; j < 8; j++) tile[dg * 16 + 8 + j][tl] = c[j];
    }
    __syncthreads();
    {
        const int dl = tid >> 2, tg = (tid & 3) * 16;
        u16x8 a, c;
#pragma unroll
        for (int j = 0; j < 8; j++) a[j] = tile[dl][tg + j];
#pragma unroll
        for (int j = 0; j < 8; j++) c[j] = tile[dl][tg + 8 + j];
        u16* dst = vt + ((long)b * HD_ + d0 + dl) * T_ + t0 + tg;
        *(u16x8*)dst = a;
        *(u16x8*)(dst + 8) = c;
    }
}

// ---------------------------------------------------------------------------
// MFMA sliding-window attention v6 (verified)
// ---------------------------------------------------------------------------
#define PLD 72

__global__ __launch_bounds__(256)
void attn_mfma6_kernel(const u16* __restrict__ qb, const u16* __restrict__ kb,
                       const u16* __restrict__ vt, u16* __restrict__ o)
{
    __shared__ u16 Ksh[2][64 * 128];
    __shared__ u16 Vsh[2][128 * 64];
    __shared__ u16 Psh[4 * 16 * PLD];

    const int qt = blockIdx.x, h = blockIdx.y, b = blockIdx.z;
    const int q0 = qt * 64;
    const int tid = threadIdx.x;
    const int w = tid >> 6, l = tid & 63;
    const int lr = l & 15, lg = l >> 4;

    bf16x8 qfr[4];
    {
        const u16* qp = qb + (((long)b * T_ + q0 + w * 16 + lr) * HQ_ + h) * HD_;
#pragma unroll
        for (int kt = 0; kt < 4; kt++)
            qfr[kt] = *(const bf16x8*)(qp + kt * 32 + lg * 8);
    }

    int oK[4], oV[4];
#pragma unroll
    for (int i = 0; i < 4; i++) {
        int krow = w * 16 + i * 4 + (l >> 4);
        int kc8 = (l & 15) ^ (krow & 7);
        oK[i] = krow * 128 + kc8 * 8;
        int vrow = w * 32 + i * 8 + (l >> 3);
        int vc8 = (l & 7) ^ (vrow & 7);
        oV[i] = vrow * T_ + vc8 * 8;
    }
    const u16* kbase = kb + (long)b * T_ * HD_;
    const u16* vbase = vt + (long)b * HD_ * T_;

    f32x4 oacc[8];
#pragma unroll
    for (int dt = 0; dt < 8; dt++) oacc[dt] = {0.f, 0.f, 0.f, 0.f};
    float mrun[4], srun[4];
#pragma unroll
    for (int r = 0; r < 4; r++) { mrun[r] = -1e30f; srun[r] = 0.f; }

    const int kt_lo = (q0 >= W_) ? (q0 - W_) : 0;
    const int nt = ((q0 - kt_lo) >> 6) + 1;
    const int sw = lr & 7;
    const float scale = 0.08838834764831845f;

#pragma unroll
    for (int i = 0; i < 4; i++) {
        GLOAD16(kbase + (long)kt_lo * HD_ + oK[i], &Ksh[0][w * 2048 + i * 512]);
        GLOAD16(vbase + kt_lo + oV[i], &Vsh[0][w * 2048 + i * 512]);
    }

    for (int t = 0; t < nt; ++t) {
        const int kt0 = kt_lo + t * 64;
        const int cur = t & 1;
        if (t + 1 < nt) {
            const int ktn = kt0 + 64;
#pragma unroll
            for (int i = 0; i < 4; i++) {
                GLOAD16(kbase + (long)ktn * HD_ + oK[i], &Ksh[cur ^ 1][w * 2048 + i * 512]);
                GLOAD16(vbase + ktn + oV[i], &Vsh[cur ^ 1][w * 2048 + i * 512]);
            }
            asm volatile("s_waitcnt vmcnt(8)" ::: "memory");
        } else {
            asm volatile("s_waitcnt vmcnt(0)" ::: "memory");
        }
        __builtin_amdgcn_s_barrier();
        __builtin_amdgcn_sched_barrier(0);

        const u16* Kc = Ksh[cur];
        const u16* Vc = Vsh[cur];

        f32x4 s[4];
        __builtin_amdgcn_s_setprio(1);
#pragma unroll
        for (int ct = 0; ct < 4; ct++) {
            s[ct] = {0.f, 0.f, 0.f, 0.f};
#pragma unroll
            for (int kt = 0; kt < 4; kt++) {
                bf16x8 kf = *(const bf16x8*)&Kc[(ct * 16 + lr) * 128 + (((kt * 4 + lg) ^ sw) * 8)];
                s[ct] = __builtin_amdgcn_mfma_f32_16x16x32_bf16(qfr[kt], kf, s[ct], 0, 0, 0);
            }
        }
        __builtin_amdgcn_s_setprio(0);

        float tm[4] = {-3e38f, -3e38f, -3e38f, -3e38f};
        if (kt0 == q0) {
#pragma unroll
            for (int ct = 0; ct < 4; ct++) {
                const int kpos = kt0 + ct * 16 + lr;
#pragma unroll
                for (int r = 0; r < 4; r++) {
                    const int qpos = q0 + w * 16 + lg * 4 + r;
                    float v = s[ct][r] * scale;
                    v = (kpos <= qpos) ? v : -3e38f;
                    s[ct][r] = v;
                    tm[r] = fmaxf(tm[r], v);
                }
            }
        } else if (kt0 == q0 - W_) {
#pragma unroll
            for (int ct = 0; ct < 4; ct++) {
                const int kpos = kt0 + ct * 16 + lr;
#pragma unroll
                for (int r = 0; r < 4; r++) {
                    const int qpos = q0 + w * 16 + lg * 4 + r;
                    float v = s[ct][r] * scale;
                    v = (kpos + W_ >= qpos) ? v : -3e38f;
                    s[ct][r] = v;
                    tm[r] = fmaxf(tm[r], v);
                }
            }
        } else {
#pragma unroll
            for (int ct = 0; ct < 4; ct++)
#pragma unroll
                for (int r = 0; r < 4; r++) {
                    float v = s[ct][r] * scale;
                    s[ct][r] = v;
                    tm[r] = fmaxf(tm[r], v);
                }
        }

        bool defer = (tm[0] <= mrun[0] + 8.f) && (tm[1] <= mrun[1] + 8.f) &&
                     (tm[2] <= mrun[2] + 8.f) && (tm[3] <= mrun[3] + 8.f);
        if (!__all(defer)) {
#pragma unroll
            for (int r = 0; r < 4; r++)
#pragma unroll
                for (int msk = 1; msk < 16; msk <<= 1)
                    tm[r] = fmaxf(tm[r], __shfl_xor(tm[r], msk));
            float frv[4];
#pragma unroll
            for (int r = 0; r < 4; r++) {
                float mnew = fmaxf(mrun[r], tm[r]);
                frv[r] = __expf(mrun[r] - mnew);
                mrun[r] = mnew;
                srun[r] *= frv[r];
            }
#pragma unroll
            for (int dt = 0; dt < 8; dt++) {
                oacc[dt][0] *= frv[0]; oacc[dt][1] *= frv[1];
                oacc[dt][2] *= frv[2]; oacc[dt][3] *= frv[3];
            }
        }

        u16* pw = &Psh[w * 16 * PLD];
#pragma unroll
        for (int ct = 0; ct < 4; ct++)
#pragma unroll
            for (int r = 0; r < 4; r++) {
                float p = __expf(s[ct][r] - mrun[r]);
                srun[r] += p;
                pw[(lg * 4 + r) * PLD + ct * 16 + lr] = f2bf(p);
            }

        asm volatile("s_waitcnt lgkmcnt(0)" ::: "memory");
        bf16x8 pa0 = *(const bf16x8*)&pw[lr * PLD + lg * 8];
        bf16x8 pa1 = *(const bf16x8*)&pw[lr * PLD + 32 + lg * 8];
        __builtin_amdgcn_s_setprio(1);
#pragma unroll
        for (int dt = 0; dt < 8; dt++) {
            bf16x8 vf0 = *(const bf16x8*)&Vc[(dt * 16 + lr) * 64 + ((lg ^ sw) * 8)];
            bf16x8 vf1 = *(const bf16x8*)&Vc[(dt * 16 + lr) * 64 + (((4 + lg) ^ sw) * 8)];
            oacc[dt] = __builtin_amdgcn_mfma_f32_16x16x32_bf16(pa0, vf0, oacc[dt], 0, 0, 0);
            oacc[dt] = __builtin_amdgcn_mfma_f32_16x16x32_bf16(pa1, vf1, oacc[dt], 0, 0, 0);
        }
        __builtin_amdgcn_s_setprio(0);
        __syncthreads();
    }

#pragma unroll
    for (int r = 0; r < 4; r++)
#pragma unroll
        for (int msk = 1; msk < 16; msk <<= 1)
            srun[r] += __shfl_xor(srun[r], msk);

#pragma unroll
    for (int r = 0; r < 4; r++) {
        const int qpos = q0 + w * 16 + lg * 4 + r;
        float inv = 1.f / srun[r];
        u16* op = o + ((long)b * T_ + qpos) * (HQ_ * HD_) + h * HD_;
#pragma unroll
        for (int dt = 0; dt < 8; dt++)
            op[dt * 16 + lr] = f2bf(oacc[dt][r] * inv);
    }
}

// ---------------------------------------------------------------------------
// Depthwise causal conv K=4 over u packed in GU [8192,3072] (u cols 1536+):
// u param points at GU+1536, row stride 3072. -> bf16 xc [8192,1536]
// ---------------------------------------------------------------------------
__global__ void conv_kernel(const u16* __restrict__ u, const float* __restrict__ w,
                            const float* __restrict__ bias, u16* __restrict__ xc)
{
    long idx = (long)blockIdx.x * blockDim.x + threadIdx.x;
    if (idx >= (long)B_ * T_ * HH_) return;
    int ch = (int)(idx % HH_);
    long row = idx / HH_;
    int t = (int)(row % T_);
    float acc = bias[ch];
#pragma unroll
    for (int k = 0; k < KC_; k++) {
        int ts = t - 3 + k;
        if (ts >= 0) acc += bf2f(u[(row - t + ts) * 3072 + ch]) * w[ch * KC_ + k];
    }
    xc[idx] = f2bf(acc);
}

// ---------------------------------------------------------------------------
// Chunked scan; fg/ig packed in GATES [8192,3072]; gate packed in GU
// [8192,3072] cols 0..1535; GLU written IN PLACE over GU's gate half.
// ---------------------------------------------------------------------------
#define CS_ 64
#define NC_ (T_ / CS_)

__device__ __forceinline__ void alpha_xin(const u16 fg, const u16 ig, const u16 xc,
                                          float sp, float& a, float& xin)
{
    a = expf(-8.0f * sp * sigmoidf_(bf2f(fg)));
    xin = sqrtf(1.f - a * a + 1e-6f) * sigmoidf_(bf2f(ig)) * bf2f(xc);
}

__global__ void scan1_kernel(const u16* __restrict__ gates,
                             const u16* __restrict__ xc, const float* __restrict__ fb,
                             float* __restrict__ P, float* __restrict__ L)
{
    long idx = (long)blockIdx.x * blockDim.x + threadIdx.x;
    if (idx >= (long)B_ * NC_ * HH_) return;
    int ch = (int)(idx % HH_);
    int chunk = (int)((idx / HH_) % NC_);
    int b = (int)(idx / ((long)HH_ * NC_));
    long row0 = (long)b * T_ + chunk * CS_;
    float f = fb[ch];
    float sp = (f > 20.f) ? f : log1pf(expf(f));
    float p = 1.f, lacc = 0.f;
    for (int i = 0; i < CS_; i++) {
        long rg = (row0 + i) * 3072;
        long rx = (row0 + i) * HH_;
        float a, xin;
        alpha_xin(gates[rg + ch], gates[rg + 1536 + ch], xc[rx + ch], sp, a, xin);
        lacc = a * lacc + xin;
        p *= a;
    }
    P[idx] = p; L[idx] = lacc;
}
__global__ void scan2_kernel(const float* __restrict__ P, const float* __restrict__ L,
                             float* __restrict__ I)
{
    long idx = (long)blockIdx.x * blockDim.x + threadIdx.x;
    if (idx >= (long)B_ * HH_) return;
    int ch = (int)(idx % HH_);
    int b = (int)(idx / HH_);
    float init = 0.f;
    for (int c = 0; c < NC_; c++) {
        long o = ((long)b * NC_ + c) * HH_ + ch;
        I[o] = init;
        init = P[o] * init + L[o];
    }
}
__global__ void scan3_kernel(const u16* __restrict__ gates,
                             const u16* __restrict__ xc, const float* __restrict__ fb,
                             const float* __restrict__ I, u16* __restrict__ gu)
{
    long idx = (long)blockIdx.x * blockDim.x + threadIdx.x;
    if (idx >= (long)B_ * NC_ * HH_) return;
    int ch = (int)(idx % HH_);
    int chunk = (int)((idx / HH_) % NC_);
    int b = (int)(idx / ((long)HH_ * NC_));
    long row0 = (long)b * T_ + chunk * CS_;
    float f = fb[ch];
    float sp = (f > 20.f) ? f : log1pf(expf(f));
    float h = I[idx];
    for (int i = 0; i < CS_; i++) {
        long rg = (row0 + i) * 3072;
        long rx = (row0 + i) * HH_;
        float a, xin;
        alpha_xin(gates[rg + ch], gates[rg + 1536 + ch], xc[rx + ch], sp, a, xin);
        h = a * h + xin;
        u16 g = gu[rg + ch];                       // gate (read)
        gu[rg + ch] = f2bf(gelu_exact(bf2f(g)) * h); // glu (in-place write)
    }
}

// ---------------------------------------------------------------------------
// launch
// ---------------------------------------------------------------------------
static inline long cdivl(long a, long b) { return (a + b - 1) / b; }

extern "C" void kernel_launch(void* const* d_in, const int* in_sizes, int n_in,
                              void* d_out, int out_size, void* d_ws, size_t ws_size,
                              hipStream_t stream)
{
    const float* x_in   = (const float*)d_in[0];
    const float* sn_g   = (const float*)d_in[1];
    const float* q_w    = (const float*)d_in[2];
    const float* kv_w   = (const float*)d_in[3];
    const float* ao_w   = (const float*)d_in[4];
    const float* sgn_g  = (const float*)d_in[5];
    const float* sg_grow   = (const float*)d_in[6];
    const float* sg_shrink = (const float*)d_in[7];
    const float* hn_g   = (const float*)d_in[8];
    const float* h_in_w = (const float*)d_in[9];
    const float* h_conv_w = (const float*)d_in[10];
    const float* h_conv_b = (const float*)d_in[11];
    const float* h_gates_w = (const float*)d_in[12];
    const float* h_gates_b = (const float*)d_in[13];
    const float* h_forget  = (const float*)d_in[14];
    const float* h_out_w   = (const float*)d_in[15];
    const float* hgn_g  = (const float*)d_in[16];
    const float* hg_grow   = (const float*)d_in[17];
    const float* hg_shrink = (const float*)d_in[18];
    float* out = (float*)d_out;

    // ---- workspace layout ----
    char* wsb = (char*)d_ws;
    u16* Wq  = (u16*)wsb;                 // contig with Wkv -> [1280,1024]
    u16* Wkv = Wq  + 1048576;
    u16* Wao = Wkv + 262144;
    u16* Wsg = Wao + 1048576;
    u16* Wss = Wsg + 4194304;
    u16* Whi = Wss + 2097152;
    u16* Whg = Whi + 3145728;
    u16* Who = Whg + 4718592;
    u16* Wgg = Who + 1572864;
    u16* Wgs = Wgg + 4194304;
    char* ab = wsb + 48758784;            // activation arena
    u16*   XN   = (u16*)(ab + 0);                    // [8192,1024] bf16
    char*  S2   = ab + 16777216;
    float* PB   = (float*)(ab + 150994944);
    float* LB   = (float*)(ab + 151781376);
    float* IB   = (float*)(ab + 152567808);

    const long M = (long)B_ * T_;   // 8192
    dim3 blk(256);
    dim3 blk5(512);
    const float* NULF = nullptr;
    const u16*   NULB = nullptr;

    // ---- weight conversion (single dispatch) ----
    {
        CvtArgs ca;
        const float* srcs[10] = {q_w, kv_w, ao_w, sg_grow, sg_shrink,
                                 h_in_w, h_gates_w, h_out_w, hg_grow, hg_shrink};
        u16* dsts[10] = {Wq, Wkv, Wao, Wsg, Wss, Whi, Whg, Who, Wgg, Wgs};
        long ns[10] = {1048576, 262144, 1048576, 4194304, 2097152,
                       3145728, 4718592, 1572864, 4194304, 2097152};
        long cum = 0;
        for (int i = 0; i < 10; i++) {
            ca.src[i] = srcs[i]; ca.dst[i] = dsts[i]; ca.cum[i] = cum; cum += ns[i];
        }
        ca.cum[10] = cum;
        cvt_all_kernel<<<dim3(cdivl(cum / 8, 256)), blk, 0, stream>>>(ca);
    }

    // ---- attention sublayer ----
    {
        u16*   QKVb = (u16*)(ab + 16777216);         // [8192,1280] bf16
        u16*   Kb   = (u16*)(ab + 58720256);         // [B,T,128] bf16
        u16*   Vt   = (u16*)(ab + 60817408);         // [B,128,T] bf16
        u16*   Qb   = (u16*)(ab + 62914560);         // [B,T,HQ,128] bf16
        u16*   AT   = (u16*)(ab + 79691776);         // [8192,1024] bf16
        rmsnorm_kernel<<<dim3(M), blk, 0, stream>>>(x_in, sn_g, XN);
        gemm_bf16_kernel<0,true><<<dim3(10, 64), blk, 0, stream>>>(XN, Wq, NULF, NULF, NULB, QKVb, M, 1280, 1024, 1024);
        rope_bf16_kernel<<<dim3(cdivl((long)B_ * T_ * (HQ_ + 1) * 64, 256)), blk, 0, stream>>>(QKVb, Qb, Kb);
        vtrans_kernel<<<dim3(T_ / 64, 2, B_), blk, 0, stream>>>(QKVb, Vt);
        attn_mfma6_kernel<<<dim3(T_ / 64, HQ_, B_), blk, 0, stream>>>(Qb, Kb, Vt, AT);
        gemm_bf16_kernel<2,false><<<dim3(8, 64), blk, 0, stream>>>(AT, Wao, NULF, x_in, NULB, out, M, 1024, 1024, 1024);
    }

    // ---- MLP 1 ----
    {
        u16* GATE = (u16*)S2;             // [8192,2048] bf16
        rmsnorm_kernel<<<dim3(M), blk, 0, stream>>>(out, sgn_g, XN);
        gemm_big_kernel<0,true><<<dim3(16, 32), blk5, 0, stream>>>(XN, Wsg, NULF, NULF, NULB, GATE, M, 2048, 1024);
        gemm_big_kernel<3,true><<<dim3(16, 32), blk5, 0, stream>>>(XN, Wsg + (size_t)2048 * 1024, NULF, NULF, GATE, GATE, M, 2048, 1024);
        gemm_bf16_kernel<2,false><<<dim3(8, 64), blk, 0, stream>>>(GATE, Wss, NULF, out, NULB, out, M, 1024, 2048, 2048);
    }

    // ---- hawk ----
    {
        u16* GU    = (u16*)(ab + 16777216);   // [8192,3072] gate|u, 50.3 MB
        u16* XC    = (u16*)(ab + 67108864);   // [8192,1536]
        u16* GATES = (u16*)(ab + 92274688);   // [8192,3072] fg|ig
        rmsnorm_kernel<<<dim3(M), blk, 0, stream>>>(out, hn_g, XN);
        gemm_big_kernel<0,true><<<dim3(24, 32), blk5, 0, stream>>>(XN, Whi, NULF, NULF, NULB, GU, M, 3072, 1024);
        conv_kernel<<<dim3(cdivl(M * HH_, 256)), blk, 0, stream>>>(GU + 1536, h_conv_w, h_conv_b, XC);
        gemm_big_kernel<1,true><<<dim3(24, 32), blk5, 0, stream>>>(XC, Whg, h_gates_b, NULF, NULB, GATES, M, 3072, 1536);
        scan1_kernel<<<dim3(cdivl((long)B_ * NC_ * HH_, 256)), blk, 0, stream>>>(GATES, XC, h_forget, PB, LB);
        scan2_kernel<<<dim3(cdivl((long)B_ * HH_, 256)), blk, 0, stream>>>(PB, LB, IB);
        scan3_kernel<<<dim3(cdivl((long)B_ * NC_ * HH_, 256)), blk, 0, stream>>>(GATES, XC, h_forget, IB, GU);
        gemm_bf16_kernel<2,false><<<dim3(8, 64), blk, 0, stream>>>(GU, Who, NULF, out, NULB, out, M, 1024, 1536, 3072);
    }

    // ---- MLP 2 ----
    {
        u16* GLU = (u16*)S2;              // [8192,2048] bf16
        rmsnorm_kernel<<<dim3(M), blk, 0, stream>>>(out, hgn_g, XN);
        gemm_big_kernel<0,true><<<dim3(16, 32), blk5, 0, stream>>>(XN, Wgg, NULF, NULF, NULB, GLU, M, 2048, 1024);
        gemm_big_kernel<3,true><<<dim3(16, 32), blk5, 0, stream>>>(XN, Wgg + (size_t)2048 * 1024, NULF, NULF, GLU, GLU, M, 2048, 1024);
        gemm_bf16_kernel<2,false><<<dim3(8, 64), blk, 0, stream>>>(GLU, Wgs, NULF, out, NULB, out, M, 1024, 2048, 2048);
    }
}